// Round 1
// baseline (40630.722 us; speedup 1.0000x reference)
//
#include <hip/hip_runtime.h>
#include <math.h>

// ---------------------------------------------------------------------------
// BinAlexNet forward (binarized AlexNet, training-mode BN).
// Round 0: correctness-first fp32 pipeline.
//   - htanh eliminated (sign(clip(x,-1,1)) == sign(x); every BN output is only
//     consumed through sign()).
//   - BN stats in double (exact); binary conv/FC sums are exact integers.
//   - conv+maxpool fused; BN-apply+sign in place; ping-pong buffers R1/R2.
// ---------------------------------------------------------------------------

__device__ __forceinline__ float sgn(float x) {
    return (float)((x > 0.0f) - (x < 0.0f));   // matches jnp.sign (sign(0)=0)
}

// ---- elementwise sign (weight binarization) ----
__global__ void k_sign(const float* __restrict__ in, float* __restrict__ out, long n) {
    long i = (long)blockIdx.x * blockDim.x + threadIdx.x;
    long stride = (long)gridDim.x * blockDim.x;
    for (; i < n; i += stride) out[i] = sgn(in[i]);
}

// ---- generic conv (pad, KxK) fused with maxpool (PWxPW window, stride ps) ----
// out[b,co,py,px] = max_{dy,dx} sum_{ci,ky,kx} in[b,ci, py*ps+dy-pad+ky, px*ps+dx-pad+kx] * w[co,ci,ky,kx]
// PW=1 => no pooling (ps must be 1, Ho==Hc).
template<int K, int PW>
__global__ void k_conv(const float* __restrict__ in, const float* __restrict__ w,
                       float* __restrict__ out,
                       int B, int Cin, int Hin, int Win,
                       int pad, int Hc, int Wc, int ps, int Ho, int Wo) {
    extern __shared__ float sw[];
    const int co   = blockIdx.x;
    const int Cout = gridDim.x;
    const int nw   = Cin * K * K;
    for (int i = threadIdx.x; i < nw; i += blockDim.x)
        sw[i] = w[(size_t)co * nw + i];
    __syncthreads();

    const int HWo = Ho * Wo;
    int idx = blockIdx.y * blockDim.x + threadIdx.x;
    if (idx >= B * HWo) return;
    int b  = idx / HWo;
    int r  = idx - b * HWo;
    int py = r / Wo, px = r - py * Wo;

    const float* ib = in + (size_t)b * Cin * Hin * Win;
    float best = -3.4e38f;
    for (int dy = 0; dy < PW; ++dy) {
        int yc = py * ps + dy;
        if (yc >= Hc) break;
        for (int dx = 0; dx < PW; ++dx) {
            int xc = px * ps + dx;
            if (xc >= Wc) break;
            int ky0 = max(0, pad - yc), ky1 = min(K, Hin + pad - yc);
            int kx0 = max(0, pad - xc), kx1 = min(K, Win + pad - xc);
            float sum = 0.0f;
            for (int ci = 0; ci < Cin; ++ci) {
                const float* ip = ib + (size_t)ci * Hin * Win;
                const float* wp = sw + ci * (K * K);
                for (int ky = ky0; ky < ky1; ++ky) {
                    const float* row = ip + (yc - pad + ky) * Win + (xc - pad);
                    const float* wr = wp + ky * K;
                    for (int kx = kx0; kx < kx1; ++kx)
                        sum = fmaf(row[kx], wr[kx], sum);
                }
            }
            best = fmaxf(best, sum);
        }
    }
    out[(size_t)(b * Cout + co) * HWo + r] = best;
}

// ---- BN2d stats over (B,H,W) per channel: one block per channel ----
__global__ void k_bnstats2d(const float* __restrict__ x, const float* __restrict__ g,
                            float* __restrict__ mean, float* __restrict__ inva,
                            int B, int C, int HW) {
    __shared__ double sh_s[256];
    __shared__ double sh_q[256];
    const int c = blockIdx.x;
    const int total = B * HW;
    double s = 0.0, q = 0.0;
    for (int i = threadIdx.x; i < total; i += blockDim.x) {
        int b = i / HW, j = i - b * HW;
        double v = (double)x[((size_t)b * C + c) * HW + j];
        s += v; q += v * v;
    }
    sh_s[threadIdx.x] = s; sh_q[threadIdx.x] = q;
    __syncthreads();
    for (int off = 128; off > 0; off >>= 1) {
        if ((int)threadIdx.x < off) {
            sh_s[threadIdx.x] += sh_s[threadIdx.x + off];
            sh_q[threadIdx.x] += sh_q[threadIdx.x + off];
        }
        __syncthreads();
    }
    if (threadIdx.x == 0) {
        double m   = sh_s[0] / total;
        double var = sh_q[0] / total - m * m;
        mean[c] = (float)m;
        inva[c] = g[c] * (float)(1.0 / sqrt(var + 1e-5));
    }
}

// ---- BN2d apply + sign, in place ----
__global__ void k_bnapply2d(float* __restrict__ x, const float* __restrict__ mean,
                            const float* __restrict__ inva, const float* __restrict__ beta,
                            int C, int HW, long total) {
    long i = (long)blockIdx.x * blockDim.x + threadIdx.x;
    long stride = (long)gridDim.x * blockDim.x;
    for (; i < total; i += stride) {
        int c = (int)((i / HW) % C);
        float v = (x[i] - mean[c]) * inva[c] + beta[c];
        x[i] = sgn(v);
    }
}

// ---- BN1d stats over batch: one thread per feature (coalesced across f) ----
__global__ void k_bnstats1d(const float* __restrict__ x, const float* __restrict__ g,
                            float* __restrict__ mean, float* __restrict__ inva,
                            int B, int F) {
    int f = blockIdx.x * blockDim.x + threadIdx.x;
    if (f >= F) return;
    double s = 0.0, q = 0.0;
    for (int r = 0; r < B; ++r) {
        double v = (double)x[(size_t)r * F + f];
        s += v; q += v * v;
    }
    double m   = s / B;
    double var = q / B - m * m;
    mean[f] = (float)m;
    inva[f] = g[f] * (float)(1.0 / sqrt(var + 1e-5));
}

// ---- BN1d apply + sign, in place ----
__global__ void k_bnapply1d(float* __restrict__ x, const float* __restrict__ mean,
                            const float* __restrict__ inva, const float* __restrict__ beta,
                            int F, long total) {
    long i = (long)blockIdx.x * blockDim.x + threadIdx.x;
    long stride = (long)gridDim.x * blockDim.x;
    for (; i < total; i += stride) {
        int f = (int)(i % F);
        float v = (x[i] - mean[f]) * inva[f] + beta[f];
        x[i] = sgn(v);
    }
}

// ---- FC: C[b,o] = sum_k A[b,k] * W[o,k] (+ bias). Tiled 16x16. ----
__global__ void k_fc(const float* __restrict__ A, const float* __restrict__ W,
                     const float* __restrict__ bias, float* __restrict__ C,
                     int Bm, int Kd, int O) {
    __shared__ float As[16][17];
    __shared__ float Ws[16][17];
    int tx = threadIdx.x, ty = threadIdx.y;
    int row = blockIdx.y * 16 + ty;   // batch index (Bm multiple of 16)
    int col = blockIdx.x * 16 + tx;   // output feature
    float acc = 0.0f;
    for (int k0 = 0; k0 < Kd; k0 += 16) {
        As[ty][tx] = A[(size_t)row * Kd + k0 + tx];
        int ow = blockIdx.x * 16 + ty;
        Ws[ty][tx] = (ow < O) ? W[(size_t)ow * Kd + k0 + tx] : 0.0f;
        __syncthreads();
        #pragma unroll
        for (int kk = 0; kk < 16; ++kk)
            acc = fmaf(As[ty][kk], Ws[tx][kk], acc);
        __syncthreads();
    }
    if (col < O)
        C[(size_t)row * O + col] = acc + (bias ? bias[col] : 0.0f);
}

// ---------------------------------------------------------------------------

extern "C" void kernel_launch(void* const* d_in, const int* in_sizes, int n_in,
                              void* d_out, int out_size, void* d_ws, size_t ws_size,
                              hipStream_t stream) {
    const float* x   = (const float*)d_in[0];
    const float* w1  = (const float*)d_in[1];
    const float* g1  = (const float*)d_in[2];
    const float* b1  = (const float*)d_in[3];
    const float* w2  = (const float*)d_in[4];
    const float* g2  = (const float*)d_in[5];
    const float* b2  = (const float*)d_in[6];
    const float* w3  = (const float*)d_in[7];
    const float* g3  = (const float*)d_in[8];
    const float* b3  = (const float*)d_in[9];
    const float* w4  = (const float*)d_in[10];
    const float* g4  = (const float*)d_in[11];
    const float* b4  = (const float*)d_in[12];
    const float* w5  = (const float*)d_in[13];
    const float* g5  = (const float*)d_in[14];
    const float* b5  = (const float*)d_in[15];
    const float* wl1 = (const float*)d_in[16];
    const float* gl1 = (const float*)d_in[17];
    const float* bl1 = (const float*)d_in[18];
    const float* wl2 = (const float*)d_in[19];
    const float* gl2 = (const float*)d_in[20];
    const float* bl2 = (const float*)d_in[21];
    const float* wl3 = (const float*)d_in[22];
    const float* bl3 = (const float*)d_in[23];
    float* out = (float*)d_out;

    // ---- workspace layout (floats) ----
    float* ws = (float*)d_ws;
    size_t off = 0;
    auto alloc = [&](size_t n) { float* p = ws + off; off += n; return p; };
    float* w1s  = alloc(4800);      // 64*3*5*5
    float* w2s  = alloc(307200);    // 192*64*5*5
    float* w3s  = alloc(663552);    // 384*192*3*3
    float* w4s  = alloc(884736);    // 256*384*3*3
    float* w5s  = alloc(589824);    // 256*256*3*3
    float* wl1s = alloc(4194304);   // 4096*1024
    float* wl2s = alloc(8388608);   // 2048*4096
    float* wl3s = alloc(20480);     // 10*2048
    float* R1   = alloc(7372800);   // max(p1, y3, p5, f2)
    float* R2   = alloc(4718592);   // max(p2, y4, f1)
    float* st   = alloc(2 * 4096 * 7);
    float* m_[7];
    float* a_[7];
    for (int l = 0; l < 7; ++l) { m_[l] = st + (size_t)l * 8192; a_[l] = m_[l] + 4096; }
    (void)ws_size; (void)n_in; (void)in_sizes; (void)out_size;

    // ---- binarize weights ----
    k_sign<<<64,   256, 0, stream>>>(w1,  w1s,  4800);
    k_sign<<<512,  256, 0, stream>>>(w2,  w2s,  307200);
    k_sign<<<1024, 256, 0, stream>>>(w3,  w3s,  663552);
    k_sign<<<1024, 256, 0, stream>>>(w4,  w4s,  884736);
    k_sign<<<1024, 256, 0, stream>>>(w5,  w5s,  589824);
    k_sign<<<2048, 256, 0, stream>>>(wl1, wl1s, 4194304);
    k_sign<<<2048, 256, 0, stream>>>(wl2, wl2s, 8388608);
    k_sign<<<128,  256, 0, stream>>>(wl3, wl3s, 20480);

    // ---- conv1 (real input, signed weights) + maxpool2x2 -> R1 [512,64,15,15] ----
    {
        dim3 grid(64, (512 * 225 + 255) / 256);
        k_conv<5, 2><<<grid, 256, 3 * 25 * sizeof(float), stream>>>(
            x, w1s, R1, 512, 3, 32, 32, 1, 30, 30, 2, 15, 15);
    }
    k_bnstats2d<<<64, 256, 0, stream>>>(R1, g1, m_[0], a_[0], 512, 64, 225);
    k_bnapply2d<<<2048, 256, 0, stream>>>(R1, m_[0], a_[0], b1, 64, 225, (long)512 * 64 * 225);

    // ---- conv2 + maxpool2x2 -> R2 [512,192,6,6] ----
    {
        dim3 grid(192, (512 * 36 + 255) / 256);
        k_conv<5, 2><<<grid, 256, 64 * 25 * sizeof(float), stream>>>(
            R1, w2s, R2, 512, 64, 15, 15, 1, 13, 13, 2, 6, 6);
    }
    k_bnstats2d<<<192, 256, 0, stream>>>(R2, g2, m_[1], a_[1], 512, 192, 36);
    k_bnapply2d<<<2048, 256, 0, stream>>>(R2, m_[1], a_[1], b2, 192, 36, (long)512 * 192 * 36);

    // ---- conv3 -> R1 [512,384,6,6] ----
    {
        dim3 grid(384, (512 * 36 + 255) / 256);
        k_conv<3, 1><<<grid, 256, 192 * 9 * sizeof(float), stream>>>(
            R2, w3s, R1, 512, 192, 6, 6, 1, 6, 6, 1, 6, 6);
    }
    k_bnstats2d<<<384, 256, 0, stream>>>(R1, g3, m_[2], a_[2], 512, 384, 36);
    k_bnapply2d<<<2048, 256, 0, stream>>>(R1, m_[2], a_[2], b3, 384, 36, (long)512 * 384 * 36);

    // ---- conv4 -> R2 [512,256,6,6] ----
    {
        dim3 grid(256, (512 * 36 + 255) / 256);
        k_conv<3, 1><<<grid, 256, 384 * 9 * sizeof(float), stream>>>(
            R1, w4s, R2, 512, 384, 6, 6, 1, 6, 6, 1, 6, 6);
    }
    k_bnstats2d<<<256, 256, 0, stream>>>(R2, g4, m_[3], a_[3], 512, 256, 36);
    k_bnapply2d<<<2048, 256, 0, stream>>>(R2, m_[3], a_[3], b4, 256, 36, (long)512 * 256 * 36);

    // ---- conv5 + maxpool3x3/2 -> R1 [512,256,2,2] ----
    {
        dim3 grid(256, (512 * 4 + 255) / 256);
        k_conv<3, 3><<<grid, 256, 256 * 9 * sizeof(float), stream>>>(
            R2, w5s, R1, 512, 256, 6, 6, 1, 6, 6, 2, 2, 2);
    }
    k_bnstats2d<<<256, 256, 0, stream>>>(R1, g5, m_[4], a_[4], 512, 256, 4);
    k_bnapply2d<<<512, 256, 0, stream>>>(R1, m_[4], a_[4], b5, 256, 4, (long)512 * 256 * 4);

    // ---- fc1: [512,1024] x [4096,1024]^T -> R2 [512,4096] ----
    k_fc<<<dim3(4096 / 16, 512 / 16), dim3(16, 16), 0, stream>>>(R1, wl1s, nullptr, R2, 512, 1024, 4096);
    k_bnstats1d<<<(4096 + 255) / 256, 256, 0, stream>>>(R2, gl1, m_[5], a_[5], 512, 4096);
    k_bnapply1d<<<2048, 256, 0, stream>>>(R2, m_[5], a_[5], bl1, 4096, (long)512 * 4096);

    // ---- fc2: [512,4096] x [2048,4096]^T -> R1 [512,2048] ----
    k_fc<<<dim3(2048 / 16, 512 / 16), dim3(16, 16), 0, stream>>>(R2, wl2s, nullptr, R1, 512, 4096, 2048);
    k_bnstats1d<<<(2048 + 255) / 256, 256, 0, stream>>>(R1, gl2, m_[6], a_[6], 512, 2048);
    k_bnapply1d<<<1024, 256, 0, stream>>>(R1, m_[6], a_[6], bl2, 2048, (long)512 * 2048);

    // ---- fc3: [512,2048] x [10,2048]^T + bias -> out [512,10] ----
    k_fc<<<dim3(1, 512 / 16), dim3(16, 16), 0, stream>>>(R1, wl3s, bl3, out, 512, 2048, 10);
}

// Round 2
// 2474.892 us; speedup vs baseline: 16.4172x; 16.4172x over previous
//
#include <hip/hip_runtime.h>
#include <math.h>

// ---------------------------------------------------------------------------
// BinAlexNet forward — round 2: bitpacked XOR+popcount binary convs/FCs.
//   activations {-1,0,+1} -> (sa=sign bit, na=nonzero bit) per 64-ch word
//   weights {-1,(0),+1}   -> (sw, wna)
//   dot = popc(na&wna) - 2*popc((sa^sw)&na&wna)   (exact integers)
// BN stats in double (exact for integer inputs), 2-stage reduction.
// conv1 stays fp32 (real input) with image+weights staged in LDS, identical
// fma order to round 1 (bitwise-identical sums).
// ---------------------------------------------------------------------------

typedef unsigned long long u64;

__device__ __forceinline__ float sgn(float x) {
    return (float)((x > 0.0f) - (x < 0.0f));
}

__device__ __forceinline__ int dotpack(u64 sa, u64 na, u64 sw, u64 wna) {
    u64 valid = na & wna;
    u64 diff  = (sa ^ sw) & valid;
    return __popcll(valid) - 2 * __popcll(diff);
}

// ---- conv1: real input, signed weights, fused maxpool2x2 ----
// x [512][3][32][32], w raw fp32 [64][3][5][5], out [512][64][15][15]
__global__ void k_conv1(const float* __restrict__ x, const float* __restrict__ w,
                        float* __restrict__ out) {
    __shared__ float sx[3 * 32 * 32];
    __shared__ float swt[64 * 75];
    const int b = blockIdx.x;
    for (int i = threadIdx.x; i < 3 * 32 * 32; i += blockDim.x)
        sx[i] = x[(size_t)b * 3072 + i];
    for (int i = threadIdx.x; i < 64 * 75; i += blockDim.x)
        swt[i] = sgn(w[i]);
    __syncthreads();
    for (int o = threadIdx.x; o < 64 * 225; o += blockDim.x) {
        int co = o / 225, r = o - co * 225;
        int py = r / 15, px = r - py * 15;
        float best = -3.4e38f;
        for (int dy = 0; dy < 2; ++dy) {
            for (int dx = 0; dx < 2; ++dx) {
                int yc = py * 2 + dy, xc = px * 2 + dx;   // conv coord < 30
                float sum = 0.0f;
                for (int ci = 0; ci < 3; ++ci) {
                    const float* ip = sx + ci * 1024;
                    const float* wp = swt + co * 75 + ci * 25;
                    for (int ky = 0; ky < 5; ++ky) {
                        int yy = yc - 1 + ky;
                        if ((unsigned)yy >= 32u) continue;
                        for (int kx = 0; kx < 5; ++kx) {
                            int xx = xc - 1 + kx;
                            if ((unsigned)xx >= 32u) continue;
                            sum = fmaf(ip[yy * 32 + xx], wp[ky * 5 + kx], sum);
                        }
                    }
                }
                best = fmaxf(best, sum);
            }
        }
        out[((size_t)b * 64 + co) * 225 + r] = best;
    }
}

// ---- pack conv weights: [Cout][Cin][KK] fp32 -> [Cout][KK][2*NW] u64 ----
__global__ void k_packw_conv(const float* __restrict__ w, u64* __restrict__ wp,
                             int Cout, int Cin, int KK) {
    int NW = (Cin + 63) >> 6;
    int tot = Cout * KK * NW;
    int idx = blockIdx.x * blockDim.x + threadIdx.x;
    if (idx >= tot) return;
    int wd = idx % NW, t = idx / NW;
    int tap = t % KK, co = t / KK;
    u64 s = 0, nz = 0;
    for (int c = 0; c < 64; ++c) {
        int ci = wd * 64 + c;
        if (ci >= Cin) break;
        float v = w[((size_t)co * Cin + ci) * KK + tap];
        if (v > 0.0f) s |= (1ull << c);
        if (v != 0.0f) nz |= (1ull << c);
    }
    u64* o = wp + ((size_t)co * KK + tap) * 2 * NW + 2 * wd;
    o[0] = s; o[1] = nz;
}

// ---- pack fc weights: [O][Kd] fp32 -> [O][2*NW] u64 ----
__global__ void k_packw_fc(const float* __restrict__ w, u64* __restrict__ wp,
                           int O, int Kd) {
    int NW = Kd >> 6;
    int tot = O * NW;
    int idx = blockIdx.x * blockDim.x + threadIdx.x;
    if (idx >= tot) return;
    int wd = idx % NW, o = idx / NW;
    const float* row = w + (size_t)o * Kd + wd * 64;
    u64 s = 0, nz = 0;
    for (int c = 0; c < 64; ++c) {
        float v = row[c];
        if (v > 0.0f) s |= (1ull << c);
        if (v != 0.0f) nz |= (1ull << c);
    }
    u64* op = wp + (size_t)o * 2 * NW + 2 * wd;
    op[0] = s; op[1] = nz;
}

// ---- binary conv fused with maxpool ----
// in [B][Hin][Win][2*NW] packed, w [Cout][K*K][2*NW], out [B][Cout][Ho*Wo] fp32
template<int K, int PW, int NW>
__global__ void k_convbin(const u64* __restrict__ in, const u64* __restrict__ w,
                          float* __restrict__ out,
                          int B, int Hin, int Win, int pad, int Hc, int Wc,
                          int ps, int Ho, int Wo) {
    __shared__ u64 swp[K * K * 2 * NW];
    const int co = blockIdx.x, Cout = gridDim.x;
    for (int i = threadIdx.x; i < K * K * 2 * NW; i += blockDim.x)
        swp[i] = w[(size_t)co * (K * K * 2 * NW) + i];
    __syncthreads();
    const int HWo = Ho * Wo;
    int idx = blockIdx.y * blockDim.x + threadIdx.x;
    if (idx >= B * HWo) return;
    int b = idx / HWo, r = idx - b * HWo;
    int py = r / Wo, px = r - py * Wo;
    const u64* ib = in + (size_t)b * Hin * Win * 2 * NW;
    int best = -2147483647;
    for (int dy = 0; dy < PW; ++dy) {
        int yc = py * ps + dy;
        if (yc >= Hc) break;
        for (int dx = 0; dx < PW; ++dx) {
            int xc = px * ps + dx;
            if (xc >= Wc) break;
            int sum = 0;
            for (int ky = 0; ky < K; ++ky) {
                int yy = yc - pad + ky;
                if ((unsigned)yy >= (unsigned)Hin) continue;
                for (int kx = 0; kx < K; ++kx) {
                    int xx = xc - pad + kx;
                    if ((unsigned)xx >= (unsigned)Win) continue;
                    const ulonglong2* ip = reinterpret_cast<const ulonglong2*>(
                        ib + ((size_t)yy * Win + xx) * 2 * NW);
                    const u64* wp = swp + (ky * K + kx) * 2 * NW;
                    #pragma unroll
                    for (int wd = 0; wd < NW; ++wd) {
                        ulonglong2 a = ip[wd];
                        sum += dotpack(a.x, a.y, wp[2 * wd], wp[2 * wd + 1]);
                    }
                }
            }
            best = max(best, sum);
        }
    }
    out[((size_t)b * Cout + co) * HWo + r] = (float)best;
}

// ---- BN stats stage A (2d): x [B][C][HW] -> part[(c*NB+chunk)*2] (double s,q) ----
__global__ void k_stats2d_part(const float* __restrict__ x, double* __restrict__ part,
                               int B, int C, int HW, int NB) {
    __shared__ double ss[256], sq[256];
    const int c = blockIdx.x, chunk = blockIdx.y;
    const int b0 = B * chunk / NB, b1 = B * (chunk + 1) / NB;
    const int n = (b1 - b0) * HW;
    double s = 0.0, q = 0.0;
    for (int i = threadIdx.x; i < n; i += blockDim.x) {
        int b = b0 + i / HW, j = i % HW;
        double v = (double)x[((size_t)b * C + c) * HW + j];
        s += v; q += v * v;
    }
    ss[threadIdx.x] = s; sq[threadIdx.x] = q;
    __syncthreads();
    for (int off = 128; off > 0; off >>= 1) {
        if ((int)threadIdx.x < off) {
            ss[threadIdx.x] += ss[threadIdx.x + off];
            sq[threadIdx.x] += sq[threadIdx.x + off];
        }
        __syncthreads();
    }
    if (threadIdx.x == 0) {
        part[((size_t)c * NB + chunk) * 2]     = ss[0];
        part[((size_t)c * NB + chunk) * 2 + 1] = sq[0];
    }
}

// ---- BN stats stage A (1d): x [B][F] -> part[(f*NB+chunk)*2] ----
__global__ void k_stats1d_part(const float* __restrict__ x, double* __restrict__ part,
                               int B, int F, int NB) {
    int f = blockIdx.x * blockDim.x + threadIdx.x;
    if (f >= F) return;
    int chunk = blockIdx.y;
    int b0 = B * chunk / NB, b1 = B * (chunk + 1) / NB;
    double s = 0.0, q = 0.0;
    for (int r = b0; r < b1; ++r) {
        double v = (double)x[(size_t)r * F + f];
        s += v; q += v * v;
    }
    part[((size_t)f * NB + chunk) * 2]     = s;
    part[((size_t)f * NB + chunk) * 2 + 1] = q;
}

// ---- BN stats stage B: reduce partials -> mean, inva(=g/sqrt(var+eps)) ----
__global__ void k_stats_final(const double* __restrict__ part, const float* __restrict__ g,
                              float* __restrict__ mean, float* __restrict__ inva,
                              int C, int NB, long total) {
    int c = blockIdx.x * blockDim.x + threadIdx.x;
    if (c >= C) return;
    double s = 0.0, q = 0.0;
    for (int k = 0; k < NB; ++k) {
        s += part[((size_t)c * NB + k) * 2];
        q += part[((size_t)c * NB + k) * 2 + 1];
    }
    double m = s / (double)total;
    double var = q / (double)total - m * m;
    mean[c] = (float)m;
    inva[c] = g[c] * (float)(1.0 / sqrt(var + 1e-5));
}

// ---- BN apply + sign + pack (2d, channel-packed): x [B][C][HW] -> p [B][HW][2*NW] ----
__global__ void k_bnpack2d(const float* __restrict__ x, const float* __restrict__ m,
                           const float* __restrict__ a, const float* __restrict__ bt,
                           u64* __restrict__ p, int B, int C, int HW) {
    int NW = (C + 63) >> 6;
    int tot = B * HW * NW;
    int idx = blockIdx.x * blockDim.x + threadIdx.x;
    if (idx >= tot) return;
    int wd = idx % NW, t = idx / NW;
    int j = t % HW, b = t / HW;
    u64 s = 0, nz = 0;
    for (int c0 = 0; c0 < 64; ++c0) {
        int c = wd * 64 + c0;
        if (c >= C) break;
        float v = (x[((size_t)b * C + c) * HW + j] - m[c]) * a[c] + bt[c];
        if (v > 0.0f) s |= (1ull << c0);
        if (v != 0.0f) nz |= (1ull << c0);
    }
    u64* o = p + ((size_t)b * HW + j) * 2 * NW + 2 * wd;
    o[0] = s; o[1] = nz;
}

// ---- conv5 output: BN + sign + flatten-pack: x [B][256][4] -> p [B][2*16] over f=c*4+j ----
__global__ void k_bnpack_flat(const float* __restrict__ x, const float* __restrict__ m,
                              const float* __restrict__ a, const float* __restrict__ bt,
                              u64* __restrict__ p, int B) {
    int idx = blockIdx.x * blockDim.x + threadIdx.x;
    if (idx >= B * 16) return;
    int wd = idx % 16, b = idx / 16;
    u64 s = 0, nz = 0;
    for (int k = 0; k < 64; ++k) {
        int f = wd * 64 + k;
        int c = f >> 2, j = f & 3;
        float v = (x[((size_t)b * 256 + c) * 4 + j] - m[c]) * a[c] + bt[c];
        if (v > 0.0f) s |= (1ull << k);
        if (v != 0.0f) nz |= (1ull << k);
    }
    u64* o = p + (size_t)b * 32 + 2 * wd;
    o[0] = s; o[1] = nz;
}

// ---- BN apply + sign + pack (1d): x [B][F] -> p [B][2*NW] ----
__global__ void k_bnpack1d(const float* __restrict__ x, const float* __restrict__ m,
                           const float* __restrict__ a, const float* __restrict__ bt,
                           u64* __restrict__ p, int B, int F) {
    int NW = F >> 6;
    int idx = blockIdx.x * blockDim.x + threadIdx.x;
    if (idx >= B * NW) return;
    int wd = idx % NW, b = idx / NW;
    const float* row = x + (size_t)b * F + wd * 64;
    u64 s = 0, nz = 0;
    for (int c = 0; c < 64; ++c) {
        int f = wd * 64 + c;
        float v = (row[c] - m[f]) * a[f] + bt[f];
        if (v > 0.0f) s |= (1ull << c);
        if (v != 0.0f) nz |= (1ull << c);
    }
    u64* o = p + (size_t)b * 2 * NW + 2 * wd;
    o[0] = s; o[1] = nz;
}

// ---- binary FC: A [B][2*NW], W [O][2*NW] -> C [B][O] fp32 (+bias) ----
__global__ void k_fcbin(const u64* __restrict__ A, const u64* __restrict__ W,
                        const float* __restrict__ bias, float* __restrict__ C,
                        int B, int O, int NW) {
    int idx = blockIdx.x * blockDim.x + threadIdx.x;
    if (idx >= B * O) return;
    int o = idx % O, b = idx / O;
    const ulonglong2* ar = reinterpret_cast<const ulonglong2*>(A + (size_t)b * 2 * NW);
    const ulonglong2* wr = reinterpret_cast<const ulonglong2*>(W + (size_t)o * 2 * NW);
    int sum = 0;
    for (int wd = 0; wd < NW; ++wd) {
        ulonglong2 a = ar[wd], w = wr[wd];
        sum += dotpack(a.x, a.y, w.x, w.y);
    }
    C[(size_t)b * O + o] = (float)sum + (bias ? bias[o] : 0.0f);
}

// ---------------------------------------------------------------------------

static inline int cdiv(long a, int b) { return (int)((a + b - 1) / b); }

extern "C" void kernel_launch(void* const* d_in, const int* in_sizes, int n_in,
                              void* d_out, int out_size, void* d_ws, size_t ws_size,
                              hipStream_t stream) {
    const float* x   = (const float*)d_in[0];
    const float* w1  = (const float*)d_in[1];
    const float* g1  = (const float*)d_in[2];
    const float* b1  = (const float*)d_in[3];
    const float* w2  = (const float*)d_in[4];
    const float* g2  = (const float*)d_in[5];
    const float* b2  = (const float*)d_in[6];
    const float* w3  = (const float*)d_in[7];
    const float* g3  = (const float*)d_in[8];
    const float* b3  = (const float*)d_in[9];
    const float* w4  = (const float*)d_in[10];
    const float* g4  = (const float*)d_in[11];
    const float* b4  = (const float*)d_in[12];
    const float* w5  = (const float*)d_in[13];
    const float* g5  = (const float*)d_in[14];
    const float* b5  = (const float*)d_in[15];
    const float* wl1 = (const float*)d_in[16];
    const float* gl1 = (const float*)d_in[17];
    const float* bl1 = (const float*)d_in[18];
    const float* wl2 = (const float*)d_in[19];
    const float* gl2 = (const float*)d_in[20];
    const float* bl2 = (const float*)d_in[21];
    const float* wl3 = (const float*)d_in[22];
    const float* bl3 = (const float*)d_in[23];
    float* out = (float*)d_out;
    (void)in_sizes; (void)n_in; (void)out_size; (void)ws_size;

    // ---- workspace layout (byte allocator, 16B aligned) ----
    char* base = (char*)d_ws;
    size_t off = 0;
    auto alloc = [&](size_t bytes) {
        char* p = base + off;
        off += (bytes + 15) & ~(size_t)15;
        return (void*)p;
    };
    float* R1 = (float*)alloc(7372800 * 4);   // conv1/conv3/conv5/fc2 outputs
    float* R2 = (float*)alloc(4718592 * 4);   // conv2/conv4/fc1 outputs
    u64* p1  = (u64*)alloc(230400 * 8);   // [512][225][2]
    u64* p2  = (u64*)alloc(110592 * 8);   // [512][36][6]
    u64* p3  = (u64*)alloc(221184 * 8);   // [512][36][12]
    u64* p4  = (u64*)alloc(147456 * 8);   // [512][36][8]
    u64* p5  = (u64*)alloc(16384 * 8);    // [512][32]
    u64* pf1 = (u64*)alloc(65536 * 8);    // [512][128]
    u64* pf2 = (u64*)alloc(32768 * 8);    // [512][64]
    u64* w2p  = (u64*)alloc(9600 * 8);
    u64* w3p  = (u64*)alloc(20736 * 8);
    u64* w4p  = (u64*)alloc(27648 * 8);
    u64* w5p  = (u64*)alloc(18432 * 8);
    u64* wl1p = (u64*)alloc(131072 * 8);
    u64* wl2p = (u64*)alloc(262144 * 8);
    u64* wl3p = (u64*)alloc(640 * 8);
    double* part = (double*)alloc(4096 * 16 * 2 * 8);
    float* stats = (float*)alloc(7 * 2 * 4096 * 4);
    float* m_[7]; float* a_[7];
    for (int l = 0; l < 7; ++l) { m_[l] = stats + (size_t)l * 8192; a_[l] = m_[l] + 4096; }
    const int NB = 16;

    // ---- pack all binary weights (from raw fp32, sign folded in) ----
    k_packw_conv<<<cdiv(4800, 256),  256, 0, stream>>>(w2, w2p, 192, 64, 25);
    k_packw_conv<<<cdiv(10368, 256), 256, 0, stream>>>(w3, w3p, 384, 192, 9);
    k_packw_conv<<<cdiv(13824, 256), 256, 0, stream>>>(w4, w4p, 256, 384, 9);
    k_packw_conv<<<cdiv(9216, 256),  256, 0, stream>>>(w5, w5p, 256, 256, 9);
    k_packw_fc<<<cdiv(65536, 256),  256, 0, stream>>>(wl1, wl1p, 4096, 1024);
    k_packw_fc<<<cdiv(131072, 256), 256, 0, stream>>>(wl2, wl2p, 2048, 4096);
    k_packw_fc<<<cdiv(320, 256),    256, 0, stream>>>(wl3, wl3p, 10, 2048);

    // ---- conv1 (fp32) + pool -> R1 [512,64,225]; bn1; pack -> p1 ----
    k_conv1<<<512, 256, 0, stream>>>(x, w1, R1);
    k_stats2d_part<<<dim3(64, NB), 256, 0, stream>>>(R1, part, 512, 64, 225, NB);
    k_stats_final<<<1, 64, 0, stream>>>(part, g1, m_[0], a_[0], 64, NB, (long)512 * 225);
    k_bnpack2d<<<cdiv((long)512 * 225 * 1, 256), 256, 0, stream>>>(R1, m_[0], a_[0], b1, p1, 512, 64, 225);

    // ---- conv2 (bin, NW=1) + pool -> R2 [512,192,36]; bn2; pack -> p2 ----
    k_convbin<5, 2, 1><<<dim3(192, cdiv(512 * 36, 256)), 256, 0, stream>>>(
        p1, w2p, R2, 512, 15, 15, 1, 13, 13, 2, 6, 6);
    k_stats2d_part<<<dim3(192, NB), 256, 0, stream>>>(R2, part, 512, 192, 36, NB);
    k_stats_final<<<1, 192, 0, stream>>>(part, g2, m_[1], a_[1], 192, NB, (long)512 * 36);
    k_bnpack2d<<<cdiv((long)512 * 36 * 3, 256), 256, 0, stream>>>(R2, m_[1], a_[1], b2, p2, 512, 192, 36);

    // ---- conv3 (bin, NW=3) -> R1 [512,384,36]; bn3; pack -> p3 ----
    k_convbin<3, 1, 3><<<dim3(384, cdiv(512 * 36, 256)), 256, 0, stream>>>(
        p2, w3p, R1, 512, 6, 6, 1, 6, 6, 1, 6, 6);
    k_stats2d_part<<<dim3(384, NB), 256, 0, stream>>>(R1, part, 512, 384, 36, NB);
    k_stats_final<<<2, 192, 0, stream>>>(part, g3, m_[2], a_[2], 384, NB, (long)512 * 36);
    k_bnpack2d<<<cdiv((long)512 * 36 * 6, 256), 256, 0, stream>>>(R1, m_[2], a_[2], b3, p3, 512, 384, 36);

    // ---- conv4 (bin, NW=6) -> R2 [512,256,36]; bn4; pack -> p4 ----
    k_convbin<3, 1, 6><<<dim3(256, cdiv(512 * 36, 256)), 256, 0, stream>>>(
        p3, w4p, R2, 512, 6, 6, 1, 6, 6, 1, 6, 6);
    k_stats2d_part<<<dim3(256, NB), 256, 0, stream>>>(R2, part, 512, 256, 36, NB);
    k_stats_final<<<1, 256, 0, stream>>>(part, g4, m_[3], a_[3], 256, NB, (long)512 * 36);
    k_bnpack2d<<<cdiv((long)512 * 36 * 4, 256), 256, 0, stream>>>(R2, m_[3], a_[3], b4, p4, 512, 256, 36);

    // ---- conv5 (bin, NW=4) + pool3x3/2 -> R1 [512,256,4]; bn5; flat-pack -> p5 ----
    k_convbin<3, 3, 4><<<dim3(256, cdiv(512 * 4, 256)), 256, 0, stream>>>(
        p4, w5p, R1, 512, 6, 6, 1, 6, 6, 2, 2, 2);
    k_stats2d_part<<<dim3(256, NB), 256, 0, stream>>>(R1, part, 512, 256, 4, NB);
    k_stats_final<<<1, 256, 0, stream>>>(part, g5, m_[4], a_[4], 256, NB, (long)512 * 4);
    k_bnpack_flat<<<cdiv(512 * 16, 256), 256, 0, stream>>>(R1, m_[4], a_[4], b5, p5, 512);

    // ---- fc1 (bin, NW=16): p5 x wl1p -> R2 [512,4096]; bn; pack -> pf1 ----
    k_fcbin<<<cdiv((long)512 * 4096, 256), 256, 0, stream>>>(p5, wl1p, nullptr, R2, 512, 4096, 16);
    k_stats1d_part<<<dim3(16, NB), 256, 0, stream>>>(R2, part, 512, 4096, NB);
    k_stats_final<<<16, 256, 0, stream>>>(part, gl1, m_[5], a_[5], 4096, NB, 512);
    k_bnpack1d<<<cdiv(512 * 64, 256), 256, 0, stream>>>(R2, m_[5], a_[5], bl1, pf1, 512, 4096);

    // ---- fc2 (bin, NW=64): pf1 x wl2p -> R1 [512,2048]; bn; pack -> pf2 ----
    k_fcbin<<<cdiv((long)512 * 2048, 256), 256, 0, stream>>>(pf1, wl2p, nullptr, R1, 512, 2048, 64);
    k_stats1d_part<<<dim3(8, NB), 256, 0, stream>>>(R1, part, 512, 2048, NB);
    k_stats_final<<<8, 256, 0, stream>>>(part, gl2, m_[6], a_[6], 2048, NB, 512);
    k_bnpack1d<<<cdiv(512 * 32, 256), 256, 0, stream>>>(R1, m_[6], a_[6], bl2, pf2, 512, 2048);

    // ---- fc3 (bin, NW=32) + bias -> out [512,10] ----
    k_fcbin<<<cdiv(512 * 10, 256), 256, 0, stream>>>(pf2, wl3p, bl3, out, 512, 10, 32);
}

// Round 3
// 1180.012 us; speedup vs baseline: 34.4325x; 2.0973x over previous
//
#include <hip/hip_runtime.h>
#include <math.h>

// ---------------------------------------------------------------------------
// BinAlexNet forward — round 3: LDS-staged conv1 + LDS-staged binary convs.
//   conv1: padded image in LDS (34-stride, no bank aliasing, no bounds checks),
//          weights via block-uniform scalar loads; per-window fma order
//          identical to round 2 (bit-identical fp32 sums).
//   binary convs: zero-padded packed input tiles in LDS per batch-group;
//          pool-window tap dedup for conv2; weights via uniform s_loads.
//   FCs: 16x16 LDS-tiled with +2 u64 row pad (bank-conflict-free).
// ---------------------------------------------------------------------------

typedef unsigned long long u64;

__device__ __forceinline__ float sgn(float x) {
    return (float)((x > 0.0f) - (x < 0.0f));
}

__device__ __forceinline__ int dotpack(u64 sa, u64 na, u64 sw, u64 wna) {
    u64 valid = na & wna;
    u64 diff  = (sa ^ sw) & valid;
    return __popcll(valid) - 2 * __popcll(diff);
}

// ---- elementwise sign (conv1 weight binarization) ----
__global__ void k_sign(const float* __restrict__ in, float* __restrict__ out, long n) {
    long i = (long)blockIdx.x * blockDim.x + threadIdx.x;
    long stride = (long)gridDim.x * blockDim.x;
    for (; i < n; i += stride) out[i] = sgn(in[i]);
}

// ---- conv1: real input, signed weights (pre-signed w1s), fused maxpool2x2 ----
// grid (8 co-groups, 512 b), 256 thr. x [512][3][32][32] -> out [512][64][225]
__global__ __launch_bounds__(256)
void k_conv1(const float* __restrict__ x, const float* __restrict__ w1s,
             float* __restrict__ out) {
    __shared__ float sx[3 * 34 * 34];
    const int b = blockIdx.y, cg = blockIdx.x, t = threadIdx.x;
    for (int i = t; i < 3 * 34 * 34; i += 256) sx[i] = 0.0f;
    __syncthreads();
    for (int i = t; i < 3072; i += 256) {
        int ch = i >> 10, rem = i & 1023, yy = rem >> 5, xx = rem & 31;
        sx[(ch * 34 + yy + 1) * 34 + xx + 1] = x[(size_t)b * 3072 + i];
    }
    __syncthreads();
    if (t >= 225) return;
    const int py = t / 15, px = t - py * 15;
    #pragma unroll 1
    for (int cc = 0; cc < 8; ++cc) {
        const int co = cg * 8 + cc;
        const float* wb = w1s + co * 75;
        float acc0 = 0.f, acc1 = 0.f, acc2 = 0.f, acc3 = 0.f;
        #pragma unroll 1
        for (int ch = 0; ch < 3; ++ch) {
            const float* wc = wb + ch * 25;
            #pragma unroll
            for (int yy6 = 0; yy6 < 6; ++yy6) {
                const float2* rp = (const float2*)&sx[(ch * 34 + py * 2 + yy6) * 34 + px * 2];
                float2 ra = rp[0], rb = rp[1], rc = rp[2];
                float r[6] = {ra.x, ra.y, rb.x, rb.y, rc.x, rc.y};
                #pragma unroll
                for (int dy = 0; dy < 2; ++dy) {
                    const int ky = yy6 - dy;
                    if (ky < 0 || ky > 4) continue;
                    #pragma unroll
                    for (int kx = 0; kx < 5; ++kx) {
                        const float wv = wc[ky * 5 + kx];
                        if (dy == 0) {
                            acc0 = fmaf(r[kx],     wv, acc0);
                            acc1 = fmaf(r[kx + 1], wv, acc1);
                        } else {
                            acc2 = fmaf(r[kx],     wv, acc2);
                            acc3 = fmaf(r[kx + 1], wv, acc3);
                        }
                    }
                }
            }
        }
        float best = fmaxf(fmaxf(acc0, acc1), fmaxf(acc2, acc3));
        out[((size_t)b * 64 + co) * 225 + t] = best;
    }
}

// ---- pack conv weights: [Cout][Cin][KK] fp32 -> [Cout][KK][2*NW] u64 ----
__global__ void k_packw_conv(const float* __restrict__ w, u64* __restrict__ wp,
                             int Cout, int Cin, int KK) {
    int NW = (Cin + 63) >> 6;
    int tot = Cout * KK * NW;
    int idx = blockIdx.x * blockDim.x + threadIdx.x;
    if (idx >= tot) return;
    int wd = idx % NW, t = idx / NW;
    int tap = t % KK, co = t / KK;
    u64 s = 0, nz = 0;
    for (int c = 0; c < 64; ++c) {
        int ci = wd * 64 + c;
        if (ci >= Cin) break;
        float v = w[((size_t)co * Cin + ci) * KK + tap];
        if (v > 0.0f) s |= (1ull << c);
        if (v != 0.0f) nz |= (1ull << c);
    }
    u64* o = wp + ((size_t)co * KK + tap) * 2 * NW + 2 * wd;
    o[0] = s; o[1] = nz;
}

// ---- pack fc weights: [O][Kd] fp32 -> [O][2*NW] u64 ----
__global__ void k_packw_fc(const float* __restrict__ w, u64* __restrict__ wp,
                           int O, int Kd) {
    int NW = Kd >> 6;
    int tot = O * NW;
    int idx = blockIdx.x * blockDim.x + threadIdx.x;
    if (idx >= tot) return;
    int wd = idx % NW, o = idx / NW;
    const float* row = w + (size_t)o * Kd + wd * 64;
    u64 s = 0, nz = 0;
    for (int c = 0; c < 64; ++c) {
        float v = row[c];
        if (v > 0.0f) s |= (1ull << c);
        if (v != 0.0f) nz |= (1ull << c);
    }
    u64* op = wp + (size_t)o * 2 * NW + 2 * wd;
    op[0] = s; op[1] = nz;
}

// ---- conv2 (binary, K=5, NW=1) + maxpool2x2, LDS-staged, 8 batches/block ----
// in p1 [512][225][2] u64, w [192][25][2], out [512][192][36]
__global__ __launch_bounds__(320)
void k_conv2(const u64* __restrict__ in, const u64* __restrict__ w,
             float* __restrict__ out) {
    __shared__ ulonglong2 st[8 * 17 * 17];
    const int co = blockIdx.x, b0 = blockIdx.y * 8, t = threadIdx.x;
    for (int i = t; i < 8 * 17 * 17; i += 320) { st[i].x = 0; st[i].y = 0; }
    __syncthreads();
    const ulonglong2* gin = (const ulonglong2*)in;
    for (int i = t; i < 8 * 225; i += 320) {
        int bb = i / 225, j = i - bb * 225;
        int yy = j / 15, xx = j - yy * 15;
        st[(bb * 17 + yy + 1) * 17 + xx + 1] = gin[(size_t)(b0 + bb) * 225 + j];
    }
    __syncthreads();
    if (t >= 288) return;
    const int bb = t / 36, r = t - bb * 36;
    const int py = r / 6, px = r - py * 6;
    const u64* wb = w + co * 50;
    int acc0 = 0, acc1 = 0, acc2 = 0, acc3 = 0;
    #pragma unroll
    for (int yy6 = 0; yy6 < 6; ++yy6) {
        const ulonglong2* rp = &st[(bb * 17 + py * 2 + yy6) * 17 + px * 2];
        ulonglong2 v[6];
        #pragma unroll
        for (int k = 0; k < 6; ++k) v[k] = rp[k];
        #pragma unroll
        for (int dy = 0; dy < 2; ++dy) {
            const int ky = yy6 - dy;
            if (ky < 0 || ky > 4) continue;
            #pragma unroll
            for (int kx = 0; kx < 5; ++kx) {
                const u64 wsg = wb[(ky * 5 + kx) * 2];
                const u64 wnz = wb[(ky * 5 + kx) * 2 + 1];
                if (dy == 0) {
                    acc0 += dotpack(v[kx].x,     v[kx].y,     wsg, wnz);
                    acc1 += dotpack(v[kx + 1].x, v[kx + 1].y, wsg, wnz);
                } else {
                    acc2 += dotpack(v[kx].x,     v[kx].y,     wsg, wnz);
                    acc3 += dotpack(v[kx + 1].x, v[kx + 1].y, wsg, wnz);
                }
            }
        }
    }
    int best = max(max(acc0, acc1), max(acc2, acc3));
    out[((size_t)(b0 + bb) * 192 + co) * 36 + r] = (float)best;
}

// ---- generic 3x3 pad-1 binary conv on 6x6, LDS-staged (conv3/4/5 raw) ----
// in [512][36][2*NW] u64, w [Cout][9][2*NW], out [512][Cout][36]
template<int NW, int BG, int NT>
__global__ __launch_bounds__(NT)
void k_convbin3(const u64* __restrict__ in, const u64* __restrict__ w,
                float* __restrict__ out, int Cout) {
    __shared__ ulonglong2 st[BG * 64 * NW];
    const int co = blockIdx.x, b0 = blockIdx.y * BG, t = threadIdx.x;
    for (int i = t; i < BG * 64 * NW; i += NT) { st[i].x = 0; st[i].y = 0; }
    __syncthreads();
    const ulonglong2* gin = (const ulonglong2*)in;
    for (int i = t; i < BG * 36 * NW; i += NT) {
        int wd = i % NW, j = (i / NW) % 36, bb = i / (36 * NW);
        int y = j / 6, x = j - y * 6;
        st[((bb * 8 + y + 1) * 8 + x + 1) * NW + wd] =
            gin[((size_t)(b0 + bb) * 36 + j) * NW + wd];
    }
    __syncthreads();
    if (t >= BG * 36) return;
    const int bb = t / 36, r = t - bb * 36;
    const int y = r / 6, x = r - y * 6;
    const u64* wb = w + (size_t)co * 9 * 2 * NW;
    int acc = 0;
    #pragma unroll
    for (int ky = 0; ky < 3; ++ky) {
        #pragma unroll
        for (int kx = 0; kx < 3; ++kx) {
            const ulonglong2* vp = &st[((bb * 8 + y + ky) * 8 + x + kx) * NW];
            const u64* wp = wb + (ky * 3 + kx) * 2 * NW;
            #pragma unroll
            for (int wd = 0; wd < NW; ++wd) {
                ulonglong2 a = vp[wd];
                acc += dotpack(a.x, a.y, wp[2 * wd], wp[2 * wd + 1]);
            }
        }
    }
    out[((size_t)(b0 + bb) * Cout + co) * 36 + r] = (float)acc;
}

// ---- maxpool 3x3 stride 2 on conv5 raw: [512][256][36] -> [512][256][4] ----
__global__ void k_pool5(const float* __restrict__ in, float* __restrict__ out) {
    int idx = blockIdx.x * 256 + threadIdx.x;
    if (idx >= 512 * 256 * 4) return;
    int px = idx & 1, py = (idx >> 1) & 1;
    int c = (idx >> 2) & 255, b = idx >> 10;
    const float* ip = in + ((size_t)b * 256 + c) * 36;
    float best = -3.4e38f;
    for (int dy = 0; dy < 3; ++dy)
        for (int dx = 0; dx < 3; ++dx)
            best = fmaxf(best, ip[(2 * py + dy) * 6 + (2 * px + dx)]);
    out[idx] = best;
}

// ---- BN stats stage A (2d) ----
__global__ void k_stats2d_part(const float* __restrict__ x, double* __restrict__ part,
                               int B, int C, int HW, int NB) {
    __shared__ double ss[256], sq[256];
    const int c = blockIdx.x, chunk = blockIdx.y;
    const int b0 = B * chunk / NB, b1 = B * (chunk + 1) / NB;
    const int n = (b1 - b0) * HW;
    double s = 0.0, q = 0.0;
    for (int i = threadIdx.x; i < n; i += blockDim.x) {
        int b = b0 + i / HW, j = i % HW;
        double v = (double)x[((size_t)b * C + c) * HW + j];
        s += v; q += v * v;
    }
    ss[threadIdx.x] = s; sq[threadIdx.x] = q;
    __syncthreads();
    for (int off = 128; off > 0; off >>= 1) {
        if ((int)threadIdx.x < off) {
            ss[threadIdx.x] += ss[threadIdx.x + off];
            sq[threadIdx.x] += sq[threadIdx.x + off];
        }
        __syncthreads();
    }
    if (threadIdx.x == 0) {
        part[((size_t)c * NB + chunk) * 2]     = ss[0];
        part[((size_t)c * NB + chunk) * 2 + 1] = sq[0];
    }
}

// ---- BN stats stage A (1d) ----
__global__ void k_stats1d_part(const float* __restrict__ x, double* __restrict__ part,
                               int B, int F, int NB) {
    int f = blockIdx.x * blockDim.x + threadIdx.x;
    if (f >= F) return;
    int chunk = blockIdx.y;
    int b0 = B * chunk / NB, b1 = B * (chunk + 1) / NB;
    double s = 0.0, q = 0.0;
    for (int r = b0; r < b1; ++r) {
        double v = (double)x[(size_t)r * F + f];
        s += v; q += v * v;
    }
    part[((size_t)f * NB + chunk) * 2]     = s;
    part[((size_t)f * NB + chunk) * 2 + 1] = q;
}

// ---- BN stats stage B ----
__global__ void k_stats_final(const double* __restrict__ part, const float* __restrict__ g,
                              float* __restrict__ mean, float* __restrict__ inva,
                              int C, int NB, long total) {
    int c = blockIdx.x * blockDim.x + threadIdx.x;
    if (c >= C) return;
    double s = 0.0, q = 0.0;
    for (int k = 0; k < NB; ++k) {
        s += part[((size_t)c * NB + k) * 2];
        q += part[((size_t)c * NB + k) * 2 + 1];
    }
    double m = s / (double)total;
    double var = q / (double)total - m * m;
    mean[c] = (float)m;
    inva[c] = g[c] * (float)(1.0 / sqrt(var + 1e-5));
}

// ---- BN apply + sign + pack (2d, channel-packed) ----
__global__ void k_bnpack2d(const float* __restrict__ x, const float* __restrict__ m,
                           const float* __restrict__ a, const float* __restrict__ bt,
                           u64* __restrict__ p, int B, int C, int HW) {
    int NW = (C + 63) >> 6;
    int tot = B * HW * NW;
    int idx = blockIdx.x * blockDim.x + threadIdx.x;
    if (idx >= tot) return;
    int wd = idx % NW, t = idx / NW;
    int j = t % HW, b = t / HW;
    u64 s = 0, nz = 0;
    for (int c0 = 0; c0 < 64; ++c0) {
        int c = wd * 64 + c0;
        if (c >= C) break;
        float v = (x[((size_t)b * C + c) * HW + j] - m[c]) * a[c] + bt[c];
        if (v > 0.0f) s |= (1ull << c0);
        if (v != 0.0f) nz |= (1ull << c0);
    }
    u64* o = p + ((size_t)b * HW + j) * 2 * NW + 2 * wd;
    o[0] = s; o[1] = nz;
}

// ---- conv5 pooled output: BN + sign + flatten-pack: [512][256][4] -> [512][2*16] ----
__global__ void k_bnpack_flat(const float* __restrict__ x, const float* __restrict__ m,
                              const float* __restrict__ a, const float* __restrict__ bt,
                              u64* __restrict__ p, int B) {
    int idx = blockIdx.x * blockDim.x + threadIdx.x;
    if (idx >= B * 16) return;
    int wd = idx % 16, b = idx / 16;
    u64 s = 0, nz = 0;
    for (int k = 0; k < 64; ++k) {
        int f = wd * 64 + k;
        int c = f >> 2, j = f & 3;
        float v = (x[((size_t)b * 256 + c) * 4 + j] - m[c]) * a[c] + bt[c];
        if (v > 0.0f) s |= (1ull << k);
        if (v != 0.0f) nz |= (1ull << k);
    }
    u64* o = p + (size_t)b * 32 + 2 * wd;
    o[0] = s; o[1] = nz;
}

// ---- BN apply + sign + pack (1d) ----
__global__ void k_bnpack1d(const float* __restrict__ x, const float* __restrict__ m,
                           const float* __restrict__ a, const float* __restrict__ bt,
                           u64* __restrict__ p, int B, int F) {
    int NW = F >> 6;
    int idx = blockIdx.x * blockDim.x + threadIdx.x;
    if (idx >= B * NW) return;
    int wd = idx % NW, b = idx / NW;
    const float* row = x + (size_t)b * F + wd * 64;
    u64 s = 0, nz = 0;
    for (int c = 0; c < 64; ++c) {
        int f = wd * 64 + c;
        float v = (row[c] - m[f]) * a[f] + bt[f];
        if (v > 0.0f) s |= (1ull << c);
        if (v != 0.0f) nz |= (1ull << c);
    }
    u64* o = p + (size_t)b * 2 * NW + 2 * wd;
    o[0] = s; o[1] = nz;
}

// ---- binary FC, 16x16 LDS-tiled: A [B][2NW], W [O][2NW] -> C [B][O] ----
template<int NW>
__global__ __launch_bounds__(256)
void k_fcbin2(const u64* __restrict__ A, const u64* __restrict__ W,
              const float* __restrict__ bias, float* __restrict__ C, int O) {
    __shared__ u64 As[16][2 * NW + 2];
    __shared__ u64 Ws[16][2 * NW + 2];
    const int t = threadIdx.x;
    const int b0 = blockIdx.y * 16, o0 = blockIdx.x * 16;
    for (int i = t; i < 16 * 2 * NW; i += 256) {
        int rr = i / (2 * NW), cc = i % (2 * NW);
        As[rr][cc] = A[(size_t)(b0 + rr) * 2 * NW + cc];
        int o = o0 + rr;
        Ws[rr][cc] = (o < O) ? W[(size_t)o * 2 * NW + cc] : 0ull;
    }
    __syncthreads();
    const int tx = t % 16, ty = t / 16;
    int acc = 0;
    #pragma unroll
    for (int wd = 0; wd < NW; ++wd) {
        ulonglong2 a = *(const ulonglong2*)&As[ty][2 * wd];
        ulonglong2 w = *(const ulonglong2*)&Ws[tx][2 * wd];
        acc += dotpack(a.x, a.y, w.x, w.y);
    }
    int o = o0 + tx;
    if (o < O)
        C[(size_t)(b0 + ty) * O + o] = (float)acc + (bias ? bias[o] : 0.0f);
}

// ---------------------------------------------------------------------------

static inline int cdiv(long a, int b) { return (int)((a + b - 1) / b); }

extern "C" void kernel_launch(void* const* d_in, const int* in_sizes, int n_in,
                              void* d_out, int out_size, void* d_ws, size_t ws_size,
                              hipStream_t stream) {
    const float* x   = (const float*)d_in[0];
    const float* w1  = (const float*)d_in[1];
    const float* g1  = (const float*)d_in[2];
    const float* b1  = (const float*)d_in[3];
    const float* w2  = (const float*)d_in[4];
    const float* g2  = (const float*)d_in[5];
    const float* b2  = (const float*)d_in[6];
    const float* w3  = (const float*)d_in[7];
    const float* g3  = (const float*)d_in[8];
    const float* b3  = (const float*)d_in[9];
    const float* w4  = (const float*)d_in[10];
    const float* g4  = (const float*)d_in[11];
    const float* b4  = (const float*)d_in[12];
    const float* w5  = (const float*)d_in[13];
    const float* g5  = (const float*)d_in[14];
    const float* b5  = (const float*)d_in[15];
    const float* wl1 = (const float*)d_in[16];
    const float* gl1 = (const float*)d_in[17];
    const float* bl1 = (const float*)d_in[18];
    const float* wl2 = (const float*)d_in[19];
    const float* gl2 = (const float*)d_in[20];
    const float* bl2 = (const float*)d_in[21];
    const float* wl3 = (const float*)d_in[22];
    const float* bl3 = (const float*)d_in[23];
    float* out = (float*)d_out;
    (void)in_sizes; (void)n_in; (void)out_size; (void)ws_size;

    char* base = (char*)d_ws;
    size_t off = 0;
    auto alloc = [&](size_t bytes) {
        char* p = base + off;
        off += (bytes + 15) & ~(size_t)15;
        return (void*)p;
    };
    float* R1   = (float*)alloc(7372800 * 4);  // conv1 / conv3 / conv5raw / fc2
    float* R2   = (float*)alloc(4718592 * 4);  // conv2 / conv4 / fc1
    float* R3   = (float*)alloc(524288 * 4);   // conv5 pooled [512,256,4]
    float* w1s  = (float*)alloc(4800 * 4);
    u64* p1  = (u64*)alloc(230400 * 8);   // [512][225][2]
    u64* p2  = (u64*)alloc(110592 * 8);   // [512][36][6]
    u64* p3  = (u64*)alloc(221184 * 8);   // [512][36][12]
    u64* p4  = (u64*)alloc(147456 * 8);   // [512][36][8]
    u64* p5  = (u64*)alloc(16384 * 8);    // [512][32]
    u64* pf1 = (u64*)alloc(65536 * 8);    // [512][128]
    u64* pf2 = (u64*)alloc(32768 * 8);    // [512][64]
    u64* w2p  = (u64*)alloc(9600 * 8);
    u64* w3p  = (u64*)alloc(20736 * 8);
    u64* w4p  = (u64*)alloc(27648 * 8);
    u64* w5p  = (u64*)alloc(18432 * 8);
    u64* wl1p = (u64*)alloc(131072 * 8);
    u64* wl2p = (u64*)alloc(262144 * 8);
    u64* wl3p = (u64*)alloc(640 * 8);
    double* part = (double*)alloc(4096 * 16 * 2 * 8);
    float* stats = (float*)alloc(7 * 2 * 4096 * 4);
    float* m_[7]; float* a_[7];
    for (int l = 0; l < 7; ++l) { m_[l] = stats + (size_t)l * 8192; a_[l] = m_[l] + 4096; }
    const int NB = 16;

    // ---- weight prep ----
    k_sign<<<32, 256, 0, stream>>>(w1, w1s, 4800);
    k_packw_conv<<<cdiv(4800, 256),  256, 0, stream>>>(w2, w2p, 192, 64, 25);
    k_packw_conv<<<cdiv(10368, 256), 256, 0, stream>>>(w3, w3p, 384, 192, 9);
    k_packw_conv<<<cdiv(13824, 256), 256, 0, stream>>>(w4, w4p, 256, 384, 9);
    k_packw_conv<<<cdiv(9216, 256),  256, 0, stream>>>(w5, w5p, 256, 256, 9);
    k_packw_fc<<<cdiv(65536, 256),  256, 0, stream>>>(wl1, wl1p, 4096, 1024);
    k_packw_fc<<<cdiv(131072, 256), 256, 0, stream>>>(wl2, wl2p, 2048, 4096);
    k_packw_fc<<<cdiv(320, 256),    256, 0, stream>>>(wl3, wl3p, 10, 2048);

    // ---- conv1 + pool -> R1 [512,64,225]; bn1; pack -> p1 ----
    k_conv1<<<dim3(8, 512), 256, 0, stream>>>(x, w1s, R1);
    k_stats2d_part<<<dim3(64, NB), 256, 0, stream>>>(R1, part, 512, 64, 225, NB);
    k_stats_final<<<1, 64, 0, stream>>>(part, g1, m_[0], a_[0], 64, NB, (long)512 * 225);
    k_bnpack2d<<<cdiv((long)512 * 225, 256), 256, 0, stream>>>(R1, m_[0], a_[0], b1, p1, 512, 64, 225);

    // ---- conv2 + pool -> R2 [512,192,36]; bn2; pack -> p2 ----
    k_conv2<<<dim3(192, 64), 320, 0, stream>>>(p1, w2p, R2);
    k_stats2d_part<<<dim3(192, NB), 256, 0, stream>>>(R2, part, 512, 192, 36, NB);
    k_stats_final<<<1, 192, 0, stream>>>(part, g2, m_[1], a_[1], 192, NB, (long)512 * 36);
    k_bnpack2d<<<cdiv((long)512 * 36 * 3, 256), 256, 0, stream>>>(R2, m_[1], a_[1], b2, p2, 512, 192, 36);

    // ---- conv3 -> R1 [512,384,36]; bn3; pack -> p3 ----
    k_convbin3<3, 8, 320><<<dim3(384, 64), 320, 0, stream>>>(p2, w3p, R1, 384);
    k_stats2d_part<<<dim3(384, NB), 256, 0, stream>>>(R1, part, 512, 384, 36, NB);
    k_stats_final<<<2, 192, 0, stream>>>(part, g3, m_[2], a_[2], 384, NB, (long)512 * 36);
    k_bnpack2d<<<cdiv((long)512 * 36 * 6, 256), 256, 0, stream>>>(R1, m_[2], a_[2], b3, p3, 512, 384, 36);

    // ---- conv4 -> R2 [512,256,36]; bn4; pack -> p4 ----
    k_convbin3<6, 4, 192><<<dim3(256, 128), 192, 0, stream>>>(p3, w4p, R2, 256);
    k_stats2d_part<<<dim3(256, NB), 256, 0, stream>>>(R2, part, 512, 256, 36, NB);
    k_stats_final<<<1, 256, 0, stream>>>(part, g4, m_[3], a_[3], 256, NB, (long)512 * 36);
    k_bnpack2d<<<cdiv((long)512 * 36 * 4, 256), 256, 0, stream>>>(R2, m_[3], a_[3], b4, p4, 512, 256, 36);

    // ---- conv5 raw -> R1 [512,256,36]; pool -> R3; bn5; flat-pack -> p5 ----
    k_convbin3<4, 8, 320><<<dim3(256, 64), 320, 0, stream>>>(p4, w5p, R1, 256);
    k_pool5<<<cdiv(512 * 256 * 4, 256), 256, 0, stream>>>(R1, R3);
    k_stats2d_part<<<dim3(256, NB), 256, 0, stream>>>(R3, part, 512, 256, 4, NB);
    k_stats_final<<<1, 256, 0, stream>>>(part, g5, m_[4], a_[4], 256, NB, (long)512 * 4);
    k_bnpack_flat<<<cdiv(512 * 16, 256), 256, 0, stream>>>(R3, m_[4], a_[4], b5, p5, 512);

    // ---- fc1 -> R2 [512,4096]; bn; pack -> pf1 ----
    k_fcbin2<16><<<dim3(256, 32), 256, 0, stream>>>(p5, wl1p, nullptr, R2, 4096);
    k_stats1d_part<<<dim3(16, NB), 256, 0, stream>>>(R2, part, 512, 4096, NB);
    k_stats_final<<<16, 256, 0, stream>>>(part, gl1, m_[5], a_[5], 4096, NB, 512);
    k_bnpack1d<<<cdiv(512 * 64, 256), 256, 0, stream>>>(R2, m_[5], a_[5], bl1, pf1, 512, 4096);

    // ---- fc2 -> R1 [512,2048]; bn; pack -> pf2 ----
    k_fcbin2<64><<<dim3(128, 32), 256, 0, stream>>>(pf1, wl2p, nullptr, R1, 2048);
    k_stats1d_part<<<dim3(8, NB), 256, 0, stream>>>(R1, part, 512, 2048, NB);
    k_stats_final<<<8, 256, 0, stream>>>(part, gl2, m_[6], a_[6], 2048, NB, 512);
    k_bnpack1d<<<cdiv(512 * 32, 256), 256, 0, stream>>>(R1, m_[6], a_[6], bl2, pf2, 512, 2048);

    // ---- fc3 + bias -> out [512,10] ----
    k_fcbin2<32><<<dim3(1, 32), 256, 0, stream>>>(pf2, wl3p, bl3, out, 10);
}

// Round 5
// 964.232 us; speedup vs baseline: 42.1379x; 1.2238x over previous
//
#include <hip/hip_runtime.h>
#include <math.h>

// ---------------------------------------------------------------------------
// BinAlexNet forward — round 5 (= round 4 + prep-launch-size fix).
//   - split popcount accumulators (aV/aD), fold once per window
//   - BN stats fused into conv/FC epilogues (exact integer block sums,
//     deterministic per-(channel,chunk) slots, no atomics)
//   - conv5 pools 3x3/2 in-LDS and emits pooled output directly
//   - single merged weight-prep kernel (PREP_TOTAL = 239936 — was launched
//     with 235936 in round 4, leaving fc3 weights as workspace poison)
// ---------------------------------------------------------------------------

typedef unsigned long long u64;

__device__ __forceinline__ float sgn(float x) {
    return (float)((x > 0.0f) - (x < 0.0f));
}

// ---------------------------------------------------------------------------
// merged weight prep: sign(w1) + pack conv w2..w5 + pack fc wl1..wl3
// ---------------------------------------------------------------------------
__device__ void pack_conv_one(int idx, const float* __restrict__ w,
                              u64* __restrict__ wp, int Cout, int Cin, int KK) {
    int NW = (Cin + 63) >> 6;
    int wd = idx % NW, t = idx / NW;
    int tap = t % KK, co = t / KK;
    u64 s = 0, nz = 0;
    for (int c = 0; c < 64; ++c) {
        int ci = wd * 64 + c;
        if (ci >= Cin) break;
        float v = w[((size_t)co * Cin + ci) * KK + tap];
        if (v > 0.0f) s |= (1ull << c);
        if (v != 0.0f) nz |= (1ull << c);
    }
    u64* o = wp + ((size_t)co * KK + tap) * 2 * NW + 2 * wd;
    o[0] = s; o[1] = nz;
}

__device__ void pack_fc_one(int idx, const float* __restrict__ w,
                            u64* __restrict__ wp, int Kd) {
    int NW = Kd >> 6;
    int wd = idx % NW, o = idx / NW;
    const float* row = w + (size_t)o * Kd + wd * 64;
    u64 s = 0, nz = 0;
    for (int c = 0; c < 64; ++c) {
        float v = row[c];
        if (v > 0.0f) s |= (1ull << c);
        if (v != 0.0f) nz |= (1ull << c);
    }
    u64* op = wp + (size_t)o * 2 * NW + 2 * wd;
    op[0] = s; op[1] = nz;
}

// segment sizes (device + host must agree)
#define PN0 4800     // sign w1
#define PN1 4800     // w2 pack: 192*25*1
#define PN2 10368    // w3: 384*9*3
#define PN3 13824    // w4: 256*9*6
#define PN4 9216     // w5: 256*9*4
#define PN5 65536    // wl1: 4096*16
#define PN6 131072   // wl2: 2048*64
#define PN7 320      // wl3: 10*32
#define PREP_TOTAL (PN0+PN1+PN2+PN3+PN4+PN5+PN6+PN7)   // 239936

__global__ void k_prep(const float* w1, float* w1s,
                       const float* w2, u64* w2p,
                       const float* w3, u64* w3p,
                       const float* w4, u64* w4p,
                       const float* w5, u64* w5p,
                       const float* wl1, u64* wl1p,
                       const float* wl2, u64* wl2p,
                       const float* wl3, u64* wl3p) {
    int idx = blockIdx.x * blockDim.x + threadIdx.x;
    int r = idx;
    if (r < PN0) { w1s[r] = sgn(w1[r]); return; } r -= PN0;
    if (r < PN1) { pack_conv_one(r, w2, w2p, 192, 64, 25); return; } r -= PN1;
    if (r < PN2) { pack_conv_one(r, w3, w3p, 384, 192, 9); return; } r -= PN2;
    if (r < PN3) { pack_conv_one(r, w4, w4p, 256, 384, 9); return; } r -= PN3;
    if (r < PN4) { pack_conv_one(r, w5, w5p, 256, 256, 9); return; } r -= PN4;
    if (r < PN5) { pack_fc_one(r, wl1, wl1p, 1024); return; } r -= PN5;
    if (r < PN6) { pack_fc_one(r, wl2, wl2p, 4096); return; } r -= PN6;
    if (r < PN7) { pack_fc_one(r, wl3, wl3p, 2048); return; }
}

// ---------------------------------------------------------------------------
// conv1: real input, signed weights, fused maxpool2x2 + per-(c,b) stats.
// grid (8 co-groups, 512 b), 256 thr. out [512][64][225], part[(c*512+b)*2]
// fma order per window identical to round 3 (bit-identical fp32 sums).
// ---------------------------------------------------------------------------
__global__ __launch_bounds__(256)
void k_conv1(const float* __restrict__ x, const float* __restrict__ w1s,
             float* __restrict__ out, double* __restrict__ part) {
    __shared__ float sx[3 * 34 * 34];
    __shared__ double sS[256];
    __shared__ double sQ[256];
    const int b = blockIdx.y, cg = blockIdx.x, t = threadIdx.x;
    for (int i = t; i < 3 * 34 * 34; i += 256) sx[i] = 0.0f;
    __syncthreads();
    for (int i = t; i < 3072; i += 256) {
        int ch = i >> 10, rem = i & 1023, yy = rem >> 5, xx = rem & 31;
        sx[(ch * 34 + yy + 1) * 34 + xx + 1] = x[(size_t)b * 3072 + i];
    }
    __syncthreads();
    const bool act = t < 225;
    const int py = act ? t / 15 : 0, px = act ? t % 15 : 0;
    float a0[8], a1[8], a2[8], a3[8];
    #pragma unroll
    for (int c = 0; c < 8; ++c) { a0[c] = a1[c] = a2[c] = a3[c] = 0.f; }
    #pragma unroll 1
    for (int ch = 0; ch < 3; ++ch) {
        const float* wc = w1s + (size_t)(cg * 8) * 75 + ch * 25;
        #pragma unroll 1
        for (int yy6 = 0; yy6 < 6; ++yy6) {
            const float2* rp = (const float2*)&sx[(ch * 34 + py * 2 + yy6) * 34 + px * 2];
            float2 ra = rp[0], rb = rp[1], rc = rp[2];
            float r[6] = {ra.x, ra.y, rb.x, rb.y, rc.x, rc.y};
            if (yy6 <= 4) {   // dy=0 windows, ky=yy6
                #pragma unroll
                for (int kx = 0; kx < 5; ++kx)
                    #pragma unroll
                    for (int cc = 0; cc < 8; ++cc) {
                        float wv = wc[cc * 75 + yy6 * 5 + kx];
                        a0[cc] = fmaf(r[kx],     wv, a0[cc]);
                        a1[cc] = fmaf(r[kx + 1], wv, a1[cc]);
                    }
            }
            if (yy6 >= 1) {   // dy=1 windows, ky=yy6-1
                #pragma unroll
                for (int kx = 0; kx < 5; ++kx)
                    #pragma unroll
                    for (int cc = 0; cc < 8; ++cc) {
                        float wv = wc[cc * 75 + (yy6 - 1) * 5 + kx];
                        a2[cc] = fmaf(r[kx],     wv, a2[cc]);
                        a3[cc] = fmaf(r[kx + 1], wv, a3[cc]);
                    }
            }
        }
    }
    #pragma unroll
    for (int cc = 0; cc < 8; ++cc) {
        float best = 0.f;
        if (act) {
            best = fmaxf(fmaxf(a0[cc], a1[cc]), fmaxf(a2[cc], a3[cc]));
            out[((size_t)b * 64 + cg * 8 + cc) * 225 + t] = best;
        }
        double v = act ? (double)best : 0.0;
        sS[t] = v; sQ[t] = v * v;
        __syncthreads();
        for (int o2 = 128; o2 > 0; o2 >>= 1) {
            if (t < o2) { sS[t] += sS[t + o2]; sQ[t] += sQ[t + o2]; }
            __syncthreads();
        }
        if (t == 0) {
            part[((size_t)(cg * 8 + cc) * 512 + b) * 2]     = sS[0];
            part[((size_t)(cg * 8 + cc) * 512 + b) * 2 + 1] = sQ[0];
        }
        __syncthreads();
    }
}

// ---------------------------------------------------------------------------
// conv2 (binary K=5, NW=1) + maxpool2x2 + fused stats.
// grid (192, 64), 320 thr. part[(co*64+bg)*2]
// ---------------------------------------------------------------------------
#define TAP(vv, WS, WN, AV, AD) { u64 _val = (vv).y & (WN); \
    u64 _df = ((vv).x ^ (WS)) & _val; \
    AV += (int)__popcll(_val); AD += (int)__popcll(_df); }

__global__ __launch_bounds__(320)
void k_conv2(const u64* __restrict__ in, const u64* __restrict__ w,
             float* __restrict__ out, double* __restrict__ part) {
    __shared__ ulonglong2 st[8 * 17 * 17];
    const int co = blockIdx.x, bg = blockIdx.y, b0 = bg * 8, t = threadIdx.x;
    for (int i = t; i < 8 * 17 * 17; i += 320) { st[i].x = 0; st[i].y = 0; }
    __syncthreads();
    const ulonglong2* gin = (const ulonglong2*)in;
    for (int i = t; i < 8 * 225; i += 320) {
        int bb = i / 225, j = i - bb * 225;
        int yy = j / 15, xx = j - yy * 15;
        st[(bb * 17 + yy + 1) * 17 + xx + 1] = gin[(size_t)(b0 + bb) * 225 + j];
    }
    __syncthreads();
    const bool act = t < 288;
    const int bb = act ? t / 36 : 0, r = act ? t - (t / 36) * 36 : 0;
    const int py = r / 6, px = r - py * 6;
    const u64* wb = w + co * 50;
    int aV0 = 0, aD0 = 0, aV1 = 0, aD1 = 0, aV2 = 0, aD2 = 0, aV3 = 0, aD3 = 0;
    if (act) {
        #pragma unroll 1
        for (int yy6 = 0; yy6 < 6; ++yy6) {
            const ulonglong2* rp = &st[(bb * 17 + py * 2 + yy6) * 17 + px * 2];
            ulonglong2 V[6];
            #pragma unroll
            for (int k = 0; k < 6; ++k) V[k] = rp[k];
            if (yy6 <= 4) {   // ky = yy6
                const u64* wr_ = wb + (yy6 * 5) * 2;
                #pragma unroll
                for (int kx = 0; kx < 5; ++kx) {
                    u64 ws_ = wr_[kx * 2], wn_ = wr_[kx * 2 + 1];
                    TAP(V[kx],     ws_, wn_, aV0, aD0);
                    TAP(V[kx + 1], ws_, wn_, aV1, aD1);
                }
            }
            if (yy6 >= 1) {   // ky = yy6-1
                const u64* wr_ = wb + ((yy6 - 1) * 5) * 2;
                #pragma unroll
                for (int kx = 0; kx < 5; ++kx) {
                    u64 ws_ = wr_[kx * 2], wn_ = wr_[kx * 2 + 1];
                    TAP(V[kx],     ws_, wn_, aV2, aD2);
                    TAP(V[kx + 1], ws_, wn_, aV3, aD3);
                }
            }
        }
    }
    int best = 0;
    if (act) {
        int s0 = aV0 - 2 * aD0, s1 = aV1 - 2 * aD1;
        int s2 = aV2 - 2 * aD2, s3 = aV3 - 2 * aD3;
        best = max(max(s0, s1), max(s2, s3));
        out[((size_t)(b0 + bb) * 192 + co) * 36 + r] = (float)best;
    }
    __syncthreads();
    int* si = (int*)st;
    long long* sq = (long long*)(si + 512);
    si[t] = act ? best : 0;
    sq[t] = act ? (long long)best * best : 0;
    __syncthreads();
    if (t < 64) { si[t] += si[t + 256]; sq[t] += sq[t + 256]; }
    __syncthreads();
    for (int o2 = 128; o2 > 0; o2 >>= 1) {
        if (t < o2) { si[t] += si[t + o2]; sq[t] += sq[t + o2]; }
        __syncthreads();
    }
    if (t == 0) {
        part[((size_t)co * 64 + bg) * 2]     = (double)si[0];
        part[((size_t)co * 64 + bg) * 2 + 1] = (double)sq[0];
    }
}

// ---------------------------------------------------------------------------
// 3x3 pad-1 binary conv on 6x6 (conv3/conv4), K-chunked LDS, fused stats.
// rows stride 9 (bank spread). grid (Cout, 64), 320 thr, BG=8.
// ---------------------------------------------------------------------------
template<int NW, int NWC>
__global__ __launch_bounds__(320)
void k_convbin3(const u64* __restrict__ in, const u64* __restrict__ w,
                float* __restrict__ out, double* __restrict__ part, int Cout) {
    __shared__ ulonglong2 st[8 * 72 * NWC];
    const int co = blockIdx.x, bg = blockIdx.y, b0 = bg * 8, t = threadIdx.x;
    const bool act = t < 288;
    const int bb = act ? t / 36 : 0, r = act ? t - (t / 36) * 36 : 0;
    const int y = r / 6, x0 = r - y * 6;
    const u64* wb = w + (size_t)co * 9 * 2 * NW;
    const ulonglong2* gin = (const ulonglong2*)in;
    int aV = 0, aD = 0;
    #pragma unroll 1
    for (int c0 = 0; c0 < NW; c0 += NWC) {
        __syncthreads();
        for (int i = t; i < 8 * 72 * NWC; i += 320) { st[i].x = 0; st[i].y = 0; }
        __syncthreads();
        for (int i = t; i < 8 * 36 * NWC; i += 320) {
            int wd = i % NWC, j = (i / NWC) % 36, bb2 = i / (36 * NWC);
            int yy = j / 6, xx = j - yy * 6;
            st[((bb2 * 8 + yy + 1) * 9 + xx + 1) * NWC + wd] =
                gin[((size_t)(b0 + bb2) * 36 + j) * NW + c0 + wd];
        }
        __syncthreads();
        if (act) {
            #pragma unroll
            for (int ky = 0; ky < 3; ++ky)
                #pragma unroll
                for (int kx = 0; kx < 3; ++kx) {
                    const ulonglong2* vp = &st[((bb * 8 + y + ky) * 9 + x0 + kx) * NWC];
                    const u64* wp = wb + (ky * 3 + kx) * 2 * NW + 2 * c0;
                    #pragma unroll
                    for (int wd = 0; wd < NWC; ++wd) {
                        ulonglong2 a = vp[wd];
                        u64 val = a.y & wp[2 * wd + 1];
                        u64 df  = (a.x ^ wp[2 * wd]) & val;
                        aV += (int)__popcll(val); aD += (int)__popcll(df);
                    }
                }
        }
    }
    int s = aV - 2 * aD;
    if (act) out[((size_t)(b0 + bb) * Cout + co) * 36 + r] = (float)s;
    __syncthreads();
    int* si = (int*)st;
    long long* sq = (long long*)(si + 512);
    si[t] = act ? s : 0;
    sq[t] = act ? (long long)s * s : 0;
    __syncthreads();
    if (t < 64) { si[t] += si[t + 256]; sq[t] += sq[t + 256]; }
    __syncthreads();
    for (int o2 = 128; o2 > 0; o2 >>= 1) {
        if (t < o2) { si[t] += si[t + o2]; sq[t] += sq[t + o2]; }
        __syncthreads();
    }
    if (t == 0) {
        part[((size_t)co * 64 + bg) * 2]     = (double)si[0];
        part[((size_t)co * 64 + bg) * 2 + 1] = (double)sq[0];
    }
}

// ---------------------------------------------------------------------------
// conv5 (NW=4, K-chunk 2) + in-LDS maxpool3x3/2 + fused stats on POOLED vals.
// grid (256, 64), 320 thr. outp [512][256][4], part[(co*64+bg)*2]
// ---------------------------------------------------------------------------
__global__ __launch_bounds__(320)
void k_conv5(const u64* __restrict__ in, const u64* __restrict__ w,
             float* __restrict__ outp, double* __restrict__ part) {
    __shared__ ulonglong2 st[8 * 72 * 2];
    __shared__ int sacc[8 * 36];
    const int co = blockIdx.x, bg = blockIdx.y, b0 = bg * 8, t = threadIdx.x;
    const bool act = t < 288;
    const int bb = act ? t / 36 : 0, r = act ? t - (t / 36) * 36 : 0;
    const int y = r / 6, x0 = r - y * 6;
    const u64* wb = w + (size_t)co * 9 * 2 * 4;
    const ulonglong2* gin = (const ulonglong2*)in;
    int aV = 0, aD = 0;
    #pragma unroll 1
    for (int c0 = 0; c0 < 4; c0 += 2) {
        __syncthreads();
        for (int i = t; i < 8 * 72 * 2; i += 320) { st[i].x = 0; st[i].y = 0; }
        __syncthreads();
        for (int i = t; i < 8 * 36 * 2; i += 320) {
            int wd = i % 2, j = (i / 2) % 36, bb2 = i / 72;
            int yy = j / 6, xx = j - yy * 6;
            st[((bb2 * 8 + yy + 1) * 9 + xx + 1) * 2 + wd] =
                gin[((size_t)(b0 + bb2) * 36 + j) * 4 + c0 + wd];
        }
        __syncthreads();
        if (act) {
            #pragma unroll
            for (int ky = 0; ky < 3; ++ky)
                #pragma unroll
                for (int kx = 0; kx < 3; ++kx) {
                    const ulonglong2* vp = &st[((bb * 8 + y + ky) * 9 + x0 + kx) * 2];
                    const u64* wp = wb + (ky * 3 + kx) * 8 + 2 * c0;
                    #pragma unroll
                    for (int wd = 0; wd < 2; ++wd) {
                        ulonglong2 a = vp[wd];
                        u64 val = a.y & wp[2 * wd + 1];
                        u64 df  = (a.x ^ wp[2 * wd]) & val;
                        aV += (int)__popcll(val); aD += (int)__popcll(df);
                    }
                }
        }
    }
    if (act) sacc[bb * 36 + r] = aV - 2 * aD;
    __syncthreads();
    int pooled = 0;
    const bool pact = t < 32;
    if (pact) {
        int bb2 = t / 4, wi = t % 4, py = (wi >> 1) * 2, px = (wi & 1) * 2;
        int best = -1000000;
        #pragma unroll
        for (int dy = 0; dy < 3; ++dy)
            #pragma unroll
            for (int dx = 0; dx < 3; ++dx)
                best = max(best, sacc[bb2 * 36 + (py + dy) * 6 + (px + dx)]);
        pooled = best;
        outp[((size_t)(b0 + bb2) * 256 + co) * 4 + wi] = (float)pooled;
    }
    __syncthreads();
    int* si = (int*)st;
    long long* sq = (long long*)(si + 512);
    si[t] = pact ? pooled : 0;
    sq[t] = pact ? (long long)pooled * pooled : 0;
    __syncthreads();
    if (t < 64) { si[t] += si[t + 256]; sq[t] += sq[t + 256]; }
    __syncthreads();
    for (int o2 = 128; o2 > 0; o2 >>= 1) {
        if (t < o2) { si[t] += si[t + o2]; sq[t] += sq[t + o2]; }
        __syncthreads();
    }
    if (t == 0) {
        part[((size_t)co * 64 + bg) * 2]     = (double)si[0];
        part[((size_t)co * 64 + bg) * 2 + 1] = (double)sq[0];
    }
}

// ---------------------------------------------------------------------------
// BN stats finalize: one block per channel, tree over NB chunks.
// ---------------------------------------------------------------------------
__global__ void k_stats_final(const double* __restrict__ part, const float* __restrict__ g,
                              float* __restrict__ mean, float* __restrict__ inva,
                              int NB, long total) {
    __shared__ double sS[64], sQ[64];
    const int c = blockIdx.x, t = threadIdx.x;
    double s = 0.0, q = 0.0;
    for (int k = t; k < NB; k += 64) {
        s += part[((size_t)c * NB + k) * 2];
        q += part[((size_t)c * NB + k) * 2 + 1];
    }
    sS[t] = s; sQ[t] = q;
    __syncthreads();
    for (int o = 32; o > 0; o >>= 1) {
        if (t < o) { sS[t] += sS[t + o]; sQ[t] += sQ[t + o]; }
        __syncthreads();
    }
    if (t == 0) {
        double m = sS[0] / (double)total;
        double var = sQ[0] / (double)total - m * m;
        mean[c] = (float)m;
        inva[c] = g[c] * (float)(1.0 / sqrt(var + 1e-5));
    }
}

// ---- BN apply + sign + pack (2d, channel-packed) ----
__global__ void k_bnpack2d(const float* __restrict__ x, const float* __restrict__ m,
                           const float* __restrict__ a, const float* __restrict__ bt,
                           u64* __restrict__ p, int B, int C, int HW) {
    int NW = (C + 63) >> 6;
    int tot = B * HW * NW;
    int idx = blockIdx.x * blockDim.x + threadIdx.x;
    if (idx >= tot) return;
    int wd = idx % NW, t = idx / NW;
    int j = t % HW, b = t / HW;
    u64 s = 0, nz = 0;
    for (int c0 = 0; c0 < 64; ++c0) {
        int c = wd * 64 + c0;
        if (c >= C) break;
        float v = (x[((size_t)b * C + c) * HW + j] - m[c]) * a[c] + bt[c];
        if (v > 0.0f) s |= (1ull << c0);
        if (v != 0.0f) nz |= (1ull << c0);
    }
    u64* o = p + ((size_t)b * HW + j) * 2 * NW + 2 * wd;
    o[0] = s; o[1] = nz;
}

// ---- conv5 pooled output: BN + sign + flatten-pack ----
__global__ void k_bnpack_flat(const float* __restrict__ x, const float* __restrict__ m,
                              const float* __restrict__ a, const float* __restrict__ bt,
                              u64* __restrict__ p, int B) {
    int idx = blockIdx.x * blockDim.x + threadIdx.x;
    if (idx >= B * 16) return;
    int wd = idx % 16, b = idx / 16;
    u64 s = 0, nz = 0;
    for (int k = 0; k < 64; ++k) {
        int f = wd * 64 + k;
        int c = f >> 2, j = f & 3;
        float v = (x[((size_t)b * 256 + c) * 4 + j] - m[c]) * a[c] + bt[c];
        if (v > 0.0f) s |= (1ull << k);
        if (v != 0.0f) nz |= (1ull << k);
    }
    u64* o = p + (size_t)b * 32 + 2 * wd;
    o[0] = s; o[1] = nz;
}

// ---- BN apply + sign + pack (1d) ----
__global__ void k_bnpack1d(const float* __restrict__ x, const float* __restrict__ m,
                           const float* __restrict__ a, const float* __restrict__ bt,
                           u64* __restrict__ p, int B, int F) {
    int NW = F >> 6;
    int idx = blockIdx.x * blockDim.x + threadIdx.x;
    if (idx >= B * NW) return;
    int wd = idx % NW, b = idx / NW;
    const float* row = x + (size_t)b * F + wd * 64;
    u64 s = 0, nz = 0;
    for (int c = 0; c < 64; ++c) {
        int f = wd * 64 + c;
        float v = (row[c] - m[f]) * a[f] + bt[f];
        if (v > 0.0f) s |= (1ull << c);
        if (v != 0.0f) nz |= (1ull << c);
    }
    u64* o = p + (size_t)b * 2 * NW + 2 * wd;
    o[0] = s; o[1] = nz;
}

// ---------------------------------------------------------------------------
// binary FC, 16x16 LDS-tiled, split accumulators, optional fused stats.
// grid (O/16, B/16), 256 thr. part[(o*nbc + blockIdx.y)*2] if part != null.
// ---------------------------------------------------------------------------
template<int NW>
__global__ __launch_bounds__(256)
void k_fcbin2(const u64* __restrict__ A, const u64* __restrict__ W,
              const float* __restrict__ bias, float* __restrict__ C, int O,
              double* __restrict__ part, int nbc) {
    __shared__ u64 As[16][2 * NW + 2];
    __shared__ u64 Ws[16][2 * NW + 2];
    __shared__ int sacc[16][16];
    const int t = threadIdx.x;
    const int b0 = blockIdx.y * 16, o0 = blockIdx.x * 16;
    for (int i = t; i < 16 * 2 * NW; i += 256) {
        int rr = i / (2 * NW), cc = i % (2 * NW);
        As[rr][cc] = A[(size_t)(b0 + rr) * 2 * NW + cc];
        int o = o0 + rr;
        Ws[rr][cc] = (o < O) ? W[(size_t)o * 2 * NW + cc] : 0ull;
    }
    __syncthreads();
    const int tx = t % 16, ty = t / 16;
    int aV = 0, aD = 0;
    #pragma unroll
    for (int wd = 0; wd < NW; ++wd) {
        ulonglong2 a = *(const ulonglong2*)&As[ty][2 * wd];
        ulonglong2 w = *(const ulonglong2*)&Ws[tx][2 * wd];
        u64 val = a.y & w.y;
        u64 df  = (a.x ^ w.x) & val;
        aV += (int)__popcll(val); aD += (int)__popcll(df);
    }
    int acc = aV - 2 * aD;
    int o = o0 + tx;
    if (o < O)
        C[(size_t)(b0 + ty) * O + o] = (float)acc + (bias ? bias[o] : 0.0f);
    sacc[ty][tx] = (o < O) ? acc : 0;
    __syncthreads();
    if (part != nullptr && ty == 0) {
        int s = 0; long long q = 0;
        #pragma unroll
        for (int b = 0; b < 16; ++b) {
            int v = sacc[b][tx];
            s += v; q += (long long)v * v;
        }
        part[((size_t)(o0 + tx) * nbc + blockIdx.y) * 2]     = (double)s;
        part[((size_t)(o0 + tx) * nbc + blockIdx.y) * 2 + 1] = (double)q;
    }
}

// ---------------------------------------------------------------------------

static inline int cdiv(long a, int b) { return (int)((a + b - 1) / b); }

extern "C" void kernel_launch(void* const* d_in, const int* in_sizes, int n_in,
                              void* d_out, int out_size, void* d_ws, size_t ws_size,
                              hipStream_t stream) {
    const float* x   = (const float*)d_in[0];
    const float* w1  = (const float*)d_in[1];
    const float* g1  = (const float*)d_in[2];
    const float* b1  = (const float*)d_in[3];
    const float* w2  = (const float*)d_in[4];
    const float* g2  = (const float*)d_in[5];
    const float* b2  = (const float*)d_in[6];
    const float* w3  = (const float*)d_in[7];
    const float* g3  = (const float*)d_in[8];
    const float* b3  = (const float*)d_in[9];
    const float* w4  = (const float*)d_in[10];
    const float* g4  = (const float*)d_in[11];
    const float* b4  = (const float*)d_in[12];
    const float* w5  = (const float*)d_in[13];
    const float* g5  = (const float*)d_in[14];
    const float* b5  = (const float*)d_in[15];
    const float* wl1 = (const float*)d_in[16];
    const float* gl1 = (const float*)d_in[17];
    const float* bl1 = (const float*)d_in[18];
    const float* wl2 = (const float*)d_in[19];
    const float* gl2 = (const float*)d_in[20];
    const float* bl2 = (const float*)d_in[21];
    const float* wl3 = (const float*)d_in[22];
    const float* bl3 = (const float*)d_in[23];
    float* out = (float*)d_out;
    (void)in_sizes; (void)n_in; (void)out_size; (void)ws_size;

    char* base = (char*)d_ws;
    size_t off = 0;
    auto alloc = [&](size_t bytes) {
        char* p = base + off;
        off += (bytes + 15) & ~(size_t)15;
        return (void*)p;
    };
    float* R1   = (float*)alloc(7372800 * 4);  // conv1 / conv3 / fc2
    float* R2   = (float*)alloc(4718592 * 4);  // conv2 / conv4 / fc1
    float* R3   = (float*)alloc(524288 * 4);   // conv5 pooled [512,256,4]
    float* w1s  = (float*)alloc(4800 * 4);
    u64* p1  = (u64*)alloc(230400 * 8);   // [512][225][2]
    u64* p2  = (u64*)alloc(110592 * 8);   // [512][36][6]
    u64* p3  = (u64*)alloc(221184 * 8);   // [512][36][12]
    u64* p4  = (u64*)alloc(147456 * 8);   // [512][36][8]
    u64* p5  = (u64*)alloc(16384 * 8);    // [512][32]
    u64* pf1 = (u64*)alloc(65536 * 8);    // [512][128]
    u64* pf2 = (u64*)alloc(32768 * 8);    // [512][64]
    u64* w2p  = (u64*)alloc(9600 * 8);
    u64* w3p  = (u64*)alloc(20736 * 8);
    u64* w4p  = (u64*)alloc(27648 * 8);
    u64* w5p  = (u64*)alloc(18432 * 8);
    u64* wl1p = (u64*)alloc(131072 * 8);
    u64* wl2p = (u64*)alloc(262144 * 8);
    u64* wl3p = (u64*)alloc(640 * 8);
    double* part = (double*)alloc((size_t)4096 * 32 * 2 * 8);   // max 4096ch x 32 chunks
    float* stats = (float*)alloc(7 * 2 * 4096 * 4);
    float* m_[7]; float* a_[7];
    for (int l = 0; l < 7; ++l) { m_[l] = stats + (size_t)l * 8192; a_[l] = m_[l] + 4096; }

    // ---- weight prep (one kernel; PREP_TOTAL = 239936) ----
    k_prep<<<cdiv(PREP_TOTAL, 256), 256, 0, stream>>>(
        w1, w1s, w2, w2p, w3, w3p, w4, w4p, w5, w5p, wl1, wl1p, wl2, wl2p, wl3, wl3p);

    // ---- conv1 + pool -> R1 (+stats); bn1; pack -> p1 ----
    k_conv1<<<dim3(8, 512), 256, 0, stream>>>(x, w1s, R1, part);
    k_stats_final<<<64, 64, 0, stream>>>(part, g1, m_[0], a_[0], 512, (long)512 * 225);
    k_bnpack2d<<<cdiv((long)512 * 225, 256), 256, 0, stream>>>(R1, m_[0], a_[0], b1, p1, 512, 64, 225);

    // ---- conv2 + pool -> R2 (+stats); bn2; pack -> p2 ----
    k_conv2<<<dim3(192, 64), 320, 0, stream>>>(p1, w2p, R2, part);
    k_stats_final<<<192, 64, 0, stream>>>(part, g2, m_[1], a_[1], 64, (long)512 * 36);
    k_bnpack2d<<<cdiv((long)512 * 36 * 3, 256), 256, 0, stream>>>(R2, m_[1], a_[1], b2, p2, 512, 192, 36);

    // ---- conv3 -> R1 (+stats); bn3; pack -> p3 ----
    k_convbin3<3, 3><<<dim3(384, 64), 320, 0, stream>>>(p2, w3p, R1, part, 384);
    k_stats_final<<<384, 64, 0, stream>>>(part, g3, m_[2], a_[2], 64, (long)512 * 36);
    k_bnpack2d<<<cdiv((long)512 * 36 * 6, 256), 256, 0, stream>>>(R1, m_[2], a_[2], b3, p3, 512, 384, 36);

    // ---- conv4 -> R2 (+stats); bn4; pack -> p4 ----
    k_convbin3<6, 3><<<dim3(256, 64), 320, 0, stream>>>(p3, w4p, R2, part, 256);
    k_stats_final<<<256, 64, 0, stream>>>(part, g4, m_[3], a_[3], 64, (long)512 * 36);
    k_bnpack2d<<<cdiv((long)512 * 36 * 4, 256), 256, 0, stream>>>(R2, m_[3], a_[3], b4, p4, 512, 256, 36);

    // ---- conv5 + in-LDS pool -> R3 (+stats on pooled); bn5; flat-pack -> p5 ----
    k_conv5<<<dim3(256, 64), 320, 0, stream>>>(p4, w5p, R3, part);
    k_stats_final<<<256, 64, 0, stream>>>(part, g5, m_[4], a_[4], 64, (long)512 * 4);
    k_bnpack_flat<<<cdiv(512 * 16, 256), 256, 0, stream>>>(R3, m_[4], a_[4], b5, p5, 512);

    // ---- fc1 -> R2 (+stats); bn; pack -> pf1 ----
    k_fcbin2<16><<<dim3(256, 32), 256, 0, stream>>>(p5, wl1p, nullptr, R2, 4096, part, 32);
    k_stats_final<<<4096, 64, 0, stream>>>(part, gl1, m_[5], a_[5], 32, 512);
    k_bnpack1d<<<cdiv(512 * 64, 256), 256, 0, stream>>>(R2, m_[5], a_[5], bl1, pf1, 512, 4096);

    // ---- fc2 -> R1 (+stats); bn; pack -> pf2 ----
    k_fcbin2<64><<<dim3(128, 32), 256, 0, stream>>>(pf1, wl2p, nullptr, R1, 2048, part, 32);
    k_stats_final<<<2048, 64, 0, stream>>>(part, gl2, m_[6], a_[6], 32, 512);
    k_bnpack1d<<<cdiv(512 * 32, 256), 256, 0, stream>>>(R1, m_[6], a_[6], bl2, pf2, 512, 2048);

    // ---- fc3 + bias -> out [512,10] ----
    k_fcbin2<32><<<dim3(1, 32), 256, 0, stream>>>(pf2, wl3p, bl3, out, 10, nullptr, 0);
}

// Round 6
// 877.365 us; speedup vs baseline: 46.3099x; 1.0990x over previous
//
#include <hip/hip_runtime.h>
#include <math.h>

// ---------------------------------------------------------------------------
// BinAlexNet forward — round 6: XNOR fast path with geometric pad correction.
//   Exactness: has-zero flags (activations & weights) computed at pack time;
//   fast path (no masks, 4 VALU/tap-word) used only when flag==0, else the
//   round-5 exact masked path. Padding over-count corrected via per-channel
//   weight-sign-popcount prefix tables:
//     dot = 64*NW*nvalid - 2*S + 2*(Wtot - Wrect),  S = sum popc(sa ^ sw)
// ---------------------------------------------------------------------------

typedef unsigned long long u64;

__device__ __forceinline__ float sgn(float x) {
    return (float)((x > 0.0f) - (x < 0.0f));
}

// flag slots: 0:conv2 1:conv3 2:conv4 3:conv5 4:fc1 5:fc2 6:fc3
// ---------------------------------------------------------------------------
// merged weight prep: sign(w1) + pack conv w2..w5 + pack fc wl1..wl3
// packers atomicOr consumer flag if any zero weight found.
// ---------------------------------------------------------------------------
__device__ void pack_conv_one(int idx, const float* __restrict__ w,
                              u64* __restrict__ wp, int Cout, int Cin, int KK,
                              int* flag) {
    int NW = (Cin + 63) >> 6;
    int wd = idx % NW, t = idx / NW;
    int tap = t % KK, co = t / KK;
    u64 s = 0, nz = 0;
    for (int c = 0; c < 64; ++c) {
        int ci = wd * 64 + c;
        if (ci >= Cin) break;
        float v = w[((size_t)co * Cin + ci) * KK + tap];
        if (v > 0.0f) s |= (1ull << c);
        if (v != 0.0f) nz |= (1ull << c);
    }
    u64* o = wp + ((size_t)co * KK + tap) * 2 * NW + 2 * wd;
    o[0] = s; o[1] = nz;
    if (nz != ~0ull) atomicOr(flag, 1);
}

__device__ void pack_fc_one(int idx, const float* __restrict__ w,
                            u64* __restrict__ wp, int Kd, int* flag) {
    int NW = Kd >> 6;
    int wd = idx % NW, o = idx / NW;
    const float* row = w + (size_t)o * Kd + wd * 64;
    u64 s = 0, nz = 0;
    for (int c = 0; c < 64; ++c) {
        float v = row[c];
        if (v > 0.0f) s |= (1ull << c);
        if (v != 0.0f) nz |= (1ull << c);
    }
    u64* op = wp + (size_t)o * 2 * NW + 2 * wd;
    op[0] = s; op[1] = nz;
    if (nz != ~0ull) atomicOr(flag, 1);
}

#define PN0 4800
#define PN1 4800
#define PN2 10368
#define PN3 13824
#define PN4 9216
#define PN5 65536
#define PN6 131072
#define PN7 320
#define PREP_TOTAL (PN0+PN1+PN2+PN3+PN4+PN5+PN6+PN7)   // 239936

__global__ void k_prep(const float* w1, float* w1s,
                       const float* w2, u64* w2p,
                       const float* w3, u64* w3p,
                       const float* w4, u64* w4p,
                       const float* w5, u64* w5p,
                       const float* wl1, u64* wl1p,
                       const float* wl2, u64* wl2p,
                       const float* wl3, u64* wl3p,
                       int* flags) {
    int idx = blockIdx.x * blockDim.x + threadIdx.x;
    int r = idx;
    if (r < PN0) { w1s[r] = sgn(w1[r]); return; } r -= PN0;
    if (r < PN1) { pack_conv_one(r, w2, w2p, 192, 64, 25, flags + 0); return; } r -= PN1;
    if (r < PN2) { pack_conv_one(r, w3, w3p, 384, 192, 9, flags + 1); return; } r -= PN2;
    if (r < PN3) { pack_conv_one(r, w4, w4p, 256, 384, 9, flags + 2); return; } r -= PN3;
    if (r < PN4) { pack_conv_one(r, w5, w5p, 256, 256, 9, flags + 3); return; } r -= PN4;
    if (r < PN5) { pack_fc_one(r, wl1, wl1p, 1024, flags + 4); return; } r -= PN5;
    if (r < PN6) { pack_fc_one(r, wl2, wl2p, 4096, flags + 5); return; } r -= PN6;
    if (r < PN7) { pack_fc_one(r, wl3, wl3p, 2048, flags + 6); return; }
}

// ---------------------------------------------------------------------------
// prep2: per-channel weight-sign popcount tables (from packed sign words).
//   conv2: R1 (row0 sum), C1 (col0 sum), X (corner) per co -> t2[co*4]
//   conv3/4/5: 4x4 2D prefix of the 3x3 per-tap popc grid -> tN[co*16]
// ---------------------------------------------------------------------------
__device__ void prefix3(const u64* __restrict__ wb, int NW, ushort* __restrict__ o) {
    int c00, c01, c02, c10, c11, c12, c20, c21, c22;
    int cs[9];
    #pragma unroll
    for (int tap = 0; tap < 9; ++tap) {
        int s = 0;
        for (int wd = 0; wd < NW; ++wd)
            s += (int)__popcll(wb[tap * 2 * NW + 2 * wd]);
        cs[tap] = s;
    }
    c00 = cs[0]; c01 = cs[1]; c02 = cs[2];
    c10 = cs[3]; c11 = cs[4]; c12 = cs[5];
    c20 = cs[6]; c21 = cs[7]; c22 = cs[8];
    // P[i][j] = sum_{ky<i,kx<j} c[ky][kx], i,j in 0..3
    int P[4][4];
    P[0][0] = 0; P[0][1] = 0; P[0][2] = 0; P[0][3] = 0;
    P[1][0] = 0; P[2][0] = 0; P[3][0] = 0;
    P[1][1] = c00;             P[1][2] = c00 + c01;             P[1][3] = c00 + c01 + c02;
    P[2][1] = c00 + c10;       P[2][2] = c00 + c01 + c10 + c11; P[2][3] = P[1][3] + c10 + c11 + c12;
    P[3][1] = c00 + c10 + c20; P[3][2] = P[2][2] + c20 + c21;   P[3][3] = P[2][3] + c20 + c21 + c22;
    #pragma unroll
    for (int i = 0; i < 4; ++i)
        #pragma unroll
        for (int j = 0; j < 4; ++j)
            o[i * 4 + j] = (ushort)P[i][j];
}

__global__ void k_prep2(const u64* w2p, const u64* w3p, const u64* w4p, const u64* w5p,
                        ushort* t2, ushort* t3, ushort* t4, ushort* t5) {
    int idx = blockIdx.x * blockDim.x + threadIdx.x;
    if (idx < 192) {
        const u64* wb = w2p + idx * 50;
        int cnt[25];
        #pragma unroll
        for (int tap = 0; tap < 25; ++tap) cnt[tap] = (int)__popcll(wb[tap * 2]);
        int R1 = 0, C1 = 0;
        #pragma unroll
        for (int k = 0; k < 5; ++k) { R1 += cnt[k]; C1 += cnt[k * 5]; }
        t2[idx * 4 + 0] = (ushort)R1;
        t2[idx * 4 + 1] = (ushort)C1;
        t2[idx * 4 + 2] = (ushort)cnt[0];
        t2[idx * 4 + 3] = 0;
        return;
    }
    idx -= 192;
    if (idx < 384) { prefix3(w3p + (size_t)idx * 54, 3, t3 + idx * 16); return; }
    idx -= 384;
    if (idx < 256) { prefix3(w4p + (size_t)idx * 108, 6, t4 + idx * 16); return; }
    idx -= 256;
    if (idx < 256) { prefix3(w5p + (size_t)idx * 72, 4, t5 + idx * 16); return; }
}

// ---------------------------------------------------------------------------
// conv1: unchanged (fp32, LDS image, fused pool + stats)
// ---------------------------------------------------------------------------
__global__ __launch_bounds__(256)
void k_conv1(const float* __restrict__ x, const float* __restrict__ w1s,
             float* __restrict__ out, double* __restrict__ part) {
    __shared__ float sx[3 * 34 * 34];
    __shared__ double sS[256];
    __shared__ double sQ[256];
    const int b = blockIdx.y, cg = blockIdx.x, t = threadIdx.x;
    for (int i = t; i < 3 * 34 * 34; i += 256) sx[i] = 0.0f;
    __syncthreads();
    for (int i = t; i < 3072; i += 256) {
        int ch = i >> 10, rem = i & 1023, yy = rem >> 5, xx = rem & 31;
        sx[(ch * 34 + yy + 1) * 34 + xx + 1] = x[(size_t)b * 3072 + i];
    }
    __syncthreads();
    const bool act = t < 225;
    const int py = act ? t / 15 : 0, px = act ? t % 15 : 0;
    float a0[8], a1[8], a2[8], a3[8];
    #pragma unroll
    for (int c = 0; c < 8; ++c) { a0[c] = a1[c] = a2[c] = a3[c] = 0.f; }
    #pragma unroll 1
    for (int ch = 0; ch < 3; ++ch) {
        const float* wc = w1s + (size_t)(cg * 8) * 75 + ch * 25;
        #pragma unroll 1
        for (int yy6 = 0; yy6 < 6; ++yy6) {
            const float2* rp = (const float2*)&sx[(ch * 34 + py * 2 + yy6) * 34 + px * 2];
            float2 ra = rp[0], rb = rp[1], rc = rp[2];
            float r[6] = {ra.x, ra.y, rb.x, rb.y, rc.x, rc.y};
            if (yy6 <= 4) {
                #pragma unroll
                for (int kx = 0; kx < 5; ++kx)
                    #pragma unroll
                    for (int cc = 0; cc < 8; ++cc) {
                        float wv = wc[cc * 75 + yy6 * 5 + kx];
                        a0[cc] = fmaf(r[kx],     wv, a0[cc]);
                        a1[cc] = fmaf(r[kx + 1], wv, a1[cc]);
                    }
            }
            if (yy6 >= 1) {
                #pragma unroll
                for (int kx = 0; kx < 5; ++kx)
                    #pragma unroll
                    for (int cc = 0; cc < 8; ++cc) {
                        float wv = wc[cc * 75 + (yy6 - 1) * 5 + kx];
                        a2[cc] = fmaf(r[kx],     wv, a2[cc]);
                        a3[cc] = fmaf(r[kx + 1], wv, a3[cc]);
                    }
            }
        }
    }
    #pragma unroll
    for (int cc = 0; cc < 8; ++cc) {
        float best = 0.f;
        if (act) {
            best = fmaxf(fmaxf(a0[cc], a1[cc]), fmaxf(a2[cc], a3[cc]));
            out[((size_t)b * 64 + cg * 8 + cc) * 225 + t] = best;
        }
        double v = act ? (double)best : 0.0;
        sS[t] = v; sQ[t] = v * v;
        __syncthreads();
        for (int o2 = 128; o2 > 0; o2 >>= 1) {
            if (t < o2) { sS[t] += sS[t + o2]; sQ[t] += sQ[t + o2]; }
            __syncthreads();
        }
        if (t == 0) {
            part[((size_t)(cg * 8 + cc) * 512 + b) * 2]     = sS[0];
            part[((size_t)(cg * 8 + cc) * 512 + b) * 2 + 1] = sQ[0];
        }
        __syncthreads();
    }
}

// ---------------------------------------------------------------------------
// conv2 (binary K=5, NW=1) + maxpool2x2 + fused stats. Fast XNOR path.
// ---------------------------------------------------------------------------
#define TAP(vv, WS, WN, AV, AD) { u64 _val = (vv).y & (WN); \
    u64 _df = ((vv).x ^ (WS)) & _val; \
    AV += (int)__popcll(_val); AD += (int)__popcll(_df); }

__global__ __launch_bounds__(320)
void k_conv2(const u64* __restrict__ in, const u64* __restrict__ w,
             float* __restrict__ out, double* __restrict__ part,
             const ushort* __restrict__ t2, const int* __restrict__ flags) {
    __shared__ ulonglong2 st[8 * 17 * 17];
    const int co = blockIdx.x, bg = blockIdx.y, b0 = bg * 8, t = threadIdx.x;
    const int fl = flags[0];
    for (int i = t; i < 8 * 17 * 17; i += 320) { st[i].x = 0; st[i].y = 0; }
    __syncthreads();
    const ulonglong2* gin = (const ulonglong2*)in;
    for (int i = t; i < 8 * 225; i += 320) {
        int bb = i / 225, j = i - bb * 225;
        int yy = j / 15, xx = j - yy * 15;
        st[(bb * 17 + yy + 1) * 17 + xx + 1] = gin[(size_t)(b0 + bb) * 225 + j];
    }
    __syncthreads();
    const bool act = t < 288;
    const int bb = act ? t / 36 : 0, r = act ? t - (t / 36) * 36 : 0;
    const int py = r / 6, px = r - py * 6;
    const u64* wb = w + co * 50;
    int best = 0;
    if (act) {
        if (fl == 0) {
            // ---- fast XNOR path (no zeros anywhere) ----
            const ushort* tb = t2 + co * 4;
            const int R1 = tb[0], C1 = tb[1], X = tb[2];
            int S0 = 0, S1 = 0, S2 = 0, S3 = 0;
            const u64* stx = (const u64*)st;
            #pragma unroll 1
            for (int yy6 = 0; yy6 < 6; ++yy6) {
                const int base = (bb * 17 + py * 2 + yy6) * 17 + px * 2;
                u64 V[6];
                #pragma unroll
                for (int k = 0; k < 6; ++k) V[k] = stx[(base + k) * 2];
                if (yy6 <= 4) {
                    const u64* wr_ = wb + (yy6 * 5) * 2;
                    #pragma unroll
                    for (int kx = 0; kx < 5; ++kx) {
                        u64 ws_ = wr_[kx * 2];
                        S0 += (int)__popcll(V[kx] ^ ws_);
                        S1 += (int)__popcll(V[kx + 1] ^ ws_);
                    }
                }
                if (yy6 >= 1) {
                    const u64* wr_ = wb + ((yy6 - 1) * 5) * 2;
                    #pragma unroll
                    for (int kx = 0; kx < 5; ++kx) {
                        u64 ws_ = wr_[kx * 2];
                        S2 += (int)__popcll(V[kx] ^ ws_);
                        S3 += (int)__popcll(V[kx + 1] ^ ws_);
                    }
                }
            }
            // windows: 0:(dy0,dx0) 1:(dy0,dx1) 2:(dy1,dx0) 3:(dy1,dx1)
            // yc=2py+dy<=11, xc=2px+dx<=11 -> only low-side padding matters
            const int py0 = (py == 0), px0 = (px == 0);
            int d0 = 64 * (5 - py0) * (5 - px0) - 2 * S0 + 2 * (py0 * R1 + px0 * C1 - py0 * px0 * X);
            int d1 = 64 * (5 - py0) * 5 - 2 * S1 + 2 * (py0 * R1);
            int d2 = 64 * 5 * (5 - px0) - 2 * S2 + 2 * (px0 * C1);
            int d3 = 1600 - 2 * S3;
            best = max(max(d0, d1), max(d2, d3));
        } else {
            // ---- exact masked path (round-5) ----
            int aV0 = 0, aD0 = 0, aV1 = 0, aD1 = 0, aV2 = 0, aD2 = 0, aV3 = 0, aD3 = 0;
            #pragma unroll 1
            for (int yy6 = 0; yy6 < 6; ++yy6) {
                const ulonglong2* rp = &st[(bb * 17 + py * 2 + yy6) * 17 + px * 2];
                ulonglong2 V[6];
                #pragma unroll
                for (int k = 0; k < 6; ++k) V[k] = rp[k];
                if (yy6 <= 4) {
                    const u64* wr_ = wb + (yy6 * 5) * 2;
                    #pragma unroll
                    for (int kx = 0; kx < 5; ++kx) {
                        u64 ws_ = wr_[kx * 2], wn_ = wr_[kx * 2 + 1];
                        TAP(V[kx],     ws_, wn_, aV0, aD0);
                        TAP(V[kx + 1], ws_, wn_, aV1, aD1);
                    }
                }
                if (yy6 >= 1) {
                    const u64* wr_ = wb + ((yy6 - 1) * 5) * 2;
                    #pragma unroll
                    for (int kx = 0; kx < 5; ++kx) {
                        u64 ws_ = wr_[kx * 2], wn_ = wr_[kx * 2 + 1];
                        TAP(V[kx],     ws_, wn_, aV2, aD2);
                        TAP(V[kx + 1], ws_, wn_, aV3, aD3);
                    }
                }
            }
            int s0 = aV0 - 2 * aD0, s1 = aV1 - 2 * aD1;
            int s2 = aV2 - 2 * aD2, s3 = aV3 - 2 * aD3;
            best = max(max(s0, s1), max(s2, s3));
        }
        out[((size_t)(b0 + bb) * 192 + co) * 36 + r] = (float)best;
    }
    __syncthreads();
    int* si = (int*)st;
    long long* sq = (long long*)(si + 512);
    si[t] = act ? best : 0;
    sq[t] = act ? (long long)best * best : 0;
    __syncthreads();
    if (t < 64) { si[t] += si[t + 256]; sq[t] += sq[t + 256]; }
    __syncthreads();
    for (int o2 = 128; o2 > 0; o2 >>= 1) {
        if (t < o2) { si[t] += si[t + o2]; sq[t] += sq[t + o2]; }
        __syncthreads();
    }
    if (t == 0) {
        part[((size_t)co * 64 + bg) * 2]     = (double)si[0];
        part[((size_t)co * 64 + bg) * 2 + 1] = (double)sq[0];
    }
}

// ---------------------------------------------------------------------------
// 3x3 pad-1 binary conv on 6x6 (conv3/conv4), K-chunked, fast path + stats.
// ---------------------------------------------------------------------------
template<int NW, int NWC>
__global__ __launch_bounds__(320)
void k_convbin3(const u64* __restrict__ in, const u64* __restrict__ w,
                float* __restrict__ out, double* __restrict__ part, int Cout,
                const ushort* __restrict__ tP, const int* __restrict__ flags, int slot) {
    __shared__ ulonglong2 st[8 * 72 * NWC];
    const int co = blockIdx.x, bg = blockIdx.y, b0 = bg * 8, t = threadIdx.x;
    const int fl = flags[slot];
    const bool act = t < 288;
    const int bb = act ? t / 36 : 0, r = act ? t - (t / 36) * 36 : 0;
    const int y = r / 6, x0 = r - y * 6;
    const u64* wb = w + (size_t)co * 9 * 2 * NW;
    const ulonglong2* gin = (const ulonglong2*)in;
    // geometric pad correction (fast path)
    int corr = 0, nv = 9;
    if (act && fl == 0) {
        const int ky0 = (y == 0), ky1 = (y == 5) ? 2 : 3;
        const int kx0 = (x0 == 0), kx1 = (x0 == 5) ? 2 : 3;
        const ushort* tb = tP + co * 16;
        int Wt = tb[15];
        int Wr = (int)tb[ky1 * 4 + kx1] - (int)tb[ky0 * 4 + kx1]
               - (int)tb[ky1 * 4 + kx0] + (int)tb[ky0 * 4 + kx0];
        corr = Wt - Wr;
        nv = (ky1 - ky0) * (kx1 - kx0);
    }
    int aV = 0, aD = 0, S = 0;
    #pragma unroll 1
    for (int c0 = 0; c0 < NW; c0 += NWC) {
        __syncthreads();
        for (int i = t; i < 8 * 72 * NWC; i += 320) { st[i].x = 0; st[i].y = 0; }
        __syncthreads();
        for (int i = t; i < 8 * 36 * NWC; i += 320) {
            int wd = i % NWC, j = (i / NWC) % 36, bb2 = i / (36 * NWC);
            int yy = j / 6, xx = j - yy * 6;
            st[((bb2 * 8 + yy + 1) * 9 + xx + 1) * NWC + wd] =
                gin[((size_t)(b0 + bb2) * 36 + j) * NW + c0 + wd];
        }
        __syncthreads();
        if (act) {
            if (fl == 0) {
                const u64* stx = (const u64*)st;
                #pragma unroll
                for (int ky = 0; ky < 3; ++ky)
                    #pragma unroll
                    for (int kx = 0; kx < 3; ++kx) {
                        const int vb = ((bb * 8 + y + ky) * 9 + x0 + kx) * NWC;
                        const u64* wp = wb + (ky * 3 + kx) * 2 * NW + 2 * c0;
                        #pragma unroll
                        for (int wd = 0; wd < NWC; ++wd)
                            S += (int)__popcll(stx[(vb + wd) * 2] ^ wp[2 * wd]);
                    }
            } else {
                #pragma unroll
                for (int ky = 0; ky < 3; ++ky)
                    #pragma unroll
                    for (int kx = 0; kx < 3; ++kx) {
                        const ulonglong2* vp = &st[((bb * 8 + y + ky) * 9 + x0 + kx) * NWC];
                        const u64* wp = wb + (ky * 3 + kx) * 2 * NW + 2 * c0;
                        #pragma unroll
                        for (int wd = 0; wd < NWC; ++wd) {
                            ulonglong2 a = vp[wd];
                            u64 val = a.y & wp[2 * wd + 1];
                            u64 df  = (a.x ^ wp[2 * wd]) & val;
                            aV += (int)__popcll(val); aD += (int)__popcll(df);
                        }
                    }
            }
        }
    }
    int s = (fl == 0) ? (64 * NW * nv - 2 * S + 2 * corr) : (aV - 2 * aD);
    if (act) out[((size_t)(b0 + bb) * Cout + co) * 36 + r] = (float)s;
    __syncthreads();
    int* si = (int*)st;
    long long* sq = (long long*)(si + 512);
    si[t] = act ? s : 0;
    sq[t] = act ? (long long)s * s : 0;
    __syncthreads();
    if (t < 64) { si[t] += si[t + 256]; sq[t] += sq[t + 256]; }
    __syncthreads();
    for (int o2 = 128; o2 > 0; o2 >>= 1) {
        if (t < o2) { si[t] += si[t + o2]; sq[t] += sq[t + o2]; }
        __syncthreads();
    }
    if (t == 0) {
        part[((size_t)co * 64 + bg) * 2]     = (double)si[0];
        part[((size_t)co * 64 + bg) * 2 + 1] = (double)sq[0];
    }
}

// ---------------------------------------------------------------------------
// conv5 (NW=4, K-chunk 2) + in-LDS maxpool3x3/2 + stats on POOLED vals.
// ---------------------------------------------------------------------------
__global__ __launch_bounds__(320)
void k_conv5(const u64* __restrict__ in, const u64* __restrict__ w,
             float* __restrict__ outp, double* __restrict__ part,
             const ushort* __restrict__ tP, const int* __restrict__ flags) {
    __shared__ ulonglong2 st[8 * 72 * 2];
    __shared__ int sacc[8 * 36];
    const int co = blockIdx.x, bg = blockIdx.y, b0 = bg * 8, t = threadIdx.x;
    const int fl = flags[3];
    const bool act = t < 288;
    const int bb = act ? t / 36 : 0, r = act ? t - (t / 36) * 36 : 0;
    const int y = r / 6, x0 = r - y * 6;
    const u64* wb = w + (size_t)co * 9 * 2 * 4;
    const ulonglong2* gin = (const ulonglong2*)in;
    int corr = 0, nv = 9;
    if (act && fl == 0) {
        const int ky0 = (y == 0), ky1 = (y == 5) ? 2 : 3;
        const int kx0 = (x0 == 0), kx1 = (x0 == 5) ? 2 : 3;
        const ushort* tb = tP + co * 16;
        int Wt = tb[15];
        int Wr = (int)tb[ky1 * 4 + kx1] - (int)tb[ky0 * 4 + kx1]
               - (int)tb[ky1 * 4 + kx0] + (int)tb[ky0 * 4 + kx0];
        corr = Wt - Wr;
        nv = (ky1 - ky0) * (kx1 - kx0);
    }
    int aV = 0, aD = 0, S = 0;
    #pragma unroll 1
    for (int c0 = 0; c0 < 4; c0 += 2) {
        __syncthreads();
        for (int i = t; i < 8 * 72 * 2; i += 320) { st[i].x = 0; st[i].y = 0; }
        __syncthreads();
        for (int i = t; i < 8 * 36 * 2; i += 320) {
            int wd = i % 2, j = (i / 2) % 36, bb2 = i / 72;
            int yy = j / 6, xx = j - yy * 6;
            st[((bb2 * 8 + yy + 1) * 9 + xx + 1) * 2 + wd] =
                gin[((size_t)(b0 + bb2) * 36 + j) * 4 + c0 + wd];
        }
        __syncthreads();
        if (act) {
            if (fl == 0) {
                const u64* stx = (const u64*)st;
                #pragma unroll
                for (int ky = 0; ky < 3; ++ky)
                    #pragma unroll
                    for (int kx = 0; kx < 3; ++kx) {
                        const int vb = ((bb * 8 + y + ky) * 9 + x0 + kx) * 2;
                        const u64* wp = wb + (ky * 3 + kx) * 8 + 2 * c0;
                        S += (int)__popcll(stx[vb * 2] ^ wp[0]);
                        S += (int)__popcll(stx[(vb + 1) * 2] ^ wp[2]);
                    }
            } else {
                #pragma unroll
                for (int ky = 0; ky < 3; ++ky)
                    #pragma unroll
                    for (int kx = 0; kx < 3; ++kx) {
                        const ulonglong2* vp = &st[((bb * 8 + y + ky) * 9 + x0 + kx) * 2];
                        const u64* wp = wb + (ky * 3 + kx) * 8 + 2 * c0;
                        #pragma unroll
                        for (int wd = 0; wd < 2; ++wd) {
                            ulonglong2 a = vp[wd];
                            u64 val = a.y & wp[2 * wd + 1];
                            u64 df  = (a.x ^ wp[2 * wd]) & val;
                            aV += (int)__popcll(val); aD += (int)__popcll(df);
                        }
                    }
            }
        }
    }
    if (act) sacc[bb * 36 + r] = (fl == 0) ? (256 * nv - 2 * S + 2 * corr) : (aV - 2 * aD);
    __syncthreads();
    int pooled = 0;
    const bool pact = t < 32;
    if (pact) {
        int bb2 = t / 4, wi = t % 4, py = (wi >> 1) * 2, px = (wi & 1) * 2;
        int best = -1000000;
        #pragma unroll
        for (int dy = 0; dy < 3; ++dy)
            #pragma unroll
            for (int dx = 0; dx < 3; ++dx)
                best = max(best, sacc[bb2 * 36 + (py + dy) * 6 + (px + dx)]);
        pooled = best;
        outp[((size_t)(b0 + bb2) * 256 + co) * 4 + wi] = (float)pooled;
    }
    __syncthreads();
    int* si = (int*)st;
    long long* sq = (long long*)(si + 512);
    si[t] = pact ? pooled : 0;
    sq[t] = pact ? (long long)pooled * pooled : 0;
    __syncthreads();
    if (t < 64) { si[t] += si[t + 256]; sq[t] += sq[t + 256]; }
    __syncthreads();
    for (int o2 = 128; o2 > 0; o2 >>= 1) {
        if (t < o2) { si[t] += si[t + o2]; sq[t] += sq[t + o2]; }
        __syncthreads();
    }
    if (t == 0) {
        part[((size_t)co * 64 + bg) * 2]     = (double)si[0];
        part[((size_t)co * 64 + bg) * 2 + 1] = (double)sq[0];
    }
}

// ---------------------------------------------------------------------------
__global__ void k_stats_final(const double* __restrict__ part, const float* __restrict__ g,
                              float* __restrict__ mean, float* __restrict__ inva,
                              int NB, long total) {
    __shared__ double sS[64], sQ[64];
    const int c = blockIdx.x, t = threadIdx.x;
    double s = 0.0, q = 0.0;
    for (int k = t; k < NB; k += 64) {
        s += part[((size_t)c * NB + k) * 2];
        q += part[((size_t)c * NB + k) * 2 + 1];
    }
    sS[t] = s; sQ[t] = q;
    __syncthreads();
    for (int o = 32; o > 0; o >>= 1) {
        if (t < o) { sS[t] += sS[t + o]; sQ[t] += sQ[t + o]; }
        __syncthreads();
    }
    if (t == 0) {
        double m = sS[0] / (double)total;
        double var = sQ[0] / (double)total - m * m;
        mean[c] = (float)m;
        inva[c] = g[c] * (float)(1.0 / sqrt(var + 1e-5));
    }
}

// ---- BN apply + sign + pack (2d); flags consumer slot on zero ----
__global__ void k_bnpack2d(const float* __restrict__ x, const float* __restrict__ m,
                           const float* __restrict__ a, const float* __restrict__ bt,
                           u64* __restrict__ p, int B, int C, int HW, int* flag) {
    int NW = (C + 63) >> 6;
    int tot = B * HW * NW;
    int idx = blockIdx.x * blockDim.x + threadIdx.x;
    if (idx >= tot) return;
    int wd = idx % NW, t = idx / NW;
    int j = t % HW, b = t / HW;
    u64 s = 0, nz = 0;
    for (int c0 = 0; c0 < 64; ++c0) {
        int c = wd * 64 + c0;
        if (c >= C) break;
        float v = (x[((size_t)b * C + c) * HW + j] - m[c]) * a[c] + bt[c];
        if (v > 0.0f) s |= (1ull << c0);
        if (v != 0.0f) nz |= (1ull << c0);
    }
    u64* o = p + ((size_t)b * HW + j) * 2 * NW + 2 * wd;
    o[0] = s; o[1] = nz;
    if (nz != ~0ull) atomicOr(flag, 1);
}

__global__ void k_bnpack_flat(const float* __restrict__ x, const float* __restrict__ m,
                              const float* __restrict__ a, const float* __restrict__ bt,
                              u64* __restrict__ p, int B, int* flag) {
    int idx = blockIdx.x * blockDim.x + threadIdx.x;
    if (idx >= B * 16) return;
    int wd = idx % 16, b = idx / 16;
    u64 s = 0, nz = 0;
    for (int k = 0; k < 64; ++k) {
        int f = wd * 64 + k;
        int c = f >> 2, j = f & 3;
        float v = (x[((size_t)b * 256 + c) * 4 + j] - m[c]) * a[c] + bt[c];
        if (v > 0.0f) s |= (1ull << k);
        if (v != 0.0f) nz |= (1ull << k);
    }
    u64* o = p + (size_t)b * 32 + 2 * wd;
    o[0] = s; o[1] = nz;
    if (nz != ~0ull) atomicOr(flag, 1);
}

__global__ void k_bnpack1d(const float* __restrict__ x, const float* __restrict__ m,
                           const float* __restrict__ a, const float* __restrict__ bt,
                           u64* __restrict__ p, int B, int F, int* flag) {
    int NW = F >> 6;
    int idx = blockIdx.x * blockDim.x + threadIdx.x;
    if (idx >= B * NW) return;
    int wd = idx % NW, b = idx / NW;
    const float* row = x + (size_t)b * F + wd * 64;
    u64 s = 0, nz = 0;
    for (int c = 0; c < 64; ++c) {
        int f = wd * 64 + c;
        float v = (row[c] - m[f]) * a[f] + bt[f];
        if (v > 0.0f) s |= (1ull << c);
        if (v != 0.0f) nz |= (1ull << c);
    }
    u64* o = p + (size_t)b * 2 * NW + 2 * wd;
    o[0] = s; o[1] = nz;
    if (nz != ~0ull) atomicOr(flag, 1);
}

// ---------------------------------------------------------------------------
// binary FC, 16x16 LDS-tiled, fast XNOR path, optional fused stats.
// ---------------------------------------------------------------------------
template<int NW>
__global__ __launch_bounds__(256)
void k_fcbin2(const u64* __restrict__ A, const u64* __restrict__ W,
              const float* __restrict__ bias, float* __restrict__ C, int O,
              double* __restrict__ part, int nbc, const int* __restrict__ flags, int slot) {
    __shared__ u64 As[16][2 * NW + 2];
    __shared__ u64 Ws[16][2 * NW + 2];
    __shared__ int sacc[16][16];
    const int t = threadIdx.x;
    const int fl = flags[slot];
    const int b0 = blockIdx.y * 16, o0 = blockIdx.x * 16;
    for (int i = t; i < 16 * 2 * NW; i += 256) {
        int rr = i / (2 * NW), cc = i % (2 * NW);
        As[rr][cc] = A[(size_t)(b0 + rr) * 2 * NW + cc];
        int o = o0 + rr;
        Ws[rr][cc] = (o < O) ? W[(size_t)o * 2 * NW + cc] : 0ull;
    }
    __syncthreads();
    const int tx = t % 16, ty = t / 16;
    int acc;
    if (fl == 0) {
        int S = 0;
        #pragma unroll
        for (int wd = 0; wd < NW; ++wd)
            S += (int)__popcll(As[ty][2 * wd] ^ Ws[tx][2 * wd]);
        acc = 64 * NW - 2 * S;
    } else {
        int aV = 0, aD = 0;
        #pragma unroll
        for (int wd = 0; wd < NW; ++wd) {
            ulonglong2 a = *(const ulonglong2*)&As[ty][2 * wd];
            ulonglong2 w = *(const ulonglong2*)&Ws[tx][2 * wd];
            u64 val = a.y & w.y;
            u64 df  = (a.x ^ w.x) & val;
            aV += (int)__popcll(val); aD += (int)__popcll(df);
        }
        acc = aV - 2 * aD;
    }
    int o = o0 + tx;
    if (o < O)
        C[(size_t)(b0 + ty) * O + o] = (float)acc + (bias ? bias[o] : 0.0f);
    sacc[ty][tx] = (o < O) ? acc : 0;
    __syncthreads();
    if (part != nullptr && ty == 0) {
        int s = 0; long long q = 0;
        #pragma unroll
        for (int b = 0; b < 16; ++b) {
            int v = sacc[b][tx];
            s += v; q += (long long)v * v;
        }
        part[((size_t)(o0 + tx) * nbc + blockIdx.y) * 2]     = (double)s;
        part[((size_t)(o0 + tx) * nbc + blockIdx.y) * 2 + 1] = (double)q;
    }
}

// ---------------------------------------------------------------------------

static inline int cdiv(long a, int b) { return (int)((a + b - 1) / b); }

extern "C" void kernel_launch(void* const* d_in, const int* in_sizes, int n_in,
                              void* d_out, int out_size, void* d_ws, size_t ws_size,
                              hipStream_t stream) {
    const float* x   = (const float*)d_in[0];
    const float* w1  = (const float*)d_in[1];
    const float* g1  = (const float*)d_in[2];
    const float* b1  = (const float*)d_in[3];
    const float* w2  = (const float*)d_in[4];
    const float* g2  = (const float*)d_in[5];
    const float* b2  = (const float*)d_in[6];
    const float* w3  = (const float*)d_in[7];
    const float* g3  = (const float*)d_in[8];
    const float* b3  = (const float*)d_in[9];
    const float* w4  = (const float*)d_in[10];
    const float* g4  = (const float*)d_in[11];
    const float* b4  = (const float*)d_in[12];
    const float* w5  = (const float*)d_in[13];
    const float* g5  = (const float*)d_in[14];
    const float* b5  = (const float*)d_in[15];
    const float* wl1 = (const float*)d_in[16];
    const float* gl1 = (const float*)d_in[17];
    const float* bl1 = (const float*)d_in[18];
    const float* wl2 = (const float*)d_in[19];
    const float* gl2 = (const float*)d_in[20];
    const float* bl2 = (const float*)d_in[21];
    const float* wl3 = (const float*)d_in[22];
    const float* bl3 = (const float*)d_in[23];
    float* out = (float*)d_out;
    (void)in_sizes; (void)n_in; (void)out_size; (void)ws_size;

    char* base = (char*)d_ws;
    size_t off = 0;
    auto alloc = [&](size_t bytes) {
        char* p = base + off;
        off += (bytes + 15) & ~(size_t)15;
        return (void*)p;
    };
    float* R1   = (float*)alloc(7372800 * 4);
    float* R2   = (float*)alloc(4718592 * 4);
    float* R3   = (float*)alloc(524288 * 4);
    float* w1s  = (float*)alloc(4800 * 4);
    u64* p1  = (u64*)alloc(230400 * 8);
    u64* p2  = (u64*)alloc(110592 * 8);
    u64* p3  = (u64*)alloc(221184 * 8);
    u64* p4  = (u64*)alloc(147456 * 8);
    u64* p5  = (u64*)alloc(16384 * 8);
    u64* pf1 = (u64*)alloc(65536 * 8);
    u64* pf2 = (u64*)alloc(32768 * 8);
    u64* w2p  = (u64*)alloc(9600 * 8);
    u64* w3p  = (u64*)alloc(20736 * 8);
    u64* w4p  = (u64*)alloc(27648 * 8);
    u64* w5p  = (u64*)alloc(18432 * 8);
    u64* wl1p = (u64*)alloc(131072 * 8);
    u64* wl2p = (u64*)alloc(262144 * 8);
    u64* wl3p = (u64*)alloc(640 * 8);
    double* part = (double*)alloc((size_t)4096 * 32 * 2 * 8);
    float* stats = (float*)alloc(7 * 2 * 4096 * 4);
    int*    flags = (int*)alloc(8 * 4);
    ushort* t2 = (ushort*)alloc(192 * 4 * 2);
    ushort* t3 = (ushort*)alloc(384 * 16 * 2);
    ushort* t4 = (ushort*)alloc(256 * 16 * 2);
    ushort* t5 = (ushort*)alloc(256 * 16 * 2);
    float* m_[7]; float* a_[7];
    for (int l = 0; l < 7; ++l) { m_[l] = stats + (size_t)l * 8192; a_[l] = m_[l] + 4096; }

    hipMemsetAsync(flags, 0, 8 * 4, stream);

    // ---- weight prep ----
    k_prep<<<cdiv(PREP_TOTAL, 256), 256, 0, stream>>>(
        w1, w1s, w2, w2p, w3, w3p, w4, w4p, w5, w5p, wl1, wl1p, wl2, wl2p, wl3, wl3p, flags);
    k_prep2<<<cdiv(192 + 384 + 256 + 256, 256), 256, 0, stream>>>(
        w2p, w3p, w4p, w5p, t2, t3, t4, t5);

    // ---- conv1 + pool -> R1 (+stats); bn1; pack -> p1 ----
    k_conv1<<<dim3(8, 512), 256, 0, stream>>>(x, w1s, R1, part);
    k_stats_final<<<64, 64, 0, stream>>>(part, g1, m_[0], a_[0], 512, (long)512 * 225);
    k_bnpack2d<<<cdiv((long)512 * 225, 256), 256, 0, stream>>>(R1, m_[0], a_[0], b1, p1, 512, 64, 225, flags + 0);

    // ---- conv2 + pool -> R2 (+stats); bn2; pack -> p2 ----
    k_conv2<<<dim3(192, 64), 320, 0, stream>>>(p1, w2p, R2, part, t2, flags);
    k_stats_final<<<192, 64, 0, stream>>>(part, g2, m_[1], a_[1], 64, (long)512 * 36);
    k_bnpack2d<<<cdiv((long)512 * 36 * 3, 256), 256, 0, stream>>>(R2, m_[1], a_[1], b2, p2, 512, 192, 36, flags + 1);

    // ---- conv3 -> R1 (+stats); bn3; pack -> p3 ----
    k_convbin3<3, 3><<<dim3(384, 64), 320, 0, stream>>>(p2, w3p, R1, part, 384, t3, flags, 1);
    k_stats_final<<<384, 64, 0, stream>>>(part, g3, m_[2], a_[2], 64, (long)512 * 36);
    k_bnpack2d<<<cdiv((long)512 * 36 * 6, 256), 256, 0, stream>>>(R1, m_[2], a_[2], b3, p3, 512, 384, 36, flags + 2);

    // ---- conv4 -> R2 (+stats); bn4; pack -> p4 ----
    k_convbin3<6, 3><<<dim3(256, 64), 320, 0, stream>>>(p3, w4p, R2, part, 256, t4, flags, 2);
    k_stats_final<<<256, 64, 0, stream>>>(part, g4, m_[3], a_[3], 64, (long)512 * 36);
    k_bnpack2d<<<cdiv((long)512 * 36 * 4, 256), 256, 0, stream>>>(R2, m_[3], a_[3], b4, p4, 512, 256, 36, flags + 3);

    // ---- conv5 + in-LDS pool -> R3 (+stats on pooled); bn5; flat-pack -> p5 ----
    k_conv5<<<dim3(256, 64), 320, 0, stream>>>(p4, w5p, R3, part, t5, flags);
    k_stats_final<<<256, 64, 0, stream>>>(part, g5, m_[4], a_[4], 64, (long)512 * 4);
    k_bnpack_flat<<<cdiv(512 * 16, 256), 256, 0, stream>>>(R3, m_[4], a_[4], b5, p5, 512, flags + 4);

    // ---- fc1 -> R2 (+stats); bn; pack -> pf1 ----
    k_fcbin2<16><<<dim3(256, 32), 256, 0, stream>>>(p5, wl1p, nullptr, R2, 4096, part, 32, flags, 4);
    k_stats_final<<<4096, 64, 0, stream>>>(part, gl1, m_[5], a_[5], 32, 512);
    k_bnpack1d<<<cdiv(512 * 64, 256), 256, 0, stream>>>(R2, m_[5], a_[5], bl1, pf1, 512, 4096, flags + 5);

    // ---- fc2 -> R1 (+stats); bn; pack -> pf2 ----
    k_fcbin2<64><<<dim3(128, 32), 256, 0, stream>>>(pf1, wl2p, nullptr, R1, 2048, part, 32, flags, 5);
    k_stats_final<<<2048, 64, 0, stream>>>(part, gl2, m_[6], a_[6], 32, 512);
    k_bnpack1d<<<cdiv(512 * 32, 256), 256, 0, stream>>>(R1, m_[6], a_[6], bl2, pf2, 512, 2048, flags + 6);

    // ---- fc3 + bias -> out [512,10] ----
    k_fcbin2<32><<<dim3(1, 32), 256, 0, stream>>>(pf2, wl3p, bl3, out, 10, nullptr, 0, flags, 6);
}

// Round 7
// 810.717 us; speedup vs baseline: 50.1170x; 1.0822x over previous
//
#include <hip/hip_runtime.h>
#include <math.h>

// ---------------------------------------------------------------------------
// BinAlexNet forward — round 7: SoA sign/nz split (global + LDS), bank-spread
// LDS layouts. Fast XNOR path touches ONLY sign planes; masked slow path
// (exactness fallback, flag-gated, never triggered on this data) stages nz.
//   conv2 LDS: st_s[8][17][17] u64 (row 17 -> even/odd bank-pair split by bb)
//   conv3/4/5: per-wd planes [8 bb][8 rows x 9] u64
//   FC: Ws row stride NW|1 (odd) -> 16 distinct bank-pairs for 16 tx lanes
// ---------------------------------------------------------------------------

typedef unsigned long long u64;

__device__ __forceinline__ float sgn(float x) {
    return (float)((x > 0.0f) - (x < 0.0f));
}

// flag slots: 0:conv2in 1:conv3in 2:conv4in 3:conv5in 4:fc1in 5:fc2in 6:fc3in
// (weight zeros OR into the same consumer slot)
// ---------------------------------------------------------------------------
__device__ void pack_conv_one(int idx, const float* __restrict__ w,
                              u64* __restrict__ wp, int Cout, int Cin, int KK,
                              int* flag) {
    int NW = (Cin + 63) >> 6;
    int wd = idx % NW, t = idx / NW;
    int tap = t % KK, co = t / KK;
    u64 s = 0, nz = 0;
    for (int c = 0; c < 64; ++c) {
        int ci = wd * 64 + c;
        if (ci >= Cin) break;
        float v = w[((size_t)co * Cin + ci) * KK + tap];
        if (v > 0.0f) s |= (1ull << c);
        if (v != 0.0f) nz |= (1ull << c);
    }
    u64* o = wp + ((size_t)co * KK + tap) * 2 * NW + 2 * wd;
    o[0] = s; o[1] = nz;
    if (nz != ~0ull) atomicOr(flag, 1);
}

__device__ void pack_fc_one(int idx, const float* __restrict__ w,
                            u64* __restrict__ ws_, u64* __restrict__ wn_,
                            int Kd, int* flag) {
    int NW = Kd >> 6;
    int wd = idx % NW, o = idx / NW;
    const float* row = w + (size_t)o * Kd + wd * 64;
    u64 s = 0, nz = 0;
    for (int c = 0; c < 64; ++c) {
        float v = row[c];
        if (v > 0.0f) s |= (1ull << c);
        if (v != 0.0f) nz |= (1ull << c);
    }
    ws_[(size_t)o * NW + wd] = s;
    wn_[(size_t)o * NW + wd] = nz;
    if (nz != ~0ull) atomicOr(flag, 1);
}

#define PN0 4800
#define PN1 4800
#define PN2 10368
#define PN3 13824
#define PN4 9216
#define PN5 65536
#define PN6 131072
#define PN7 320
#define PREP_TOTAL (PN0+PN1+PN2+PN3+PN4+PN5+PN6+PN7)   // 239936

__global__ void k_prep(const float* w1, float* w1s,
                       const float* w2, u64* w2p,
                       const float* w3, u64* w3p,
                       const float* w4, u64* w4p,
                       const float* w5, u64* w5p,
                       const float* wl1, u64* wl1s_, u64* wl1n_,
                       const float* wl2, u64* wl2s_, u64* wl2n_,
                       const float* wl3, u64* wl3s_, u64* wl3n_,
                       int* flags) {
    int idx = blockIdx.x * blockDim.x + threadIdx.x;
    int r = idx;
    if (r < PN0) { w1s[r] = sgn(w1[r]); return; } r -= PN0;
    if (r < PN1) { pack_conv_one(r, w2, w2p, 192, 64, 25, flags + 0); return; } r -= PN1;
    if (r < PN2) { pack_conv_one(r, w3, w3p, 384, 192, 9, flags + 1); return; } r -= PN2;
    if (r < PN3) { pack_conv_one(r, w4, w4p, 256, 384, 9, flags + 2); return; } r -= PN3;
    if (r < PN4) { pack_conv_one(r, w5, w5p, 256, 256, 9, flags + 3); return; } r -= PN4;
    if (r < PN5) { pack_fc_one(r, wl1, wl1s_, wl1n_, 1024, flags + 4); return; } r -= PN5;
    if (r < PN6) { pack_fc_one(r, wl2, wl2s_, wl2n_, 4096, flags + 5); return; } r -= PN6;
    if (r < PN7) { pack_fc_one(r, wl3, wl3s_, wl3n_, 2048, flags + 6); return; }
}

// ---------------------------------------------------------------------------
// prep2: per-channel weight-sign popcount tables (pad correction).
// ---------------------------------------------------------------------------
__device__ void prefix3(const u64* __restrict__ wb, int NW, ushort* __restrict__ o) {
    int cs[9];
    #pragma unroll
    for (int tap = 0; tap < 9; ++tap) {
        int s = 0;
        for (int wd = 0; wd < NW; ++wd)
            s += (int)__popcll(wb[tap * 2 * NW + 2 * wd]);
        cs[tap] = s;
    }
    int P[4][4];
    P[0][0] = 0; P[0][1] = 0; P[0][2] = 0; P[0][3] = 0;
    P[1][0] = 0; P[2][0] = 0; P[3][0] = 0;
    P[1][1] = cs[0];                 P[1][2] = cs[0] + cs[1];               P[1][3] = cs[0] + cs[1] + cs[2];
    P[2][1] = cs[0] + cs[3];         P[2][2] = cs[0] + cs[1] + cs[3] + cs[4]; P[2][3] = P[1][3] + cs[3] + cs[4] + cs[5];
    P[3][1] = cs[0] + cs[3] + cs[6]; P[3][2] = P[2][2] + cs[6] + cs[7];     P[3][3] = P[2][3] + cs[6] + cs[7] + cs[8];
    #pragma unroll
    for (int i = 0; i < 4; ++i)
        #pragma unroll
        for (int j = 0; j < 4; ++j)
            o[i * 4 + j] = (ushort)P[i][j];
}

__global__ void k_prep2(const u64* w2p, const u64* w3p, const u64* w4p, const u64* w5p,
                        ushort* t2, ushort* t3, ushort* t4, ushort* t5) {
    int idx = blockIdx.x * blockDim.x + threadIdx.x;
    if (idx < 192) {
        const u64* wb = w2p + idx * 50;
        int cnt[25];
        #pragma unroll
        for (int tap = 0; tap < 25; ++tap) cnt[tap] = (int)__popcll(wb[tap * 2]);
        int R1 = 0, C1 = 0;
        #pragma unroll
        for (int k = 0; k < 5; ++k) { R1 += cnt[k]; C1 += cnt[k * 5]; }
        t2[idx * 4 + 0] = (ushort)R1;
        t2[idx * 4 + 1] = (ushort)C1;
        t2[idx * 4 + 2] = (ushort)cnt[0];
        t2[idx * 4 + 3] = 0;
        return;
    }
    idx -= 192;
    if (idx < 384) { prefix3(w3p + (size_t)idx * 54, 3, t3 + idx * 16); return; }
    idx -= 384;
    if (idx < 256) { prefix3(w4p + (size_t)idx * 108, 6, t4 + idx * 16); return; }
    idx -= 256;
    if (idx < 256) { prefix3(w5p + (size_t)idx * 72, 4, t5 + idx * 16); return; }
}

// ---------------------------------------------------------------------------
// conv1: unchanged (fp32, LDS image, fused pool + stats)
// ---------------------------------------------------------------------------
__global__ __launch_bounds__(256)
void k_conv1(const float* __restrict__ x, const float* __restrict__ w1s,
             float* __restrict__ out, double* __restrict__ part) {
    __shared__ float sx[3 * 34 * 34];
    __shared__ double sS[256];
    __shared__ double sQ[256];
    const int b = blockIdx.y, cg = blockIdx.x, t = threadIdx.x;
    for (int i = t; i < 3 * 34 * 34; i += 256) sx[i] = 0.0f;
    __syncthreads();
    for (int i = t; i < 3072; i += 256) {
        int ch = i >> 10, rem = i & 1023, yy = rem >> 5, xx = rem & 31;
        sx[(ch * 34 + yy + 1) * 34 + xx + 1] = x[(size_t)b * 3072 + i];
    }
    __syncthreads();
    const bool act = t < 225;
    const int py = act ? t / 15 : 0, px = act ? t % 15 : 0;
    float a0[8], a1[8], a2[8], a3[8];
    #pragma unroll
    for (int c = 0; c < 8; ++c) { a0[c] = a1[c] = a2[c] = a3[c] = 0.f; }
    #pragma unroll 1
    for (int ch = 0; ch < 3; ++ch) {
        const float* wc = w1s + (size_t)(cg * 8) * 75 + ch * 25;
        #pragma unroll 1
        for (int yy6 = 0; yy6 < 6; ++yy6) {
            const float2* rp = (const float2*)&sx[(ch * 34 + py * 2 + yy6) * 34 + px * 2];
            float2 ra = rp[0], rb = rp[1], rc = rp[2];
            float r[6] = {ra.x, ra.y, rb.x, rb.y, rc.x, rc.y};
            if (yy6 <= 4) {
                #pragma unroll
                for (int kx = 0; kx < 5; ++kx)
                    #pragma unroll
                    for (int cc = 0; cc < 8; ++cc) {
                        float wv = wc[cc * 75 + yy6 * 5 + kx];
                        a0[cc] = fmaf(r[kx],     wv, a0[cc]);
                        a1[cc] = fmaf(r[kx + 1], wv, a1[cc]);
                    }
            }
            if (yy6 >= 1) {
                #pragma unroll
                for (int kx = 0; kx < 5; ++kx)
                    #pragma unroll
                    for (int cc = 0; cc < 8; ++cc) {
                        float wv = wc[cc * 75 + (yy6 - 1) * 5 + kx];
                        a2[cc] = fmaf(r[kx],     wv, a2[cc]);
                        a3[cc] = fmaf(r[kx + 1], wv, a3[cc]);
                    }
            }
        }
    }
    #pragma unroll
    for (int cc = 0; cc < 8; ++cc) {
        float best = 0.f;
        if (act) {
            best = fmaxf(fmaxf(a0[cc], a1[cc]), fmaxf(a2[cc], a3[cc]));
            out[((size_t)b * 64 + cg * 8 + cc) * 225 + t] = best;
        }
        double v = act ? (double)best : 0.0;
        sS[t] = v; sQ[t] = v * v;
        __syncthreads();
        for (int o2 = 128; o2 > 0; o2 >>= 1) {
            if (t < o2) { sS[t] += sS[t + o2]; sQ[t] += sQ[t + o2]; }
            __syncthreads();
        }
        if (t == 0) {
            part[((size_t)(cg * 8 + cc) * 512 + b) * 2]     = sS[0];
            part[((size_t)(cg * 8 + cc) * 512 + b) * 2 + 1] = sQ[0];
        }
        __syncthreads();
    }
}

// ---------------------------------------------------------------------------
// conv2 (binary K=5, NW=1) + maxpool2x2 + fused stats. SoA sign/nz LDS.
// ---------------------------------------------------------------------------
__global__ __launch_bounds__(320)
void k_conv2(const u64* __restrict__ ps, const u64* __restrict__ pn,
             const u64* __restrict__ w, float* __restrict__ out,
             double* __restrict__ part, const ushort* __restrict__ t2,
             const int* __restrict__ flags) {
    __shared__ u64 st_s[8 * 17 * 17];
    __shared__ u64 st_n[8 * 17 * 17];
    const int co = blockIdx.x, bg = blockIdx.y, b0 = bg * 8, t = threadIdx.x;
    const int fl = flags[0];
    for (int i = t; i < 8 * 289; i += 320) { st_s[i] = 0; if (fl) st_n[i] = 0; }
    __syncthreads();
    for (int i = t; i < 8 * 225; i += 320) {
        int bb = i / 225, j = i - bb * 225;
        int yy = j / 15, xx = j - yy * 15;
        int d = (bb * 17 + yy + 1) * 17 + xx + 1;
        size_t g = (size_t)(b0 + bb) * 225 + j;
        st_s[d] = ps[g];
        if (fl) st_n[d] = pn[g];
    }
    __syncthreads();
    const bool act = t < 288;
    const int bb = act ? t / 36 : 0, r = act ? t - (t / 36) * 36 : 0;
    const int py = r / 6, px = r - py * 6;
    const u64* wb = w + co * 50;
    int best = 0;
    if (act) {
        if (fl == 0) {
            const ushort* tb = t2 + co * 4;
            const int R1 = tb[0], C1 = tb[1], X = tb[2];
            int S0 = 0, S1 = 0, S2 = 0, S3 = 0;
            #pragma unroll 1
            for (int yy6 = 0; yy6 < 6; ++yy6) {
                const int base = (bb * 17 + py * 2 + yy6) * 17 + px * 2;
                u64 V[6];
                #pragma unroll
                for (int k = 0; k < 6; ++k) V[k] = st_s[base + k];
                if (yy6 <= 4) {
                    const u64* wr_ = wb + (yy6 * 5) * 2;
                    #pragma unroll
                    for (int kx = 0; kx < 5; ++kx) {
                        u64 ws_ = wr_[kx * 2];
                        S0 += (int)__popcll(V[kx] ^ ws_);
                        S1 += (int)__popcll(V[kx + 1] ^ ws_);
                    }
                }
                if (yy6 >= 1) {
                    const u64* wr_ = wb + ((yy6 - 1) * 5) * 2;
                    #pragma unroll
                    for (int kx = 0; kx < 5; ++kx) {
                        u64 ws_ = wr_[kx * 2];
                        S2 += (int)__popcll(V[kx] ^ ws_);
                        S3 += (int)__popcll(V[kx + 1] ^ ws_);
                    }
                }
            }
            const int py0 = (py == 0), px0 = (px == 0);
            int d0 = 64 * (5 - py0) * (5 - px0) - 2 * S0 + 2 * (py0 * R1 + px0 * C1 - py0 * px0 * X);
            int d1 = 64 * (5 - py0) * 5 - 2 * S1 + 2 * (py0 * R1);
            int d2 = 64 * 5 * (5 - px0) - 2 * S2 + 2 * (px0 * C1);
            int d3 = 1600 - 2 * S3;
            best = max(max(d0, d1), max(d2, d3));
        } else {
            int aV0 = 0, aD0 = 0, aV1 = 0, aD1 = 0, aV2 = 0, aD2 = 0, aV3 = 0, aD3 = 0;
            #pragma unroll 1
            for (int yy6 = 0; yy6 < 6; ++yy6) {
                const int base = (bb * 17 + py * 2 + yy6) * 17 + px * 2;
                u64 Vs[6], Vn[6];
                #pragma unroll
                for (int k = 0; k < 6; ++k) { Vs[k] = st_s[base + k]; Vn[k] = st_n[base + k]; }
                if (yy6 <= 4) {
                    const u64* wr_ = wb + (yy6 * 5) * 2;
                    #pragma unroll
                    for (int kx = 0; kx < 5; ++kx) {
                        u64 ws_ = wr_[kx * 2], wn_ = wr_[kx * 2 + 1];
                        u64 v0 = Vn[kx] & wn_, d0_ = (Vs[kx] ^ ws_) & v0;
                        aV0 += (int)__popcll(v0); aD0 += (int)__popcll(d0_);
                        u64 v1 = Vn[kx + 1] & wn_, d1_ = (Vs[kx + 1] ^ ws_) & v1;
                        aV1 += (int)__popcll(v1); aD1 += (int)__popcll(d1_);
                    }
                }
                if (yy6 >= 1) {
                    const u64* wr_ = wb + ((yy6 - 1) * 5) * 2;
                    #pragma unroll
                    for (int kx = 0; kx < 5; ++kx) {
                        u64 ws_ = wr_[kx * 2], wn_ = wr_[kx * 2 + 1];
                        u64 v2 = Vn[kx] & wn_, d2_ = (Vs[kx] ^ ws_) & v2;
                        aV2 += (int)__popcll(v2); aD2 += (int)__popcll(d2_);
                        u64 v3 = Vn[kx + 1] & wn_, d3_ = (Vs[kx + 1] ^ ws_) & v3;
                        aV3 += (int)__popcll(v3); aD3 += (int)__popcll(d3_);
                    }
                }
            }
            int s0 = aV0 - 2 * aD0, s1 = aV1 - 2 * aD1;
            int s2 = aV2 - 2 * aD2, s3 = aV3 - 2 * aD3;
            best = max(max(s0, s1), max(s2, s3));
        }
        out[((size_t)(b0 + bb) * 192 + co) * 36 + r] = (float)best;
    }
    __syncthreads();
    int* si = (int*)st_s;
    long long* sq = (long long*)(si + 512);
    si[t] = act ? best : 0;
    sq[t] = act ? (long long)best * best : 0;
    __syncthreads();
    if (t < 64) { si[t] += si[t + 256]; sq[t] += sq[t + 256]; }
    __syncthreads();
    for (int o2 = 128; o2 > 0; o2 >>= 1) {
        if (t < o2) { si[t] += si[t + o2]; sq[t] += sq[t + o2]; }
        __syncthreads();
    }
    if (t == 0) {
        part[((size_t)co * 64 + bg) * 2]     = (double)si[0];
        part[((size_t)co * 64 + bg) * 2 + 1] = (double)sq[0];
    }
}

// ---------------------------------------------------------------------------
// 3x3 pad-1 binary conv on 6x6 (conv3/conv4). SoA planes per wd, fused stats.
// plane wd: [8 bb][8 rows x 9 cols] u64 -> stride 576 per plane.
// ---------------------------------------------------------------------------
template<int NW, int NWC>
__global__ __launch_bounds__(320)
void k_convbin3(const u64* __restrict__ ps, const u64* __restrict__ pn,
                const u64* __restrict__ w, float* __restrict__ out,
                double* __restrict__ part, int Cout,
                const ushort* __restrict__ tP, const int* __restrict__ flags, int slot) {
    __shared__ u64 st_s[NWC * 576];
    __shared__ u64 st_n[NWC * 576];
    const int co = blockIdx.x, bg = blockIdx.y, b0 = bg * 8, t = threadIdx.x;
    const int fl = flags[slot];
    const bool act = t < 288;
    const int bb = act ? t / 36 : 0, r = act ? t - (t / 36) * 36 : 0;
    const int y = r / 6, x0 = r - y * 6;
    const u64* wb = w + (size_t)co * 9 * 2 * NW;
    int corr = 0, nv = 9;
    if (act && fl == 0) {
        const int ky0 = (y == 0), ky1 = (y == 5) ? 2 : 3;
        const int kx0 = (x0 == 0), kx1 = (x0 == 5) ? 2 : 3;
        const ushort* tb = tP + co * 16;
        int Wt = tb[15];
        int Wr = (int)tb[ky1 * 4 + kx1] - (int)tb[ky0 * 4 + kx1]
               - (int)tb[ky1 * 4 + kx0] + (int)tb[ky0 * 4 + kx0];
        corr = Wt - Wr;
        nv = (ky1 - ky0) * (kx1 - kx0);
    }
    int aV = 0, aD = 0, S = 0;
    #pragma unroll 1
    for (int c0 = 0; c0 < NW; c0 += NWC) {
        __syncthreads();
        for (int i = t; i < NWC * 576; i += 320) { st_s[i] = 0; if (fl) st_n[i] = 0; }
        __syncthreads();
        for (int i = t; i < 8 * 36 * NWC; i += 320) {
            int wd = i % NWC, j = (i / NWC) % 36, bb2 = i / (36 * NWC);
            int yy = j / 6, xx = j - yy * 6;
            int d = wd * 576 + bb2 * 72 + (yy + 1) * 9 + xx + 1;
            size_t g = ((size_t)(b0 + bb2) * 36 + j) * NW + c0 + wd;
            st_s[d] = ps[g];
            if (fl) st_n[d] = pn[g];
        }
        __syncthreads();
        if (act) {
            if (fl == 0) {
                #pragma unroll
                for (int ky = 0; ky < 3; ++ky)
                    #pragma unroll
                    for (int kx = 0; kx < 3; ++kx) {
                        const int vb = bb * 72 + (y + ky) * 9 + x0 + kx;
                        const u64* wp = wb + (ky * 3 + kx) * 2 * NW + 2 * c0;
                        #pragma unroll
                        for (int wd = 0; wd < NWC; ++wd)
                            S += (int)__popcll(st_s[wd * 576 + vb] ^ wp[2 * wd]);
                    }
            } else {
                #pragma unroll
                for (int ky = 0; ky < 3; ++ky)
                    #pragma unroll
                    for (int kx = 0; kx < 3; ++kx) {
                        const int vb = bb * 72 + (y + ky) * 9 + x0 + kx;
                        const u64* wp = wb + (ky * 3 + kx) * 2 * NW + 2 * c0;
                        #pragma unroll
                        for (int wd = 0; wd < NWC; ++wd) {
                            u64 vs = st_s[wd * 576 + vb], vn = st_n[wd * 576 + vb];
                            u64 val = vn & wp[2 * wd + 1];
                            u64 df  = (vs ^ wp[2 * wd]) & val;
                            aV += (int)__popcll(val); aD += (int)__popcll(df);
                        }
                    }
            }
        }
    }
    int s = (fl == 0) ? (64 * NW * nv - 2 * S + 2 * corr) : (aV - 2 * aD);
    if (act) out[((size_t)(b0 + bb) * Cout + co) * 36 + r] = (float)s;
    __syncthreads();
    int* si = (int*)st_s;
    long long* sq = (long long*)(si + 512);
    si[t] = act ? s : 0;
    sq[t] = act ? (long long)s * s : 0;
    __syncthreads();
    if (t < 64) { si[t] += si[t + 256]; sq[t] += sq[t + 256]; }
    __syncthreads();
    for (int o2 = 128; o2 > 0; o2 >>= 1) {
        if (t < o2) { si[t] += si[t + o2]; sq[t] += sq[t + o2]; }
        __syncthreads();
    }
    if (t == 0) {
        part[((size_t)co * 64 + bg) * 2]     = (double)si[0];
        part[((size_t)co * 64 + bg) * 2 + 1] = (double)sq[0];
    }
}

// ---------------------------------------------------------------------------
// conv5 (NW=4, chunks of 2) + in-LDS maxpool3x3/2 + stats on POOLED vals.
// ---------------------------------------------------------------------------
__global__ __launch_bounds__(320)
void k_conv5(const u64* __restrict__ ps, const u64* __restrict__ pn,
             const u64* __restrict__ w, float* __restrict__ outp,
             double* __restrict__ part, const ushort* __restrict__ tP,
             const int* __restrict__ flags) {
    __shared__ u64 st_s[2 * 576];
    __shared__ u64 st_n[2 * 576];
    __shared__ int sacc[8 * 36];
    const int co = blockIdx.x, bg = blockIdx.y, b0 = bg * 8, t = threadIdx.x;
    const int fl = flags[3];
    const bool act = t < 288;
    const int bb = act ? t / 36 : 0, r = act ? t - (t / 36) * 36 : 0;
    const int y = r / 6, x0 = r - y * 6;
    const u64* wb = w + (size_t)co * 9 * 2 * 4;
    int corr = 0, nv = 9;
    if (act && fl == 0) {
        const int ky0 = (y == 0), ky1 = (y == 5) ? 2 : 3;
        const int kx0 = (x0 == 0), kx1 = (x0 == 5) ? 2 : 3;
        const ushort* tb = tP + co * 16;
        int Wt = tb[15];
        int Wr = (int)tb[ky1 * 4 + kx1] - (int)tb[ky0 * 4 + kx1]
               - (int)tb[ky1 * 4 + kx0] + (int)tb[ky0 * 4 + kx0];
        corr = Wt - Wr;
        nv = (ky1 - ky0) * (kx1 - kx0);
    }
    int aV = 0, aD = 0, S = 0;
    #pragma unroll 1
    for (int c0 = 0; c0 < 4; c0 += 2) {
        __syncthreads();
        for (int i = t; i < 2 * 576; i += 320) { st_s[i] = 0; if (fl) st_n[i] = 0; }
        __syncthreads();
        for (int i = t; i < 8 * 36 * 2; i += 320) {
            int wd = i % 2, j = (i / 2) % 36, bb2 = i / 72;
            int yy = j / 6, xx = j - yy * 6;
            int d = wd * 576 + bb2 * 72 + (yy + 1) * 9 + xx + 1;
            size_t g = ((size_t)(b0 + bb2) * 36 + j) * 4 + c0 + wd;
            st_s[d] = ps[g];
            if (fl) st_n[d] = pn[g];
        }
        __syncthreads();
        if (act) {
            if (fl == 0) {
                #pragma unroll
                for (int ky = 0; ky < 3; ++ky)
                    #pragma unroll
                    for (int kx = 0; kx < 3; ++kx) {
                        const int vb = bb * 72 + (y + ky) * 9 + x0 + kx;
                        const u64* wp = wb + (ky * 3 + kx) * 8 + 2 * c0;
                        S += (int)__popcll(st_s[vb] ^ wp[0]);
                        S += (int)__popcll(st_s[576 + vb] ^ wp[2]);
                    }
            } else {
                #pragma unroll
                for (int ky = 0; ky < 3; ++ky)
                    #pragma unroll
                    for (int kx = 0; kx < 3; ++kx) {
                        const int vb = bb * 72 + (y + ky) * 9 + x0 + kx;
                        const u64* wp = wb + (ky * 3 + kx) * 8 + 2 * c0;
                        #pragma unroll
                        for (int wd = 0; wd < 2; ++wd) {
                            u64 vs = st_s[wd * 576 + vb], vn = st_n[wd * 576 + vb];
                            u64 val = vn & wp[2 * wd + 1];
                            u64 df  = (vs ^ wp[2 * wd]) & val;
                            aV += (int)__popcll(val); aD += (int)__popcll(df);
                        }
                    }
            }
        }
    }
    if (act) sacc[bb * 36 + r] = (fl == 0) ? (1024 * nv / 4 - 2 * S + 2 * corr) : (aV - 2 * aD);
    __syncthreads();
    int pooled = 0;
    const bool pact = t < 32;
    if (pact) {
        int bb2 = t / 4, wi = t % 4, py = (wi >> 1) * 2, px = (wi & 1) * 2;
        int best = -1000000;
        #pragma unroll
        for (int dy = 0; dy < 3; ++dy)
            #pragma unroll
            for (int dx = 0; dx < 3; ++dx)
                best = max(best, sacc[bb2 * 36 + (py + dy) * 6 + (px + dx)]);
        pooled = best;
        outp[((size_t)(b0 + bb2) * 256 + co) * 4 + wi] = (float)pooled;
    }
    __syncthreads();
    int* si = (int*)st_s;
    long long* sq = (long long*)(si + 512);
    si[t] = pact ? pooled : 0;
    sq[t] = pact ? (long long)pooled * pooled : 0;
    __syncthreads();
    if (t < 64) { si[t] += si[t + 256]; sq[t] += sq[t + 256]; }
    __syncthreads();
    for (int o2 = 128; o2 > 0; o2 >>= 1) {
        if (t < o2) { si[t] += si[t + o2]; sq[t] += sq[t + o2]; }
        __syncthreads();
    }
    if (t == 0) {
        part[((size_t)co * 64 + bg) * 2]     = (double)si[0];
        part[((size_t)co * 64 + bg) * 2 + 1] = (double)sq[0];
    }
}

// ---------------------------------------------------------------------------
__global__ void k_stats_final(const double* __restrict__ part, const float* __restrict__ g,
                              float* __restrict__ mean, float* __restrict__ inva,
                              int NB, long total) {
    __shared__ double sS[64], sQ[64];
    const int c = blockIdx.x, t = threadIdx.x;
    double s = 0.0, q = 0.0;
    for (int k = t; k < NB; k += 64) {
        s += part[((size_t)c * NB + k) * 2];
        q += part[((size_t)c * NB + k) * 2 + 1];
    }
    sS[t] = s; sQ[t] = q;
    __syncthreads();
    for (int o = 32; o > 0; o >>= 1) {
        if (t < o) { sS[t] += sS[t + o]; sQ[t] += sQ[t + o]; }
        __syncthreads();
    }
    if (t == 0) {
        double m = sS[0] / (double)total;
        double var = sQ[0] / (double)total - m * m;
        mean[c] = (float)m;
        inva[c] = g[c] * (float)(1.0 / sqrt(var + 1e-5));
    }
}

// ---- BN apply + sign + pack (2d) -> separate sign / nz arrays ----
__global__ void k_bnpack2d(const float* __restrict__ x, const float* __restrict__ m,
                           const float* __restrict__ a, const float* __restrict__ bt,
                           u64* __restrict__ ps, u64* __restrict__ pn,
                           int B, int C, int HW, int* flag) {
    int NW = (C + 63) >> 6;
    int tot = B * HW * NW;
    int idx = blockIdx.x * blockDim.x + threadIdx.x;
    if (idx >= tot) return;
    int wd = idx % NW, t = idx / NW;
    int j = t % HW, b = t / HW;
    u64 s = 0, nz = 0;
    for (int c0 = 0; c0 < 64; ++c0) {
        int c = wd * 64 + c0;
        if (c >= C) break;
        float v = (x[((size_t)b * C + c) * HW + j] - m[c]) * a[c] + bt[c];
        if (v > 0.0f) s |= (1ull << c0);
        if (v != 0.0f) nz |= (1ull << c0);
    }
    size_t o = ((size_t)b * HW + j) * NW + wd;
    ps[o] = s; pn[o] = nz;
    if (nz != ~0ull) atomicOr(flag, 1);
}

__global__ void k_bnpack_flat(const float* __restrict__ x, const float* __restrict__ m,
                              const float* __restrict__ a, const float* __restrict__ bt,
                              u64* __restrict__ ps, u64* __restrict__ pn,
                              int B, int* flag) {
    int idx = blockIdx.x * blockDim.x + threadIdx.x;
    if (idx >= B * 16) return;
    int wd = idx % 16, b = idx / 16;
    u64 s = 0, nz = 0;
    for (int k = 0; k < 64; ++k) {
        int f = wd * 64 + k;
        int c = f >> 2, j = f & 3;
        float v = (x[((size_t)b * 256 + c) * 4 + j] - m[c]) * a[c] + bt[c];
        if (v > 0.0f) s |= (1ull << k);
        if (v != 0.0f) nz |= (1ull << k);
    }
    ps[(size_t)b * 16 + wd] = s;
    pn[(size_t)b * 16 + wd] = nz;
    if (nz != ~0ull) atomicOr(flag, 1);
}

__global__ void k_bnpack1d(const float* __restrict__ x, const float* __restrict__ m,
                           const float* __restrict__ a, const float* __restrict__ bt,
                           u64* __restrict__ ps, u64* __restrict__ pn,
                           int B, int F, int* flag) {
    int NW = F >> 6;
    int idx = blockIdx.x * blockDim.x + threadIdx.x;
    if (idx >= B * NW) return;
    int wd = idx % NW, b = idx / NW;
    const float* row = x + (size_t)b * F + wd * 64;
    u64 s = 0, nz = 0;
    for (int c = 0; c < 64; ++c) {
        int f = wd * 64 + c;
        float v = (row[c] - m[f]) * a[f] + bt[f];
        if (v > 0.0f) s |= (1ull << c);
        if (v != 0.0f) nz |= (1ull << c);
    }
    ps[(size_t)b * NW + wd] = s;
    pn[(size_t)b * NW + wd] = nz;
    if (nz != ~0ull) atomicOr(flag, 1);
}

// ---------------------------------------------------------------------------
// binary FC, 16x16 tiled, SoA LDS; Ws row stride NW|1 (odd -> no conflicts).
// ---------------------------------------------------------------------------
template<int NW>
__global__ __launch_bounds__(256)
void k_fcbin2(const u64* __restrict__ As_, const u64* __restrict__ An_,
              const u64* __restrict__ Ws_, const u64* __restrict__ Wn_,
              const float* __restrict__ bias, float* __restrict__ C, int O,
              double* __restrict__ part, int nbc, const int* __restrict__ flags, int slot) {
    constexpr int ST = NW | 1;   // odd row stride
    __shared__ u64 sA[16 * ST];
    __shared__ u64 sW[16 * ST];
    __shared__ u64 sAn[16 * ST];
    __shared__ u64 sWn[16 * ST];
    __shared__ int sacc[16][16];
    const int t = threadIdx.x;
    const int fl = flags[slot];
    const int b0 = blockIdx.y * 16, o0 = blockIdx.x * 16;
    for (int i = t; i < 16 * NW; i += 256) {
        int rr = i / NW, cc = i % NW;
        sA[rr * ST + cc] = As_[(size_t)(b0 + rr) * NW + cc];
        int o = o0 + rr;
        sW[rr * ST + cc] = (o < O) ? Ws_[(size_t)o * NW + cc] : 0ull;
        if (fl) {
            sAn[rr * ST + cc] = An_[(size_t)(b0 + rr) * NW + cc];
            sWn[rr * ST + cc] = (o < O) ? Wn_[(size_t)o * NW + cc] : 0ull;
        }
    }
    __syncthreads();
    const int tx = t % 16, ty = t / 16;
    int acc;
    if (fl == 0) {
        int S = 0;
        #pragma unroll
        for (int wd = 0; wd < NW; ++wd)
            S += (int)__popcll(sA[ty * ST + wd] ^ sW[tx * ST + wd]);
        acc = 64 * NW - 2 * S;
    } else {
        int aV = 0, aD = 0;
        #pragma unroll
        for (int wd = 0; wd < NW; ++wd) {
            u64 val = sAn[ty * ST + wd] & sWn[tx * ST + wd];
            u64 df  = (sA[ty * ST + wd] ^ sW[tx * ST + wd]) & val;
            aV += (int)__popcll(val); aD += (int)__popcll(df);
        }
        acc = aV - 2 * aD;
    }
    int o = o0 + tx;
    if (o < O)
        C[(size_t)(b0 + ty) * O + o] = (float)acc + (bias ? bias[o] : 0.0f);
    sacc[ty][tx] = (o < O) ? acc : 0;
    __syncthreads();
    if (part != nullptr && ty == 0) {
        int s = 0; long long q = 0;
        #pragma unroll
        for (int b = 0; b < 16; ++b) {
            int v = sacc[b][tx];
            s += v; q += (long long)v * v;
        }
        part[((size_t)(o0 + tx) * nbc + blockIdx.y) * 2]     = (double)s;
        part[((size_t)(o0 + tx) * nbc + blockIdx.y) * 2 + 1] = (double)q;
    }
}

// ---------------------------------------------------------------------------

static inline int cdiv(long a, int b) { return (int)((a + b - 1) / b); }

extern "C" void kernel_launch(void* const* d_in, const int* in_sizes, int n_in,
                              void* d_out, int out_size, void* d_ws, size_t ws_size,
                              hipStream_t stream) {
    const float* x   = (const float*)d_in[0];
    const float* w1  = (const float*)d_in[1];
    const float* g1  = (const float*)d_in[2];
    const float* b1  = (const float*)d_in[3];
    const float* w2  = (const float*)d_in[4];
    const float* g2  = (const float*)d_in[5];
    const float* b2  = (const float*)d_in[6];
    const float* w3  = (const float*)d_in[7];
    const float* g3  = (const float*)d_in[8];
    const float* b3  = (const float*)d_in[9];
    const float* w4  = (const float*)d_in[10];
    const float* g4  = (const float*)d_in[11];
    const float* b4  = (const float*)d_in[12];
    const float* w5  = (const float*)d_in[13];
    const float* g5  = (const float*)d_in[14];
    const float* b5  = (const float*)d_in[15];
    const float* wl1 = (const float*)d_in[16];
    const float* gl1 = (const float*)d_in[17];
    const float* bl1 = (const float*)d_in[18];
    const float* wl2 = (const float*)d_in[19];
    const float* gl2 = (const float*)d_in[20];
    const float* bl2 = (const float*)d_in[21];
    const float* wl3 = (const float*)d_in[22];
    const float* bl3 = (const float*)d_in[23];
    float* out = (float*)d_out;
    (void)in_sizes; (void)n_in; (void)out_size; (void)ws_size;

    char* base = (char*)d_ws;
    size_t off = 0;
    auto alloc = [&](size_t bytes) {
        char* p = base + off;
        off += (bytes + 15) & ~(size_t)15;
        return (void*)p;
    };
    float* R1   = (float*)alloc(7372800 * 4);
    float* R2   = (float*)alloc(4718592 * 4);
    float* R3   = (float*)alloc(524288 * 4);
    float* w1s  = (float*)alloc(4800 * 4);
    u64* p1s = (u64*)alloc(115200 * 8);   u64* p1n = (u64*)alloc(115200 * 8);
    u64* p2s = (u64*)alloc(55296 * 8);    u64* p2n = (u64*)alloc(55296 * 8);
    u64* p3s = (u64*)alloc(110592 * 8);   u64* p3n = (u64*)alloc(110592 * 8);
    u64* p4s = (u64*)alloc(73728 * 8);    u64* p4n = (u64*)alloc(73728 * 8);
    u64* p5s = (u64*)alloc(8192 * 8);     u64* p5n = (u64*)alloc(8192 * 8);
    u64* pf1s = (u64*)alloc(32768 * 8);   u64* pf1n = (u64*)alloc(32768 * 8);
    u64* pf2s = (u64*)alloc(16384 * 8);   u64* pf2n = (u64*)alloc(16384 * 8);
    u64* w2p  = (u64*)alloc(9600 * 8);
    u64* w3p  = (u64*)alloc(20736 * 8);
    u64* w4p  = (u64*)alloc(27648 * 8);
    u64* w5p  = (u64*)alloc(18432 * 8);
    u64* wl1s_ = (u64*)alloc(65536 * 8);  u64* wl1n_ = (u64*)alloc(65536 * 8);
    u64* wl2s_ = (u64*)alloc(131072 * 8); u64* wl2n_ = (u64*)alloc(131072 * 8);
    u64* wl3s_ = (u64*)alloc(320 * 8);    u64* wl3n_ = (u64*)alloc(320 * 8);
    double* part = (double*)alloc((size_t)4096 * 32 * 2 * 8);
    float* stats = (float*)alloc(7 * 2 * 4096 * 4);
    int*    flags = (int*)alloc(8 * 4);
    ushort* t2 = (ushort*)alloc(192 * 4 * 2);
    ushort* t3 = (ushort*)alloc(384 * 16 * 2);
    ushort* t4 = (ushort*)alloc(256 * 16 * 2);
    ushort* t5 = (ushort*)alloc(256 * 16 * 2);
    float* m_[7]; float* a_[7];
    for (int l = 0; l < 7; ++l) { m_[l] = stats + (size_t)l * 8192; a_[l] = m_[l] + 4096; }

    hipMemsetAsync(flags, 0, 8 * 4, stream);

    // ---- weight prep ----
    k_prep<<<cdiv(PREP_TOTAL, 256), 256, 0, stream>>>(
        w1, w1s, w2, w2p, w3, w3p, w4, w4p, w5, w5p,
        wl1, wl1s_, wl1n_, wl2, wl2s_, wl2n_, wl3, wl3s_, wl3n_, flags);
    k_prep2<<<cdiv(192 + 384 + 256 + 256, 256), 256, 0, stream>>>(
        w2p, w3p, w4p, w5p, t2, t3, t4, t5);

    // ---- conv1 + pool -> R1 (+stats); bn1; pack -> p1 ----
    k_conv1<<<dim3(8, 512), 256, 0, stream>>>(x, w1s, R1, part);
    k_stats_final<<<64, 64, 0, stream>>>(part, g1, m_[0], a_[0], 512, (long)512 * 225);
    k_bnpack2d<<<cdiv((long)512 * 225, 256), 256, 0, stream>>>(R1, m_[0], a_[0], b1, p1s, p1n, 512, 64, 225, flags + 0);

    // ---- conv2 + pool -> R2 (+stats); bn2; pack -> p2 ----
    k_conv2<<<dim3(192, 64), 320, 0, stream>>>(p1s, p1n, w2p, R2, part, t2, flags);
    k_stats_final<<<192, 64, 0, stream>>>(part, g2, m_[1], a_[1], 64, (long)512 * 36);
    k_bnpack2d<<<cdiv((long)512 * 36 * 3, 256), 256, 0, stream>>>(R2, m_[1], a_[1], b2, p2s, p2n, 512, 192, 36, flags + 1);

    // ---- conv3 -> R1 (+stats); bn3; pack -> p3 ----
    k_convbin3<3, 3><<<dim3(384, 64), 320, 0, stream>>>(p2s, p2n, w3p, R1, part, 384, t3, flags, 1);
    k_stats_final<<<384, 64, 0, stream>>>(part, g3, m_[2], a_[2], 64, (long)512 * 36);
    k_bnpack2d<<<cdiv((long)512 * 36 * 6, 256), 256, 0, stream>>>(R1, m_[2], a_[2], b3, p3s, p3n, 512, 384, 36, flags + 2);

    // ---- conv4 -> R2 (+stats); bn4; pack -> p4 ----
    k_convbin3<6, 3><<<dim3(256, 64), 320, 0, stream>>>(p3s, p3n, w4p, R2, part, 256, t4, flags, 2);
    k_stats_final<<<256, 64, 0, stream>>>(part, g4, m_[3], a_[3], 64, (long)512 * 36);
    k_bnpack2d<<<cdiv((long)512 * 36 * 4, 256), 256, 0, stream>>>(R2, m_[3], a_[3], b4, p4s, p4n, 512, 256, 36, flags + 3);

    // ---- conv5 + in-LDS pool -> R3 (+stats on pooled); bn5; flat-pack -> p5 ----
    k_conv5<<<dim3(256, 64), 320, 0, stream>>>(p4s, p4n, w5p, R3, part, t5, flags);
    k_stats_final<<<256, 64, 0, stream>>>(part, g5, m_[4], a_[4], 64, (long)512 * 4);
    k_bnpack_flat<<<cdiv(512 * 16, 256), 256, 0, stream>>>(R3, m_[4], a_[4], b5, p5s, p5n, 512, flags + 4);

    // ---- fc1 -> R2 (+stats); bn; pack -> pf1 ----
    k_fcbin2<16><<<dim3(256, 32), 256, 0, stream>>>(p5s, p5n, wl1s_, wl1n_, nullptr, R2, 4096, part, 32, flags, 4);
    k_stats_final<<<4096, 64, 0, stream>>>(part, gl1, m_[5], a_[5], 32, 512);
    k_bnpack1d<<<cdiv(512 * 64, 256), 256, 0, stream>>>(R2, m_[5], a_[5], bl1, pf1s, pf1n, 512, 4096, flags + 5);

    // ---- fc2 -> R1 (+stats); bn; pack -> pf2 ----
    k_fcbin2<64><<<dim3(128, 32), 256, 0, stream>>>(pf1s, pf1n, wl2s_, wl2n_, nullptr, R1, 2048, part, 32, flags, 5);
    k_stats_final<<<2048, 64, 0, stream>>>(part, gl2, m_[6], a_[6], 32, 512);
    k_bnpack1d<<<cdiv(512 * 32, 256), 256, 0, stream>>>(R1, m_[6], a_[6], bl2, pf2s, pf2n, 512, 2048, flags + 6);

    // ---- fc3 + bias -> out [512,10] ----
    k_fcbin2<32><<<dim3(1, 32), 256, 0, stream>>>(pf2s, pf2n, wl3s_, wl3n_, bl3, out, 10, nullptr, 0, flags, 6);
}

// Round 8
// 721.442 us; speedup vs baseline: 56.3187x; 1.1237x over previous
//
#include <hip/hip_runtime.h>
#include <math.h>

// ---------------------------------------------------------------------------
// BinAlexNet forward — round 8: CO=4 output-channel blocking (each staged
// activation word feeds 4 channels' XOR+popc -> ds_reads /4), sign-only LDS
// (slow exact path reads global directly, flag-gated, never taken here),
// 2x2 micro-tiled FCs, wave-shuffle stats reductions.
// ---------------------------------------------------------------------------

typedef unsigned long long u64;

__device__ __forceinline__ float sgn(float x) {
    return (float)((x > 0.0f) - (x < 0.0f));
}

__device__ __forceinline__ void wred_i(int& s, long long& q) {
    #pragma unroll
    for (int o = 32; o > 0; o >>= 1) {
        s += __shfl_down(s, o, 64);
        q += __shfl_down(q, o, 64);
    }
}
__device__ __forceinline__ void wred_d(double& s, double& q) {
    #pragma unroll
    for (int o = 32; o > 0; o >>= 1) {
        s += __shfl_down(s, o, 64);
        q += __shfl_down(q, o, 64);
    }
}

// flag slots: 0:conv2 1:conv3 2:conv4 3:conv5 4:fc1 5:fc2 6:fc3
// ---------------------------------------------------------------------------
__device__ void pack_conv_one(int idx, const float* __restrict__ w,
                              u64* __restrict__ wp, int Cout, int Cin, int KK,
                              int* flag) {
    int NW = (Cin + 63) >> 6;
    int wd = idx % NW, t = idx / NW;
    int tap = t % KK, co = t / KK;
    u64 s = 0, nz = 0;
    for (int c = 0; c < 64; ++c) {
        int ci = wd * 64 + c;
        if (ci >= Cin) break;
        float v = w[((size_t)co * Cin + ci) * KK + tap];
        if (v > 0.0f) s |= (1ull << c);
        if (v != 0.0f) nz |= (1ull << c);
    }
    u64* o = wp + ((size_t)co * KK + tap) * 2 * NW + 2 * wd;
    o[0] = s; o[1] = nz;
    if (nz != ~0ull) atomicOr(flag, 1);
}

__device__ void pack_fc_one(int idx, const float* __restrict__ w,
                            u64* __restrict__ ws_, u64* __restrict__ wn_,
                            int Kd, int* flag) {
    int NW = Kd >> 6;
    int wd = idx % NW, o = idx / NW;
    const float* row = w + (size_t)o * Kd + wd * 64;
    u64 s = 0, nz = 0;
    for (int c = 0; c < 64; ++c) {
        float v = row[c];
        if (v > 0.0f) s |= (1ull << c);
        if (v != 0.0f) nz |= (1ull << c);
    }
    ws_[(size_t)o * NW + wd] = s;
    wn_[(size_t)o * NW + wd] = nz;
    if (nz != ~0ull) atomicOr(flag, 1);
}

#define PN0 4800
#define PN1 4800
#define PN2 10368
#define PN3 13824
#define PN4 9216
#define PN5 65536
#define PN6 131072
#define PN7 320
#define PREP_TOTAL (PN0+PN1+PN2+PN3+PN4+PN5+PN6+PN7)   // 239936

__global__ void k_prep(const float* w1, float* w1s,
                       const float* w2, u64* w2p,
                       const float* w3, u64* w3p,
                       const float* w4, u64* w4p,
                       const float* w5, u64* w5p,
                       const float* wl1, u64* wl1s_, u64* wl1n_,
                       const float* wl2, u64* wl2s_, u64* wl2n_,
                       const float* wl3, u64* wl3s_, u64* wl3n_,
                       int* flags) {
    int idx = blockIdx.x * blockDim.x + threadIdx.x;
    int r = idx;
    if (r < PN0) { w1s[r] = sgn(w1[r]); return; } r -= PN0;
    if (r < PN1) { pack_conv_one(r, w2, w2p, 192, 64, 25, flags + 0); return; } r -= PN1;
    if (r < PN2) { pack_conv_one(r, w3, w3p, 384, 192, 9, flags + 1); return; } r -= PN2;
    if (r < PN3) { pack_conv_one(r, w4, w4p, 256, 384, 9, flags + 2); return; } r -= PN3;
    if (r < PN4) { pack_conv_one(r, w5, w5p, 256, 256, 9, flags + 3); return; } r -= PN4;
    if (r < PN5) { pack_fc_one(r, wl1, wl1s_, wl1n_, 1024, flags + 4); return; } r -= PN5;
    if (r < PN6) { pack_fc_one(r, wl2, wl2s_, wl2n_, 4096, flags + 5); return; } r -= PN6;
    if (r < PN7) { pack_fc_one(r, wl3, wl3s_, wl3n_, 2048, flags + 6); return; }
}

// ---------------------------------------------------------------------------
// prep2: per-channel weight-sign popcount tables (pad correction).
// ---------------------------------------------------------------------------
__device__ void prefix3(const u64* __restrict__ wb, int NW, ushort* __restrict__ o) {
    int cs[9];
    #pragma unroll
    for (int tap = 0; tap < 9; ++tap) {
        int s = 0;
        for (int wd = 0; wd < NW; ++wd)
            s += (int)__popcll(wb[tap * 2 * NW + 2 * wd]);
        cs[tap] = s;
    }
    int P[4][4];
    P[0][0] = 0; P[0][1] = 0; P[0][2] = 0; P[0][3] = 0;
    P[1][0] = 0; P[2][0] = 0; P[3][0] = 0;
    P[1][1] = cs[0];                 P[1][2] = cs[0] + cs[1];                 P[1][3] = cs[0] + cs[1] + cs[2];
    P[2][1] = cs[0] + cs[3];         P[2][2] = cs[0] + cs[1] + cs[3] + cs[4]; P[2][3] = P[1][3] + cs[3] + cs[4] + cs[5];
    P[3][1] = cs[0] + cs[3] + cs[6]; P[3][2] = P[2][2] + cs[6] + cs[7];       P[3][3] = P[2][3] + cs[6] + cs[7] + cs[8];
    #pragma unroll
    for (int i = 0; i < 4; ++i)
        #pragma unroll
        for (int j = 0; j < 4; ++j)
            o[i * 4 + j] = (ushort)P[i][j];
}

__global__ void k_prep2(const u64* w2p, const u64* w3p, const u64* w4p, const u64* w5p,
                        ushort* t2, ushort* t3, ushort* t4, ushort* t5) {
    int idx = blockIdx.x * blockDim.x + threadIdx.x;
    if (idx < 192) {
        const u64* wb = w2p + idx * 50;
        int cnt[25];
        #pragma unroll
        for (int tap = 0; tap < 25; ++tap) cnt[tap] = (int)__popcll(wb[tap * 2]);
        int R1 = 0, C1 = 0;
        #pragma unroll
        for (int k = 0; k < 5; ++k) { R1 += cnt[k]; C1 += cnt[k * 5]; }
        t2[idx * 4 + 0] = (ushort)R1;
        t2[idx * 4 + 1] = (ushort)C1;
        t2[idx * 4 + 2] = (ushort)cnt[0];
        t2[idx * 4 + 3] = 0;
        return;
    }
    idx -= 192;
    if (idx < 384) { prefix3(w3p + (size_t)idx * 54, 3, t3 + idx * 16); return; }
    idx -= 384;
    if (idx < 256) { prefix3(w4p + (size_t)idx * 108, 6, t4 + idx * 16); return; }
    idx -= 256;
    if (idx < 256) { prefix3(w5p + (size_t)idx * 72, 4, t5 + idx * 16); return; }
}

// ---------------------------------------------------------------------------
// conv1: fp32, LDS image, fused pool + stats (wave-shuffle epilogue)
// ---------------------------------------------------------------------------
__global__ __launch_bounds__(256)
void k_conv1(const float* __restrict__ x, const float* __restrict__ w1s,
             float* __restrict__ out, double* __restrict__ part) {
    __shared__ float sx[3 * 34 * 34];
    __shared__ double sWv[4], sQv[4];
    const int b = blockIdx.y, cg = blockIdx.x, t = threadIdx.x;
    for (int i = t; i < 3 * 34 * 34; i += 256) sx[i] = 0.0f;
    __syncthreads();
    for (int i = t; i < 3072; i += 256) {
        int ch = i >> 10, rem = i & 1023, yy = rem >> 5, xx = rem & 31;
        sx[(ch * 34 + yy + 1) * 34 + xx + 1] = x[(size_t)b * 3072 + i];
    }
    __syncthreads();
    const bool act = t < 225;
    const int py = act ? t / 15 : 0, px = act ? t % 15 : 0;
    float a0[8], a1[8], a2[8], a3[8];
    #pragma unroll
    for (int c = 0; c < 8; ++c) { a0[c] = a1[c] = a2[c] = a3[c] = 0.f; }
    #pragma unroll 1
    for (int ch = 0; ch < 3; ++ch) {
        const float* wc = w1s + (size_t)(cg * 8) * 75 + ch * 25;
        #pragma unroll 1
        for (int yy6 = 0; yy6 < 6; ++yy6) {
            const float2* rp = (const float2*)&sx[(ch * 34 + py * 2 + yy6) * 34 + px * 2];
            float2 ra = rp[0], rb = rp[1], rc = rp[2];
            float r[6] = {ra.x, ra.y, rb.x, rb.y, rc.x, rc.y};
            if (yy6 <= 4) {
                #pragma unroll
                for (int kx = 0; kx < 5; ++kx)
                    #pragma unroll
                    for (int cc = 0; cc < 8; ++cc) {
                        float wv = wc[cc * 75 + yy6 * 5 + kx];
                        a0[cc] = fmaf(r[kx],     wv, a0[cc]);
                        a1[cc] = fmaf(r[kx + 1], wv, a1[cc]);
                    }
            }
            if (yy6 >= 1) {
                #pragma unroll
                for (int kx = 0; kx < 5; ++kx)
                    #pragma unroll
                    for (int cc = 0; cc < 8; ++cc) {
                        float wv = wc[cc * 75 + (yy6 - 1) * 5 + kx];
                        a2[cc] = fmaf(r[kx],     wv, a2[cc]);
                        a3[cc] = fmaf(r[kx + 1], wv, a3[cc]);
                    }
            }
        }
    }
    const int wid = t >> 6, lane = t & 63;
    #pragma unroll
    for (int cc = 0; cc < 8; ++cc) {
        float best = 0.f;
        if (act) {
            best = fmaxf(fmaxf(a0[cc], a1[cc]), fmaxf(a2[cc], a3[cc]));
            out[((size_t)b * 64 + cg * 8 + cc) * 225 + t] = best;
        }
        double v = act ? (double)best : 0.0;
        double q = v * v;
        wred_d(v, q);
        if (lane == 0) { sWv[wid] = v; sQv[wid] = q; }
        __syncthreads();
        if (t == 0) {
            double s = sWv[0] + sWv[1] + sWv[2] + sWv[3];
            double qq = sQv[0] + sQv[1] + sQv[2] + sQv[3];
            part[((size_t)(cg * 8 + cc) * 512 + b) * 2]     = s;
            part[((size_t)(cg * 8 + cc) * 512 + b) * 2 + 1] = qq;
        }
        __syncthreads();
    }
}

// ---------------------------------------------------------------------------
// conv2 (K=5, NW=1) + maxpool2x2 + fused stats. CO=4. grid (48, 64), 320 thr.
// ---------------------------------------------------------------------------
__global__ __launch_bounds__(320)
void k_conv2(const u64* __restrict__ ps, const u64* __restrict__ pn,
             const u64* __restrict__ w, float* __restrict__ out,
             double* __restrict__ part, const ushort* __restrict__ t2,
             const int* __restrict__ flags) {
    __shared__ u64 st_s[8 * 17 * 17];
    __shared__ int sWi[5];
    __shared__ long long sWq[5];
    const int co0 = blockIdx.x * 4, bg = blockIdx.y, b0 = bg * 8, t = threadIdx.x;
    const int fl = flags[0];
    for (int i = t; i < 8 * 289; i += 320) st_s[i] = 0;
    __syncthreads();
    for (int i = t; i < 8 * 225; i += 320) {
        int bb = i / 225, j = i - bb * 225;
        int yy = j / 15, xx = j - yy * 15;
        st_s[(bb * 17 + yy + 1) * 17 + xx + 1] = ps[(size_t)(b0 + bb) * 225 + j];
    }
    __syncthreads();
    const bool act = t < 288;
    const int bb = act ? t / 36 : 0, r = act ? t - (t / 36) * 36 : 0;
    const int py = r / 6, px = r - py * 6;
    int best[4] = {0, 0, 0, 0};
    if (act) {
        if (fl == 0) {
            int S0[4] = {0,0,0,0}, S1[4] = {0,0,0,0}, S2[4] = {0,0,0,0}, S3[4] = {0,0,0,0};
            #pragma unroll 1
            for (int yy6 = 0; yy6 < 6; ++yy6) {
                const int base = (bb * 17 + py * 2 + yy6) * 17 + px * 2;
                u64 V[6];
                #pragma unroll
                for (int k = 0; k < 6; ++k) V[k] = st_s[base + k];
                if (yy6 <= 4) {
                    #pragma unroll
                    for (int kx = 0; kx < 5; ++kx) {
                        #pragma unroll
                        for (int cc = 0; cc < 4; ++cc) {
                            u64 ws_ = w[(size_t)(co0 + cc) * 50 + (yy6 * 5 + kx) * 2];
                            S0[cc] += (int)__popcll(V[kx] ^ ws_);
                            S1[cc] += (int)__popcll(V[kx + 1] ^ ws_);
                        }
                    }
                }
                if (yy6 >= 1) {
                    #pragma unroll
                    for (int kx = 0; kx < 5; ++kx) {
                        #pragma unroll
                        for (int cc = 0; cc < 4; ++cc) {
                            u64 ws_ = w[(size_t)(co0 + cc) * 50 + ((yy6 - 1) * 5 + kx) * 2];
                            S2[cc] += (int)__popcll(V[kx] ^ ws_);
                            S3[cc] += (int)__popcll(V[kx + 1] ^ ws_);
                        }
                    }
                }
            }
            const int py0 = (py == 0), px0 = (px == 0);
            #pragma unroll
            for (int cc = 0; cc < 4; ++cc) {
                const ushort* tb = t2 + (co0 + cc) * 4;
                const int R1 = tb[0], C1 = tb[1], X = tb[2];
                int d0 = 64 * (5 - py0) * (5 - px0) - 2 * S0[cc] + 2 * (py0 * R1 + px0 * C1 - py0 * px0 * X);
                int d1 = 64 * (5 - py0) * 5 - 2 * S1[cc] + 2 * (py0 * R1);
                int d2 = 64 * 5 * (5 - px0) - 2 * S2[cc] + 2 * (px0 * C1);
                int d3 = 1600 - 2 * S3[cc];
                best[cc] = max(max(d0, d1), max(d2, d3));
            }
        } else {
            // exact masked path: bounds-checked global reads (flag-gated)
            #pragma unroll 1
            for (int cc = 0; cc < 4; ++cc) {
                const u64* wb = w + (size_t)(co0 + cc) * 50;
                int bst = -1000000;
                for (int dy = 0; dy < 2; ++dy)
                    for (int dx = 0; dx < 2; ++dx) {
                        int yc = py * 2 + dy, xc = px * 2 + dx;
                        int sum = 0;
                        for (int ky = 0; ky < 5; ++ky) {
                            int yy = yc - 1 + ky;
                            if ((unsigned)yy >= 15u) continue;
                            for (int kx = 0; kx < 5; ++kx) {
                                int xx = xc - 1 + kx;
                                if ((unsigned)xx >= 15u) continue;
                                size_t g = (size_t)(b0 + bb) * 225 + yy * 15 + xx;
                                u64 val = pn[g] & wb[(ky * 5 + kx) * 2 + 1];
                                u64 df  = (ps[g] ^ wb[(ky * 5 + kx) * 2]) & val;
                                sum += (int)__popcll(val) - 2 * (int)__popcll(df);
                            }
                        }
                        bst = max(bst, sum);
                    }
                best[cc] = bst;
            }
        }
        #pragma unroll
        for (int cc = 0; cc < 4; ++cc)
            out[((size_t)(b0 + bb) * 192 + co0 + cc) * 36 + r] = (float)best[cc];
    }
    const int wid = t >> 6, lane = t & 63;
    #pragma unroll 1
    for (int cc = 0; cc < 4; ++cc) {
        int v = act ? best[cc] : 0;
        long long q = (long long)v * v;
        wred_i(v, q);
        if (lane == 0) { sWi[wid] = v; sWq[wid] = q; }
        __syncthreads();
        if (t == 0) {
            int s = sWi[0] + sWi[1] + sWi[2] + sWi[3] + sWi[4];
            long long qq = sWq[0] + sWq[1] + sWq[2] + sWq[3] + sWq[4];
            part[((size_t)(co0 + cc) * 64 + bg) * 2]     = (double)s;
            part[((size_t)(co0 + cc) * 64 + bg) * 2 + 1] = (double)qq;
        }
        __syncthreads();
    }
}

// ---------------------------------------------------------------------------
// 3x3 pad-1 binary conv on 6x6 (conv3/conv4). CO=4, sign-only LDS planes.
// grid (Cout/4, 64), 320 thr.
// ---------------------------------------------------------------------------
template<int NW, int NWC>
__global__ __launch_bounds__(320)
void k_convbin3(const u64* __restrict__ ps, const u64* __restrict__ pn,
                const u64* __restrict__ w, float* __restrict__ out,
                double* __restrict__ part, int Cout,
                const ushort* __restrict__ tP, const int* __restrict__ flags, int slot) {
    __shared__ u64 st_s[NWC * 576];
    __shared__ int sWi[5];
    __shared__ long long sWq[5];
    const int co0 = blockIdx.x * 4, bg = blockIdx.y, b0 = bg * 8, t = threadIdx.x;
    const int fl = flags[slot];
    const bool act = t < 288;
    const int bb = act ? t / 36 : 0, r = act ? t - (t / 36) * 36 : 0;
    const int y = r / 6, x0 = r - y * 6;
    int S[4] = {0, 0, 0, 0};
    #pragma unroll 1
    for (int c0 = 0; c0 < NW; c0 += NWC) {
        __syncthreads();
        for (int i = t; i < NWC * 576; i += 320) st_s[i] = 0;
        __syncthreads();
        for (int i = t; i < 8 * 36 * NWC; i += 320) {
            int wd = i % NWC, j = (i / NWC) % 36, bb2 = i / (36 * NWC);
            int yy = j / 6, xx = j - yy * 6;
            st_s[wd * 576 + bb2 * 72 + (yy + 1) * 9 + xx + 1] =
                ps[((size_t)(b0 + bb2) * 36 + j) * NW + c0 + wd];
        }
        __syncthreads();
        if (act && fl == 0) {
            #pragma unroll
            for (int ky = 0; ky < 3; ++ky)
                #pragma unroll
                for (int kx = 0; kx < 3; ++kx) {
                    const int vb = bb * 72 + (y + ky) * 9 + x0 + kx;
                    #pragma unroll
                    for (int wd = 0; wd < NWC; ++wd) {
                        u64 a = st_s[wd * 576 + vb];
                        #pragma unroll
                        for (int cc = 0; cc < 4; ++cc) {
                            u64 ws_ = w[((size_t)(co0 + cc) * 9 + ky * 3 + kx) * 2 * NW + 2 * (c0 + wd)];
                            S[cc] += (int)__popcll(a ^ ws_);
                        }
                    }
                }
        }
    }
    int sv[4];
    if (fl == 0) {
        const int ky0 = (y == 0), ky1 = (y == 5) ? 2 : 3;
        const int kx0 = (x0 == 0), kx1 = (x0 == 5) ? 2 : 3;
        const int nv = (ky1 - ky0) * (kx1 - kx0);
        #pragma unroll
        for (int cc = 0; cc < 4; ++cc) {
            const ushort* tb = tP + (co0 + cc) * 16;
            int Wt = tb[15];
            int Wr = (int)tb[ky1 * 4 + kx1] - (int)tb[ky0 * 4 + kx1]
                   - (int)tb[ky1 * 4 + kx0] + (int)tb[ky0 * 4 + kx0];
            sv[cc] = 64 * NW * nv - 2 * S[cc] + 2 * (Wt - Wr);
        }
    } else {
        // exact masked path: bounds-checked global reads (flag-gated)
        #pragma unroll 1
        for (int cc = 0; cc < 4; ++cc) {
            int sum = 0;
            if (act) {
                const u64* wb = w + (size_t)(co0 + cc) * 9 * 2 * NW;
                for (int ky = 0; ky < 3; ++ky) {
                    int yy = y - 1 + ky;
                    if ((unsigned)yy >= 6u) continue;
                    for (int kx = 0; kx < 3; ++kx) {
                        int xx = x0 - 1 + kx;
                        if ((unsigned)xx >= 6u) continue;
                        size_t g = ((size_t)(b0 + bb) * 36 + yy * 6 + xx) * NW;
                        const u64* wp = wb + (ky * 3 + kx) * 2 * NW;
                        for (int wd = 0; wd < NW; ++wd) {
                            u64 val = pn[g + wd] & wp[2 * wd + 1];
                            u64 df  = (ps[g + wd] ^ wp[2 * wd]) & val;
                            sum += (int)__popcll(val) - 2 * (int)__popcll(df);
                        }
                    }
                }
            }
            sv[cc] = sum;
        }
    }
    if (act) {
        #pragma unroll
        for (int cc = 0; cc < 4; ++cc)
            out[((size_t)(b0 + bb) * Cout + co0 + cc) * 36 + r] = (float)sv[cc];
    }
    const int wid = t >> 6, lane = t & 63;
    #pragma unroll 1
    for (int cc = 0; cc < 4; ++cc) {
        int v = act ? sv[cc] : 0;
        long long q = (long long)v * v;
        wred_i(v, q);
        if (lane == 0) { sWi[wid] = v; sWq[wid] = q; }
        __syncthreads();
        if (t == 0) {
            int s = sWi[0] + sWi[1] + sWi[2] + sWi[3] + sWi[4];
            long long qq = sWq[0] + sWq[1] + sWq[2] + sWq[3] + sWq[4];
            part[((size_t)(co0 + cc) * 64 + bg) * 2]     = (double)s;
            part[((size_t)(co0 + cc) * 64 + bg) * 2 + 1] = (double)qq;
        }
        __syncthreads();
    }
}

// ---------------------------------------------------------------------------
// conv5 (NW=4, chunks of 2) + in-LDS maxpool3x3/2 + stats on POOLED. CO=4.
// grid (64, 64), 320 thr.
// ---------------------------------------------------------------------------
__global__ __launch_bounds__(320)
void k_conv5(const u64* __restrict__ ps, const u64* __restrict__ pn,
             const u64* __restrict__ w, float* __restrict__ outp,
             double* __restrict__ part, const ushort* __restrict__ tP,
             const int* __restrict__ flags) {
    __shared__ u64 st_s[2 * 576];
    __shared__ int sacc[4][288];
    __shared__ int sWi[5];
    __shared__ long long sWq[5];
    const int co0 = blockIdx.x * 4, bg = blockIdx.y, b0 = bg * 8, t = threadIdx.x;
    const int fl = flags[3];
    const bool act = t < 288;
    const int bb = act ? t / 36 : 0, r = act ? t - (t / 36) * 36 : 0;
    const int y = r / 6, x0 = r - y * 6;
    int S[4] = {0, 0, 0, 0};
    #pragma unroll 1
    for (int c0 = 0; c0 < 4; c0 += 2) {
        __syncthreads();
        for (int i = t; i < 2 * 576; i += 320) st_s[i] = 0;
        __syncthreads();
        for (int i = t; i < 8 * 36 * 2; i += 320) {
            int wd = i % 2, j = (i / 2) % 36, bb2 = i / 72;
            int yy = j / 6, xx = j - yy * 6;
            st_s[wd * 576 + bb2 * 72 + (yy + 1) * 9 + xx + 1] =
                ps[((size_t)(b0 + bb2) * 36 + j) * 4 + c0 + wd];
        }
        __syncthreads();
        if (act && fl == 0) {
            #pragma unroll
            for (int ky = 0; ky < 3; ++ky)
                #pragma unroll
                for (int kx = 0; kx < 3; ++kx) {
                    const int vb = bb * 72 + (y + ky) * 9 + x0 + kx;
                    #pragma unroll
                    for (int wd = 0; wd < 2; ++wd) {
                        u64 a = st_s[wd * 576 + vb];
                        #pragma unroll
                        for (int cc = 0; cc < 4; ++cc) {
                            u64 ws_ = w[((size_t)(co0 + cc) * 9 + ky * 3 + kx) * 8 + 2 * (c0 + wd)];
                            S[cc] += (int)__popcll(a ^ ws_);
                        }
                    }
                }
        }
    }
    if (act) {
        if (fl == 0) {
            const int ky0 = (y == 0), ky1 = (y == 5) ? 2 : 3;
            const int kx0 = (x0 == 0), kx1 = (x0 == 5) ? 2 : 3;
            const int nv = (ky1 - ky0) * (kx1 - kx0);
            #pragma unroll
            for (int cc = 0; cc < 4; ++cc) {
                const ushort* tb = tP + (co0 + cc) * 16;
                int Wt = tb[15];
                int Wr = (int)tb[ky1 * 4 + kx1] - (int)tb[ky0 * 4 + kx1]
                       - (int)tb[ky1 * 4 + kx0] + (int)tb[ky0 * 4 + kx0];
                sacc[cc][bb * 36 + r] = 256 * nv - 2 * S[cc] + 2 * (Wt - Wr);
            }
        } else {
            #pragma unroll 1
            for (int cc = 0; cc < 4; ++cc) {
                const u64* wb = w + (size_t)(co0 + cc) * 72;
                int sum = 0;
                for (int ky = 0; ky < 3; ++ky) {
                    int yy = y - 1 + ky;
                    if ((unsigned)yy >= 6u) continue;
                    for (int kx = 0; kx < 3; ++kx) {
                        int xx = x0 - 1 + kx;
                        if ((unsigned)xx >= 6u) continue;
                        size_t g = ((size_t)(b0 + bb) * 36 + yy * 6 + xx) * 4;
                        const u64* wp = wb + (ky * 3 + kx) * 8;
                        for (int wd = 0; wd < 4; ++wd) {
                            u64 val = pn[g + wd] & wp[2 * wd + 1];
                            u64 df  = (ps[g + wd] ^ wp[2 * wd]) & val;
                            sum += (int)__popcll(val) - 2 * (int)__popcll(df);
                        }
                    }
                }
                sacc[cc][bb * 36 + r] = sum;
            }
        }
    }
    __syncthreads();
    int pooled[4] = {0, 0, 0, 0};
    const bool pact = t < 32;
    if (pact) {
        int bb2 = t / 4, wi = t % 4, py = (wi >> 1) * 2, px = (wi & 1) * 2;
        #pragma unroll
        for (int cc = 0; cc < 4; ++cc) {
            int best = -1000000;
            #pragma unroll
            for (int dy = 0; dy < 3; ++dy)
                #pragma unroll
                for (int dx = 0; dx < 3; ++dx)
                    best = max(best, sacc[cc][bb2 * 36 + (py + dy) * 6 + (px + dx)]);
            pooled[cc] = best;
            outp[((size_t)(b0 + bb2) * 256 + co0 + cc) * 4 + wi] = (float)best;
        }
    }
    const int wid = t >> 6, lane = t & 63;
    #pragma unroll 1
    for (int cc = 0; cc < 4; ++cc) {
        int v = pact ? pooled[cc] : 0;
        long long q = (long long)v * v;
        wred_i(v, q);
        if (lane == 0) { sWi[wid] = v; sWq[wid] = q; }
        __syncthreads();
        if (t == 0) {
            int s = sWi[0] + sWi[1] + sWi[2] + sWi[3] + sWi[4];
            long long qq = sWq[0] + sWq[1] + sWq[2] + sWq[3] + sWq[4];
            part[((size_t)(co0 + cc) * 64 + bg) * 2]     = (double)s;
            part[((size_t)(co0 + cc) * 64 + bg) * 2 + 1] = (double)qq;
        }
        __syncthreads();
    }
}

// ---------------------------------------------------------------------------
__global__ void k_stats_final(const double* __restrict__ part, const float* __restrict__ g,
                              float* __restrict__ mean, float* __restrict__ inva,
                              int NB, long total) {
    __shared__ double sS[64], sQ[64];
    const int c = blockIdx.x, t = threadIdx.x;
    double s = 0.0, q = 0.0;
    for (int k = t; k < NB; k += 64) {
        s += part[((size_t)c * NB + k) * 2];
        q += part[((size_t)c * NB + k) * 2 + 1];
    }
    sS[t] = s; sQ[t] = q;
    __syncthreads();
    for (int o = 32; o > 0; o >>= 1) {
        if (t < o) { sS[t] += sS[t + o]; sQ[t] += sQ[t + o]; }
        __syncthreads();
    }
    if (t == 0) {
        double m = sS[0] / (double)total;
        double var = sQ[0] / (double)total - m * m;
        mean[c] = (float)m;
        inva[c] = g[c] * (float)(1.0 / sqrt(var + 1e-5));
    }
}

// ---- BN apply + sign + pack -> separate sign/nz arrays ----
__global__ void k_bnpack2d(const float* __restrict__ x, const float* __restrict__ m,
                           const float* __restrict__ a, const float* __restrict__ bt,
                           u64* __restrict__ ps, u64* __restrict__ pn,
                           int B, int C, int HW, int* flag) {
    int NW = (C + 63) >> 6;
    int tot = B * HW * NW;
    int idx = blockIdx.x * blockDim.x + threadIdx.x;
    if (idx >= tot) return;
    int wd = idx % NW, t = idx / NW;
    int j = t % HW, b = t / HW;
    u64 s = 0, nz = 0;
    for (int c0 = 0; c0 < 64; ++c0) {
        int c = wd * 64 + c0;
        if (c >= C) break;
        float v = (x[((size_t)b * C + c) * HW + j] - m[c]) * a[c] + bt[c];
        if (v > 0.0f) s |= (1ull << c0);
        if (v != 0.0f) nz |= (1ull << c0);
    }
    size_t o = ((size_t)b * HW + j) * NW + wd;
    ps[o] = s; pn[o] = nz;
    if (nz != ~0ull) atomicOr(flag, 1);
}

__global__ void k_bnpack_flat(const float* __restrict__ x, const float* __restrict__ m,
                              const float* __restrict__ a, const float* __restrict__ bt,
                              u64* __restrict__ ps, u64* __restrict__ pn,
                              int B, int* flag) {
    int idx = blockIdx.x * blockDim.x + threadIdx.x;
    if (idx >= B * 16) return;
    int wd = idx % 16, b = idx / 16;
    u64 s = 0, nz = 0;
    for (int k = 0; k < 64; ++k) {
        int f = wd * 64 + k;
        int c = f >> 2, j = f & 3;
        float v = (x[((size_t)b * 256 + c) * 4 + j] - m[c]) * a[c] + bt[c];
        if (v > 0.0f) s |= (1ull << k);
        if (v != 0.0f) nz |= (1ull << k);
    }
    ps[(size_t)b * 16 + wd] = s;
    pn[(size_t)b * 16 + wd] = nz;
    if (nz != ~0ull) atomicOr(flag, 1);
}

__global__ void k_bnpack1d(const float* __restrict__ x, const float* __restrict__ m,
                           const float* __restrict__ a, const float* __restrict__ bt,
                           u64* __restrict__ ps, u64* __restrict__ pn,
                           int B, int F, int* flag) {
    int NW = F >> 6;
    int idx = blockIdx.x * blockDim.x + threadIdx.x;
    if (idx >= B * NW) return;
    int wd = idx % NW, b = idx / NW;
    const float* row = x + (size_t)b * F + wd * 64;
    u64 s = 0, nz = 0;
    for (int c = 0; c < 64; ++c) {
        int f = wd * 64 + c;
        float v = (row[c] - m[f]) * a[f] + bt[f];
        if (v > 0.0f) s |= (1ull << c);
        if (v != 0.0f) nz |= (1ull << c);
    }
    ps[(size_t)b * NW + wd] = s;
    pn[(size_t)b * NW + wd] = nz;
    if (nz != ~0ull) atomicOr(flag, 1);
}

// ---------------------------------------------------------------------------
// binary FC, 32x32 tile, 2x2 micro-tile per thread, sign-only LDS.
// grid (ceil(O/32), B/32), 256 thr. Slow path reads global (flag-gated).
// ---------------------------------------------------------------------------
template<int NW>
__global__ __launch_bounds__(256)
void k_fcbin3(const u64* __restrict__ As_, const u64* __restrict__ An_,
              const u64* __restrict__ Ws_, const u64* __restrict__ Wn_,
              const float* __restrict__ bias, float* __restrict__ C, int O,
              double* __restrict__ part, int nbc, const int* __restrict__ flags, int slot) {
    constexpr int ST = NW | 1;
    __shared__ u64 sA[32 * ST];
    __shared__ u64 sW[32 * ST];
    __shared__ int sacc[32][32];
    const int t = threadIdx.x;
    const int fl = flags[slot];
    const int b0 = blockIdx.y * 32, o0 = blockIdx.x * 32;
    for (int i = t; i < 32 * NW; i += 256) {
        int rr = i / NW, cc = i % NW;
        sA[rr * ST + cc] = As_[(size_t)(b0 + rr) * NW + cc];
        int o = o0 + rr;
        sW[rr * ST + cc] = (o < O) ? Ws_[(size_t)o * NW + cc] : 0ull;
    }
    __syncthreads();
    const int tx = t % 16, ty = t / 16;
    int acc[2][2];
    if (fl == 0) {
        int S00 = 0, S01 = 0, S10 = 0, S11 = 0;
        #pragma unroll
        for (int wd = 0; wd < NW; ++wd) {
            u64 a0 = sA[ty * ST + wd], a1 = sA[(16 + ty) * ST + wd];
            u64 w0 = sW[tx * ST + wd], w1 = sW[(16 + tx) * ST + wd];
            S00 += (int)__popcll(a0 ^ w0); S01 += (int)__popcll(a0 ^ w1);
            S10 += (int)__popcll(a1 ^ w0); S11 += (int)__popcll(a1 ^ w1);
        }
        acc[0][0] = 64 * NW - 2 * S00; acc[0][1] = 64 * NW - 2 * S01;
        acc[1][0] = 64 * NW - 2 * S10; acc[1][1] = 64 * NW - 2 * S11;
    } else {
        #pragma unroll 1
        for (int i = 0; i < 2; ++i)
            #pragma unroll 1
            for (int j = 0; j < 2; ++j) {
                int b = b0 + ty + 16 * i, o = o0 + tx + 16 * j;
                int aV = 0, aD = 0;
                if (o < O) {
                    for (int wd = 0; wd < NW; ++wd) {
                        u64 val = An_[(size_t)b * NW + wd] & Wn_[(size_t)o * NW + wd];
                        u64 df  = (As_[(size_t)b * NW + wd] ^ Ws_[(size_t)o * NW + wd]) & val;
                        aV += (int)__popcll(val); aD += (int)__popcll(df);
                    }
                }
                acc[i][j] = aV - 2 * aD;
            }
    }
    #pragma unroll
    for (int i = 0; i < 2; ++i)
        #pragma unroll
        for (int j = 0; j < 2; ++j) {
            int o = o0 + tx + 16 * j;
            int v = (o < O) ? acc[i][j] : 0;
            if (o < O)
                C[(size_t)(b0 + ty + 16 * i) * O + o] = (float)v + (bias ? bias[o] : 0.0f);
            sacc[ty + 16 * i][tx + 16 * j] = v;
        }
    __syncthreads();
    if (part != nullptr && t < 32) {
        int s = 0; long long q = 0;
        #pragma unroll
        for (int b = 0; b < 32; ++b) {
            int v = sacc[b][t];
            s += v; q += (long long)v * v;
        }
        if (o0 + t < O) {
            part[((size_t)(o0 + t) * nbc + blockIdx.y) * 2]     = (double)s;
            part[((size_t)(o0 + t) * nbc + blockIdx.y) * 2 + 1] = (double)q;
        }
    }
}

// ---------------------------------------------------------------------------

static inline int cdiv(long a, int b) { return (int)((a + b - 1) / b); }

extern "C" void kernel_launch(void* const* d_in, const int* in_sizes, int n_in,
                              void* d_out, int out_size, void* d_ws, size_t ws_size,
                              hipStream_t stream) {
    const float* x   = (const float*)d_in[0];
    const float* w1  = (const float*)d_in[1];
    const float* g1  = (const float*)d_in[2];
    const float* b1  = (const float*)d_in[3];
    const float* w2  = (const float*)d_in[4];
    const float* g2  = (const float*)d_in[5];
    const float* b2  = (const float*)d_in[6];
    const float* w3  = (const float*)d_in[7];
    const float* g3  = (const float*)d_in[8];
    const float* b3  = (const float*)d_in[9];
    const float* w4  = (const float*)d_in[10];
    const float* g4  = (const float*)d_in[11];
    const float* b4  = (const float*)d_in[12];
    const float* w5  = (const float*)d_in[13];
    const float* g5  = (const float*)d_in[14];
    const float* b5  = (const float*)d_in[15];
    const float* wl1 = (const float*)d_in[16];
    const float* gl1 = (const float*)d_in[17];
    const float* bl1 = (const float*)d_in[18];
    const float* wl2 = (const float*)d_in[19];
    const float* gl2 = (const float*)d_in[20];
    const float* bl2 = (const float*)d_in[21];
    const float* wl3 = (const float*)d_in[22];
    const float* bl3 = (const float*)d_in[23];
    float* out = (float*)d_out;
    (void)in_sizes; (void)n_in; (void)out_size; (void)ws_size;

    char* base = (char*)d_ws;
    size_t off = 0;
    auto alloc = [&](size_t bytes) {
        char* p = base + off;
        off += (bytes + 15) & ~(size_t)15;
        return (void*)p;
    };
    float* R1   = (float*)alloc(7372800 * 4);
    float* R2   = (float*)alloc(4718592 * 4);
    float* R3   = (float*)alloc(524288 * 4);
    float* w1s  = (float*)alloc(4800 * 4);
    u64* p1s = (u64*)alloc(115200 * 8);   u64* p1n = (u64*)alloc(115200 * 8);
    u64* p2s = (u64*)alloc(55296 * 8);    u64* p2n = (u64*)alloc(55296 * 8);
    u64* p3s = (u64*)alloc(110592 * 8);   u64* p3n = (u64*)alloc(110592 * 8);
    u64* p4s = (u64*)alloc(73728 * 8);    u64* p4n = (u64*)alloc(73728 * 8);
    u64* p5s = (u64*)alloc(8192 * 8);     u64* p5n = (u64*)alloc(8192 * 8);
    u64* pf1s = (u64*)alloc(32768 * 8);   u64* pf1n = (u64*)alloc(32768 * 8);
    u64* pf2s = (u64*)alloc(16384 * 8);   u64* pf2n = (u64*)alloc(16384 * 8);
    u64* w2p  = (u64*)alloc(9600 * 8);
    u64* w3p  = (u64*)alloc(20736 * 8);
    u64* w4p  = (u64*)alloc(27648 * 8);
    u64* w5p  = (u64*)alloc(18432 * 8);
    u64* wl1s_ = (u64*)alloc(65536 * 8);  u64* wl1n_ = (u64*)alloc(65536 * 8);
    u64* wl2s_ = (u64*)alloc(131072 * 8); u64* wl2n_ = (u64*)alloc(131072 * 8);
    u64* wl3s_ = (u64*)alloc(320 * 8);    u64* wl3n_ = (u64*)alloc(320 * 8);
    double* part = (double*)alloc((size_t)4096 * 32 * 2 * 8);
    float* stats = (float*)alloc(7 * 2 * 4096 * 4);
    int*    flags = (int*)alloc(8 * 4);
    ushort* t2 = (ushort*)alloc(192 * 4 * 2);
    ushort* t3 = (ushort*)alloc(384 * 16 * 2);
    ushort* t4 = (ushort*)alloc(256 * 16 * 2);
    ushort* t5 = (ushort*)alloc(256 * 16 * 2);
    float* m_[7]; float* a_[7];
    for (int l = 0; l < 7; ++l) { m_[l] = stats + (size_t)l * 8192; a_[l] = m_[l] + 4096; }

    hipMemsetAsync(flags, 0, 8 * 4, stream);

    // ---- weight prep ----
    k_prep<<<cdiv(PREP_TOTAL, 256), 256, 0, stream>>>(
        w1, w1s, w2, w2p, w3, w3p, w4, w4p, w5, w5p,
        wl1, wl1s_, wl1n_, wl2, wl2s_, wl2n_, wl3, wl3s_, wl3n_, flags);
    k_prep2<<<cdiv(192 + 384 + 256 + 256, 256), 256, 0, stream>>>(
        w2p, w3p, w4p, w5p, t2, t3, t4, t5);

    // ---- conv1 + pool -> R1 (+stats); bn1; pack -> p1 ----
    k_conv1<<<dim3(8, 512), 256, 0, stream>>>(x, w1s, R1, part);
    k_stats_final<<<64, 64, 0, stream>>>(part, g1, m_[0], a_[0], 512, (long)512 * 225);
    k_bnpack2d<<<cdiv((long)512 * 225, 256), 256, 0, stream>>>(R1, m_[0], a_[0], b1, p1s, p1n, 512, 64, 225, flags + 0);

    // ---- conv2 (CO=4) + pool -> R2 (+stats); bn2; pack -> p2 ----
    k_conv2<<<dim3(48, 64), 320, 0, stream>>>(p1s, p1n, w2p, R2, part, t2, flags);
    k_stats_final<<<192, 64, 0, stream>>>(part, g2, m_[1], a_[1], 64, (long)512 * 36);
    k_bnpack2d<<<cdiv((long)512 * 36 * 3, 256), 256, 0, stream>>>(R2, m_[1], a_[1], b2, p2s, p2n, 512, 192, 36, flags + 1);

    // ---- conv3 (CO=4) -> R1 (+stats); bn3; pack -> p3 ----
    k_convbin3<3, 3><<<dim3(96, 64), 320, 0, stream>>>(p2s, p2n, w3p, R1, part, 384, t3, flags, 1);
    k_stats_final<<<384, 64, 0, stream>>>(part, g3, m_[2], a_[2], 64, (long)512 * 36);
    k_bnpack2d<<<cdiv((long)512 * 36 * 6, 256), 256, 0, stream>>>(R1, m_[2], a_[2], b3, p3s, p3n, 512, 384, 36, flags + 2);

    // ---- conv4 (CO=4) -> R2 (+stats); bn4; pack -> p4 ----
    k_convbin3<6, 3><<<dim3(64, 64), 320, 0, stream>>>(p3s, p3n, w4p, R2, part, 256, t4, flags, 2);
    k_stats_final<<<256, 64, 0, stream>>>(part, g4, m_[3], a_[3], 64, (long)512 * 36);
    k_bnpack2d<<<cdiv((long)512 * 36 * 4, 256), 256, 0, stream>>>(R2, m_[3], a_[3], b4, p4s, p4n, 512, 256, 36, flags + 3);

    // ---- conv5 (CO=4) + in-LDS pool -> R3 (+stats on pooled); bn5; pack -> p5 ----
    k_conv5<<<dim3(64, 64), 320, 0, stream>>>(p4s, p4n, w5p, R3, part, t5, flags);
    k_stats_final<<<256, 64, 0, stream>>>(part, g5, m_[4], a_[4], 64, (long)512 * 4);
    k_bnpack_flat<<<cdiv(512 * 16, 256), 256, 0, stream>>>(R3, m_[4], a_[4], b5, p5s, p5n, 512, flags + 4);

    // ---- fc1 -> R2 (+stats); bn; pack -> pf1 ----
    k_fcbin3<16><<<dim3(128, 16), 256, 0, stream>>>(p5s, p5n, wl1s_, wl1n_, nullptr, R2, 4096, part, 16, flags, 4);
    k_stats_final<<<4096, 64, 0, stream>>>(part, gl1, m_[5], a_[5], 16, 512);
    k_bnpack1d<<<cdiv(512 * 64, 256), 256, 0, stream>>>(R2, m_[5], a_[5], bl1, pf1s, pf1n, 512, 4096, flags + 5);

    // ---- fc2 -> R1 (+stats); bn; pack -> pf2 ----
    k_fcbin3<64><<<dim3(64, 16), 256, 0, stream>>>(pf1s, pf1n, wl2s_, wl2n_, nullptr, R1, 2048, part, 16, flags, 5);
    k_stats_final<<<2048, 64, 0, stream>>>(part, gl2, m_[6], a_[6], 16, 512);
    k_bnpack1d<<<cdiv(512 * 32, 256), 256, 0, stream>>>(R1, m_[6], a_[6], bl2, pf2s, pf2n, 512, 2048, flags + 6);

    // ---- fc3 + bias -> out [512,10] ----
    k_fcbin3<32><<<dim3(1, 16), 256, 0, stream>>>(pf2s, pf2n, wl3s_, wl3n_, bl3, out, 10, nullptr, 0, flags, 6);
}

// Round 9
// 583.069 us; speedup vs baseline: 69.6843x; 1.2373x over previous
//
#include <hip/hip_runtime.h>
#include <math.h>

// ---------------------------------------------------------------------------
// BinAlexNet forward — round 9: unified fast XNOR path + sparse zero-correction.
//   Activation zeros (rare but REAL: integer-valued pre-BN activations can
//   exactly equal the batch mean) handled exactly via
//     dot_true = dot_fast - popc(za) + 2*popc(sw & za)
//   applied only for batch-slabs/rows flagged in tiny bz[] arrays.
//   Weight-zero flag retained as a (probability ~0) exact global fallback.
// ---------------------------------------------------------------------------

typedef unsigned long long u64;

__device__ __forceinline__ float sgn(float x) {
    return (float)((x > 0.0f) - (x < 0.0f));
}

__device__ __forceinline__ void wred_i(int& s, long long& q) {
    #pragma unroll
    for (int o = 32; o > 0; o >>= 1) {
        s += __shfl_down(s, o, 64);
        q += __shfl_down(q, o, 64);
    }
}
__device__ __forceinline__ void wred_d(double& s, double& q) {
    #pragma unroll
    for (int o = 32; o > 0; o >>= 1) {
        s += __shfl_down(s, o, 64);
        q += __shfl_down(q, o, 64);
    }
}

// wflags slots (weight zeros only): 0:conv2 1:conv3 2:conv4 3:conv5 4:fc1 5:fc2 6:fc3
// ---------------------------------------------------------------------------
__device__ void pack_conv_one(int idx, const float* __restrict__ w,
                              u64* __restrict__ wp, int Cout, int Cin, int KK,
                              int* flag) {
    int NW = (Cin + 63) >> 6;
    int wd = idx % NW, t = idx / NW;
    int tap = t % KK, co = t / KK;
    u64 s = 0, nz = 0;
    for (int c = 0; c < 64; ++c) {
        int ci = wd * 64 + c;
        if (ci >= Cin) break;
        float v = w[((size_t)co * Cin + ci) * KK + tap];
        if (v > 0.0f) s |= (1ull << c);
        if (v != 0.0f) nz |= (1ull << c);
    }
    u64* o = wp + ((size_t)co * KK + tap) * 2 * NW + 2 * wd;
    o[0] = s; o[1] = nz;
    if (nz != ~0ull) atomicOr(flag, 1);
}

__device__ void pack_fc_one(int idx, const float* __restrict__ w,
                            u64* __restrict__ ws_, u64* __restrict__ wn_,
                            int Kd, int* flag) {
    int NW = Kd >> 6;
    int wd = idx % NW, o = idx / NW;
    const float* row = w + (size_t)o * Kd + wd * 64;
    u64 s = 0, nz = 0;
    for (int c = 0; c < 64; ++c) {
        float v = row[c];
        if (v > 0.0f) s |= (1ull << c);
        if (v != 0.0f) nz |= (1ull << c);
    }
    ws_[(size_t)o * NW + wd] = s;
    wn_[(size_t)o * NW + wd] = nz;
    if (nz != ~0ull) atomicOr(flag, 1);
}

#define PN0 4800
#define PN1 4800
#define PN2 10368
#define PN3 13824
#define PN4 9216
#define PN5 65536
#define PN6 131072
#define PN7 320
#define PREP_TOTAL (PN0+PN1+PN2+PN3+PN4+PN5+PN6+PN7)   // 239936

__global__ void k_prep(const float* w1, float* w1s,
                       const float* w2, u64* w2p,
                       const float* w3, u64* w3p,
                       const float* w4, u64* w4p,
                       const float* w5, u64* w5p,
                       const float* wl1, u64* wl1s_, u64* wl1n_,
                       const float* wl2, u64* wl2s_, u64* wl2n_,
                       const float* wl3, u64* wl3s_, u64* wl3n_,
                       int* wflags) {
    int idx = blockIdx.x * blockDim.x + threadIdx.x;
    int r = idx;
    if (r < PN0) { w1s[r] = sgn(w1[r]); return; } r -= PN0;
    if (r < PN1) { pack_conv_one(r, w2, w2p, 192, 64, 25, wflags + 0); return; } r -= PN1;
    if (r < PN2) { pack_conv_one(r, w3, w3p, 384, 192, 9, wflags + 1); return; } r -= PN2;
    if (r < PN3) { pack_conv_one(r, w4, w4p, 256, 384, 9, wflags + 2); return; } r -= PN3;
    if (r < PN4) { pack_conv_one(r, w5, w5p, 256, 256, 9, wflags + 3); return; } r -= PN4;
    if (r < PN5) { pack_fc_one(r, wl1, wl1s_, wl1n_, 1024, wflags + 4); return; } r -= PN5;
    if (r < PN6) { pack_fc_one(r, wl2, wl2s_, wl2n_, 4096, wflags + 5); return; } r -= PN6;
    if (r < PN7) { pack_fc_one(r, wl3, wl3s_, wl3n_, 2048, wflags + 6); return; }
}

// ---------------------------------------------------------------------------
__device__ void prefix3(const u64* __restrict__ wb, int NW, ushort* __restrict__ o) {
    int cs[9];
    #pragma unroll
    for (int tap = 0; tap < 9; ++tap) {
        int s = 0;
        for (int wd = 0; wd < NW; ++wd)
            s += (int)__popcll(wb[tap * 2 * NW + 2 * wd]);
        cs[tap] = s;
    }
    int P[4][4];
    P[0][0] = 0; P[0][1] = 0; P[0][2] = 0; P[0][3] = 0;
    P[1][0] = 0; P[2][0] = 0; P[3][0] = 0;
    P[1][1] = cs[0];                 P[1][2] = cs[0] + cs[1];                 P[1][3] = cs[0] + cs[1] + cs[2];
    P[2][1] = cs[0] + cs[3];         P[2][2] = cs[0] + cs[1] + cs[3] + cs[4]; P[2][3] = P[1][3] + cs[3] + cs[4] + cs[5];
    P[3][1] = cs[0] + cs[3] + cs[6]; P[3][2] = P[2][2] + cs[6] + cs[7];       P[3][3] = P[2][3] + cs[6] + cs[7] + cs[8];
    #pragma unroll
    for (int i = 0; i < 4; ++i)
        #pragma unroll
        for (int j = 0; j < 4; ++j)
            o[i * 4 + j] = (ushort)P[i][j];
}

__global__ void k_prep2(const u64* w2p, const u64* w3p, const u64* w4p, const u64* w5p,
                        ushort* t2, ushort* t3, ushort* t4, ushort* t5) {
    int idx = blockIdx.x * blockDim.x + threadIdx.x;
    if (idx < 192) {
        const u64* wb = w2p + idx * 50;
        int cnt[25];
        #pragma unroll
        for (int tap = 0; tap < 25; ++tap) cnt[tap] = (int)__popcll(wb[tap * 2]);
        int R1 = 0, C1 = 0;
        #pragma unroll
        for (int k = 0; k < 5; ++k) { R1 += cnt[k]; C1 += cnt[k * 5]; }
        t2[idx * 4 + 0] = (ushort)R1;
        t2[idx * 4 + 1] = (ushort)C1;
        t2[idx * 4 + 2] = (ushort)cnt[0];
        t2[idx * 4 + 3] = 0;
        return;
    }
    idx -= 192;
    if (idx < 384) { prefix3(w3p + (size_t)idx * 54, 3, t3 + idx * 16); return; }
    idx -= 384;
    if (idx < 256) { prefix3(w4p + (size_t)idx * 108, 6, t4 + idx * 16); return; }
    idx -= 256;
    if (idx < 256) { prefix3(w5p + (size_t)idx * 72, 4, t5 + idx * 16); return; }
}

// ---------------------------------------------------------------------------
// conv1: fp32, LDS image, fused pool + stats
// ---------------------------------------------------------------------------
__global__ __launch_bounds__(256)
void k_conv1(const float* __restrict__ x, const float* __restrict__ w1s,
             float* __restrict__ out, double* __restrict__ part) {
    __shared__ float sx[3 * 34 * 34];
    __shared__ double sWv[4], sQv[4];
    const int b = blockIdx.y, cg = blockIdx.x, t = threadIdx.x;
    for (int i = t; i < 3 * 34 * 34; i += 256) sx[i] = 0.0f;
    __syncthreads();
    for (int i = t; i < 3072; i += 256) {
        int ch = i >> 10, rem = i & 1023, yy = rem >> 5, xx = rem & 31;
        sx[(ch * 34 + yy + 1) * 34 + xx + 1] = x[(size_t)b * 3072 + i];
    }
    __syncthreads();
    const bool act = t < 225;
    const int py = act ? t / 15 : 0, px = act ? t % 15 : 0;
    float a0[8], a1[8], a2[8], a3[8];
    #pragma unroll
    for (int c = 0; c < 8; ++c) { a0[c] = a1[c] = a2[c] = a3[c] = 0.f; }
    #pragma unroll 1
    for (int ch = 0; ch < 3; ++ch) {
        const float* wc = w1s + (size_t)(cg * 8) * 75 + ch * 25;
        #pragma unroll 1
        for (int yy6 = 0; yy6 < 6; ++yy6) {
            const float2* rp = (const float2*)&sx[(ch * 34 + py * 2 + yy6) * 34 + px * 2];
            float2 ra = rp[0], rb = rp[1], rc = rp[2];
            float r[6] = {ra.x, ra.y, rb.x, rb.y, rc.x, rc.y};
            if (yy6 <= 4) {
                #pragma unroll
                for (int kx = 0; kx < 5; ++kx)
                    #pragma unroll
                    for (int cc = 0; cc < 8; ++cc) {
                        float wv = wc[cc * 75 + yy6 * 5 + kx];
                        a0[cc] = fmaf(r[kx],     wv, a0[cc]);
                        a1[cc] = fmaf(r[kx + 1], wv, a1[cc]);
                    }
            }
            if (yy6 >= 1) {
                #pragma unroll
                for (int kx = 0; kx < 5; ++kx)
                    #pragma unroll
                    for (int cc = 0; cc < 8; ++cc) {
                        float wv = wc[cc * 75 + (yy6 - 1) * 5 + kx];
                        a2[cc] = fmaf(r[kx],     wv, a2[cc]);
                        a3[cc] = fmaf(r[kx + 1], wv, a3[cc]);
                    }
            }
        }
    }
    const int wid = t >> 6, lane = t & 63;
    #pragma unroll
    for (int cc = 0; cc < 8; ++cc) {
        float best = 0.f;
        if (act) {
            best = fmaxf(fmaxf(a0[cc], a1[cc]), fmaxf(a2[cc], a3[cc]));
            out[((size_t)b * 64 + cg * 8 + cc) * 225 + t] = best;
        }
        double v = act ? (double)best : 0.0;
        double q = v * v;
        wred_d(v, q);
        if (lane == 0) { sWv[wid] = v; sQv[wid] = q; }
        __syncthreads();
        if (t == 0) {
            part[((size_t)(cg * 8 + cc) * 512 + b) * 2]     = sWv[0] + sWv[1] + sWv[2] + sWv[3];
            part[((size_t)(cg * 8 + cc) * 512 + b) * 2 + 1] = sQv[0] + sQv[1] + sQv[2] + sQv[3];
        }
        __syncthreads();
    }
}

// ---------------------------------------------------------------------------
// conv2 (K=5, NW=1) + maxpool2x2 + fused stats. CO=4, zero-correction.
// ---------------------------------------------------------------------------
__global__ __launch_bounds__(320)
void k_conv2(const u64* __restrict__ ps, const u64* __restrict__ zap,
             const u64* __restrict__ w, float* __restrict__ out,
             double* __restrict__ part, const ushort* __restrict__ t2,
             const int* __restrict__ wflags, const int* __restrict__ bz) {
    __shared__ u64 st_s[8 * 17 * 17];
    __shared__ int sbz[8];
    __shared__ int sWi[5];
    __shared__ long long sWq[5];
    const int co0 = blockIdx.x * 4, bg = blockIdx.y, b0 = bg * 8, t = threadIdx.x;
    const int wfl = wflags[0];
    if (t < 8) sbz[t] = bz[b0 + t];
    for (int i = t; i < 8 * 289; i += 320) st_s[i] = 0;
    __syncthreads();
    for (int i = t; i < 8 * 225; i += 320) {
        int bb = i / 225, j = i - bb * 225;
        int yy = j / 15, xx = j - yy * 15;
        st_s[(bb * 17 + yy + 1) * 17 + xx + 1] = ps[(size_t)(b0 + bb) * 225 + j];
    }
    __syncthreads();
    const bool act = t < 288;
    const int bb = act ? t / 36 : 0, r = act ? t - (t / 36) * 36 : 0;
    const int py = r / 6, px = r - py * 6;
    int best[4] = {0, 0, 0, 0};
    if (act) {
        if (wfl == 0) {
            int S0[4] = {0,0,0,0}, S1[4] = {0,0,0,0}, S2[4] = {0,0,0,0}, S3[4] = {0,0,0,0};
            #pragma unroll 1
            for (int yy6 = 0; yy6 < 6; ++yy6) {
                const int base = (bb * 17 + py * 2 + yy6) * 17 + px * 2;
                u64 V[6];
                #pragma unroll
                for (int k = 0; k < 6; ++k) V[k] = st_s[base + k];
                if (yy6 <= 4) {
                    #pragma unroll
                    for (int kx = 0; kx < 5; ++kx) {
                        #pragma unroll
                        for (int cc = 0; cc < 4; ++cc) {
                            u64 ws_ = w[(size_t)(co0 + cc) * 50 + (yy6 * 5 + kx) * 2];
                            S0[cc] += (int)__popcll(V[kx] ^ ws_);
                            S1[cc] += (int)__popcll(V[kx + 1] ^ ws_);
                        }
                    }
                }
                if (yy6 >= 1) {
                    #pragma unroll
                    for (int kx = 0; kx < 5; ++kx) {
                        #pragma unroll
                        for (int cc = 0; cc < 4; ++cc) {
                            u64 ws_ = w[(size_t)(co0 + cc) * 50 + ((yy6 - 1) * 5 + kx) * 2];
                            S2[cc] += (int)__popcll(V[kx] ^ ws_);
                            S3[cc] += (int)__popcll(V[kx + 1] ^ ws_);
                        }
                    }
                }
            }
            int C0[4] = {0,0,0,0}, C1[4] = {0,0,0,0}, C2[4] = {0,0,0,0}, C3[4] = {0,0,0,0};
            if (sbz[bb]) {
                #pragma unroll 1
                for (int dy = 0; dy < 2; ++dy)
                #pragma unroll 1
                for (int dx = 0; dx < 2; ++dx) {
                    int yc = py * 2 + dy, xc = px * 2 + dx;
                    #pragma unroll 1
                    for (int ky = 0; ky < 5; ++ky) {
                        int yy = yc - 1 + ky;
                        if ((unsigned)yy >= 15u) continue;
                        #pragma unroll 1
                        for (int kx = 0; kx < 5; ++kx) {
                            int xx = xc - 1 + kx;
                            if ((unsigned)xx >= 15u) continue;
                            u64 za = zap[(size_t)(b0 + bb) * 225 + yy * 15 + xx];
                            if (za) {
                                int pz = (int)__popcll(za);
                                #pragma unroll
                                for (int cc = 0; cc < 4; ++cc) {
                                    u64 ws_ = w[(size_t)(co0 + cc) * 50 + (ky * 5 + kx) * 2];
                                    int d = 2 * (int)__popcll(ws_ & za) - pz;
                                    if (dy == 0 && dx == 0) C0[cc] += d;
                                    else if (dy == 0)       C1[cc] += d;
                                    else if (dx == 0)       C2[cc] += d;
                                    else                    C3[cc] += d;
                                }
                            }
                        }
                    }
                }
            }
            const int py0 = (py == 0), px0 = (px == 0);
            #pragma unroll
            for (int cc = 0; cc < 4; ++cc) {
                const ushort* tb = t2 + (co0 + cc) * 4;
                const int R1 = tb[0], C1v = tb[1], X = tb[2];
                int d0 = 64 * (5 - py0) * (5 - px0) - 2 * S0[cc] + 2 * (py0 * R1 + px0 * C1v - py0 * px0 * X) + C0[cc];
                int d1 = 64 * (5 - py0) * 5 - 2 * S1[cc] + 2 * (py0 * R1) + C1[cc];
                int d2 = 64 * 5 * (5 - px0) - 2 * S2[cc] + 2 * (px0 * C1v) + C2[cc];
                int d3 = 1600 - 2 * S3[cc] + C3[cc];
                best[cc] = max(max(d0, d1), max(d2, d3));
            }
        } else {
            // weight-zero fallback (exact, probability ~0): masked global reads
            #pragma unroll 1
            for (int cc = 0; cc < 4; ++cc) {
                const u64* wb = w + (size_t)(co0 + cc) * 50;
                int bst = -1000000;
                for (int dy = 0; dy < 2; ++dy)
                    for (int dx = 0; dx < 2; ++dx) {
                        int yc = py * 2 + dy, xc = px * 2 + dx;
                        int sum = 0;
                        for (int ky = 0; ky < 5; ++ky) {
                            int yy = yc - 1 + ky;
                            if ((unsigned)yy >= 15u) continue;
                            for (int kx = 0; kx < 5; ++kx) {
                                int xx = xc - 1 + kx;
                                if ((unsigned)xx >= 15u) continue;
                                size_t g = (size_t)(b0 + bb) * 225 + yy * 15 + xx;
                                u64 val = ~zap[g] & wb[(ky * 5 + kx) * 2 + 1];
                                u64 df  = (ps[g] ^ wb[(ky * 5 + kx) * 2]) & val;
                                sum += (int)__popcll(val) - 2 * (int)__popcll(df);
                            }
                        }
                        bst = max(bst, sum);
                    }
                best[cc] = bst;
            }
        }
        #pragma unroll
        for (int cc = 0; cc < 4; ++cc)
            out[((size_t)(b0 + bb) * 192 + co0 + cc) * 36 + r] = (float)best[cc];
    }
    const int wid = t >> 6, lane = t & 63;
    #pragma unroll 1
    for (int cc = 0; cc < 4; ++cc) {
        int v = act ? best[cc] : 0;
        long long q = (long long)v * v;
        wred_i(v, q);
        if (lane == 0) { sWi[wid] = v; sWq[wid] = q; }
        __syncthreads();
        if (t == 0) {
            part[((size_t)(co0 + cc) * 64 + bg) * 2]     = (double)(sWi[0] + sWi[1] + sWi[2] + sWi[3] + sWi[4]);
            part[((size_t)(co0 + cc) * 64 + bg) * 2 + 1] = (double)(sWq[0] + sWq[1] + sWq[2] + sWq[3] + sWq[4]);
        }
        __syncthreads();
    }
}

// ---------------------------------------------------------------------------
// 3x3 pad-1 binary conv on 6x6 (conv3/conv4). CO=4, zero-correction.
// ---------------------------------------------------------------------------
template<int NW, int NWC>
__global__ __launch_bounds__(320)
void k_convbin3(const u64* __restrict__ ps, const u64* __restrict__ zap,
                const u64* __restrict__ w, float* __restrict__ out,
                double* __restrict__ part, int Cout,
                const ushort* __restrict__ tP, const int* __restrict__ wflags,
                int slot, const int* __restrict__ bz) {
    __shared__ u64 st_s[NWC * 576];
    __shared__ int sbz[8];
    __shared__ int sWi[5];
    __shared__ long long sWq[5];
    const int co0 = blockIdx.x * 4, bg = blockIdx.y, b0 = bg * 8, t = threadIdx.x;
    const int wfl = wflags[slot];
    if (t < 8) sbz[t] = bz[b0 + t];
    const bool act = t < 288;
    const int bb = act ? t / 36 : 0, r = act ? t - (t / 36) * 36 : 0;
    const int y = r / 6, x0 = r - y * 6;
    int S[4] = {0, 0, 0, 0};
    #pragma unroll 1
    for (int c0 = 0; c0 < NW; c0 += NWC) {
        __syncthreads();
        for (int i = t; i < NWC * 576; i += 320) st_s[i] = 0;
        __syncthreads();
        for (int i = t; i < 8 * 36 * NWC; i += 320) {
            int wd = i % NWC, j = (i / NWC) % 36, bb2 = i / (36 * NWC);
            int yy = j / 6, xx = j - yy * 6;
            st_s[wd * 576 + bb2 * 72 + (yy + 1) * 9 + xx + 1] =
                ps[((size_t)(b0 + bb2) * 36 + j) * NW + c0 + wd];
        }
        __syncthreads();
        if (act && wfl == 0) {
            #pragma unroll
            for (int ky = 0; ky < 3; ++ky)
                #pragma unroll
                for (int kx = 0; kx < 3; ++kx) {
                    const int vb = bb * 72 + (y + ky) * 9 + x0 + kx;
                    #pragma unroll
                    for (int wd = 0; wd < NWC; ++wd) {
                        u64 a = st_s[wd * 576 + vb];
                        #pragma unroll
                        for (int cc = 0; cc < 4; ++cc) {
                            u64 ws_ = w[((size_t)(co0 + cc) * 9 + ky * 3 + kx) * 2 * NW + 2 * (c0 + wd)];
                            S[cc] += (int)__popcll(a ^ ws_);
                        }
                    }
                }
        }
    }
    int sv[4];
    if (wfl == 0) {
        const int ky0 = (y == 0), ky1 = (y == 5) ? 2 : 3;
        const int kx0 = (x0 == 0), kx1 = (x0 == 5) ? 2 : 3;
        const int nv = (ky1 - ky0) * (kx1 - kx0);
        #pragma unroll
        for (int cc = 0; cc < 4; ++cc) {
            const ushort* tb = tP + (co0 + cc) * 16;
            int Wt = tb[15];
            int Wr = (int)tb[ky1 * 4 + kx1] - (int)tb[ky0 * 4 + kx1]
                   - (int)tb[ky1 * 4 + kx0] + (int)tb[ky0 * 4 + kx0];
            sv[cc] = 64 * NW * nv - 2 * S[cc] + 2 * (Wt - Wr);
        }
        if (act && sbz[bb]) {
            #pragma unroll 1
            for (int ky = 0; ky < 3; ++ky) {
                int yy = y - 1 + ky;
                if ((unsigned)yy >= 6u) continue;
                #pragma unroll 1
                for (int kx = 0; kx < 3; ++kx) {
                    int xx = x0 - 1 + kx;
                    if ((unsigned)xx >= 6u) continue;
                    size_t g = ((size_t)(b0 + bb) * 36 + yy * 6 + xx) * NW;
                    #pragma unroll 1
                    for (int wd = 0; wd < NW; ++wd) {
                        u64 za = zap[g + wd];
                        if (za) {
                            int pz = (int)__popcll(za);
                            #pragma unroll
                            for (int cc = 0; cc < 4; ++cc) {
                                u64 ws_ = w[((size_t)(co0 + cc) * 9 + ky * 3 + kx) * 2 * NW + 2 * wd];
                                sv[cc] += 2 * (int)__popcll(ws_ & za) - pz;
                            }
                        }
                    }
                }
            }
        }
    } else {
        #pragma unroll 1
        for (int cc = 0; cc < 4; ++cc) {
            int sum = 0;
            if (act) {
                const u64* wb = w + (size_t)(co0 + cc) * 9 * 2 * NW;
                for (int ky = 0; ky < 3; ++ky) {
                    int yy = y - 1 + ky;
                    if ((unsigned)yy >= 6u) continue;
                    for (int kx = 0; kx < 3; ++kx) {
                        int xx = x0 - 1 + kx;
                        if ((unsigned)xx >= 6u) continue;
                        size_t g = ((size_t)(b0 + bb) * 36 + yy * 6 + xx) * NW;
                        const u64* wp = wb + (ky * 3 + kx) * 2 * NW;
                        for (int wd = 0; wd < NW; ++wd) {
                            u64 val = ~zap[g + wd] & wp[2 * wd + 1];
                            u64 df  = (ps[g + wd] ^ wp[2 * wd]) & val;
                            sum += (int)__popcll(val) - 2 * (int)__popcll(df);
                        }
                    }
                }
            }
            sv[cc] = sum;
        }
    }
    if (act) {
        #pragma unroll
        for (int cc = 0; cc < 4; ++cc)
            out[((size_t)(b0 + bb) * Cout + co0 + cc) * 36 + r] = (float)sv[cc];
    }
    const int wid = t >> 6, lane = t & 63;
    #pragma unroll 1
    for (int cc = 0; cc < 4; ++cc) {
        int v = act ? sv[cc] : 0;
        long long q = (long long)v * v;
        wred_i(v, q);
        if (lane == 0) { sWi[wid] = v; sWq[wid] = q; }
        __syncthreads();
        if (t == 0) {
            part[((size_t)(co0 + cc) * 64 + bg) * 2]     = (double)(sWi[0] + sWi[1] + sWi[2] + sWi[3] + sWi[4]);
            part[((size_t)(co0 + cc) * 64 + bg) * 2 + 1] = (double)(sWq[0] + sWq[1] + sWq[2] + sWq[3] + sWq[4]);
        }
        __syncthreads();
    }
}

// ---------------------------------------------------------------------------
// conv5 (NW=4, chunks of 2) + in-LDS maxpool3x3/2 + stats on POOLED. CO=4.
// ---------------------------------------------------------------------------
__global__ __launch_bounds__(320)
void k_conv5(const u64* __restrict__ ps, const u64* __restrict__ zap,
             const u64* __restrict__ w, float* __restrict__ outp,
             double* __restrict__ part, const ushort* __restrict__ tP,
             const int* __restrict__ wflags, const int* __restrict__ bz) {
    __shared__ u64 st_s[2 * 576];
    __shared__ int sacc[4][288];
    __shared__ int sbz[8];
    __shared__ int sWi[5];
    __shared__ long long sWq[5];
    const int co0 = blockIdx.x * 4, bg = blockIdx.y, b0 = bg * 8, t = threadIdx.x;
    const int wfl = wflags[3];
    if (t < 8) sbz[t] = bz[b0 + t];
    const bool act = t < 288;
    const int bb = act ? t / 36 : 0, r = act ? t - (t / 36) * 36 : 0;
    const int y = r / 6, x0 = r - y * 6;
    int S[4] = {0, 0, 0, 0};
    #pragma unroll 1
    for (int c0 = 0; c0 < 4; c0 += 2) {
        __syncthreads();
        for (int i = t; i < 2 * 576; i += 320) st_s[i] = 0;
        __syncthreads();
        for (int i = t; i < 8 * 36 * 2; i += 320) {
            int wd = i % 2, j = (i / 2) % 36, bb2 = i / 72;
            int yy = j / 6, xx = j - yy * 6;
            st_s[wd * 576 + bb2 * 72 + (yy + 1) * 9 + xx + 1] =
                ps[((size_t)(b0 + bb2) * 36 + j) * 4 + c0 + wd];
        }
        __syncthreads();
        if (act && wfl == 0) {
            #pragma unroll
            for (int ky = 0; ky < 3; ++ky)
                #pragma unroll
                for (int kx = 0; kx < 3; ++kx) {
                    const int vb = bb * 72 + (y + ky) * 9 + x0 + kx;
                    #pragma unroll
                    for (int wd = 0; wd < 2; ++wd) {
                        u64 a = st_s[wd * 576 + vb];
                        #pragma unroll
                        for (int cc = 0; cc < 4; ++cc) {
                            u64 ws_ = w[((size_t)(co0 + cc) * 9 + ky * 3 + kx) * 8 + 2 * (c0 + wd)];
                            S[cc] += (int)__popcll(a ^ ws_);
                        }
                    }
                }
        }
    }
    if (act) {
        int sv[4];
        if (wfl == 0) {
            const int ky0 = (y == 0), ky1 = (y == 5) ? 2 : 3;
            const int kx0 = (x0 == 0), kx1 = (x0 == 5) ? 2 : 3;
            const int nv = (ky1 - ky0) * (kx1 - kx0);
            #pragma unroll
            for (int cc = 0; cc < 4; ++cc) {
                const ushort* tb = tP + (co0 + cc) * 16;
                int Wt = tb[15];
                int Wr = (int)tb[ky1 * 4 + kx1] - (int)tb[ky0 * 4 + kx1]
                       - (int)tb[ky1 * 4 + kx0] + (int)tb[ky0 * 4 + kx0];
                sv[cc] = 256 * nv - 2 * S[cc] + 2 * (Wt - Wr);
            }
            if (sbz[bb]) {
                #pragma unroll 1
                for (int ky = 0; ky < 3; ++ky) {
                    int yy = y - 1 + ky;
                    if ((unsigned)yy >= 6u) continue;
                    #pragma unroll 1
                    for (int kx = 0; kx < 3; ++kx) {
                        int xx = x0 - 1 + kx;
                        if ((unsigned)xx >= 6u) continue;
                        size_t g = ((size_t)(b0 + bb) * 36 + yy * 6 + xx) * 4;
                        #pragma unroll 1
                        for (int wd = 0; wd < 4; ++wd) {
                            u64 za = zap[g + wd];
                            if (za) {
                                int pz = (int)__popcll(za);
                                #pragma unroll
                                for (int cc = 0; cc < 4; ++cc) {
                                    u64 ws_ = w[((size_t)(co0 + cc) * 9 + ky * 3 + kx) * 8 + 2 * wd];
                                    sv[cc] += 2 * (int)__popcll(ws_ & za) - pz;
                                }
                            }
                        }
                    }
                }
            }
        } else {
            #pragma unroll 1
            for (int cc = 0; cc < 4; ++cc) {
                const u64* wb = w + (size_t)(co0 + cc) * 72;
                int sum = 0;
                for (int ky = 0; ky < 3; ++ky) {
                    int yy = y - 1 + ky;
                    if ((unsigned)yy >= 6u) continue;
                    for (int kx = 0; kx < 3; ++kx) {
                        int xx = x0 - 1 + kx;
                        if ((unsigned)xx >= 6u) continue;
                        size_t g = ((size_t)(b0 + bb) * 36 + yy * 6 + xx) * 4;
                        const u64* wp = wb + (ky * 3 + kx) * 8;
                        for (int wd = 0; wd < 4; ++wd) {
                            u64 val = ~zap[g + wd] & wp[2 * wd + 1];
                            u64 df  = (ps[g + wd] ^ wp[2 * wd]) & val;
                            sum += (int)__popcll(val) - 2 * (int)__popcll(df);
                        }
                    }
                }
                sv[cc] = sum;
            }
        }
        #pragma unroll
        for (int cc = 0; cc < 4; ++cc)
            sacc[cc][bb * 36 + r] = sv[cc];
    }
    __syncthreads();
    int pooled[4] = {0, 0, 0, 0};
    const bool pact = t < 32;
    if (pact) {
        int bb2 = t / 4, wi = t % 4, py = (wi >> 1) * 2, px = (wi & 1) * 2;
        #pragma unroll
        for (int cc = 0; cc < 4; ++cc) {
            int best = -1000000;
            #pragma unroll
            for (int dy = 0; dy < 3; ++dy)
                #pragma unroll
                for (int dx = 0; dx < 3; ++dx)
                    best = max(best, sacc[cc][bb2 * 36 + (py + dy) * 6 + (px + dx)]);
            pooled[cc] = best;
            outp[((size_t)(b0 + bb2) * 256 + co0 + cc) * 4 + wi] = (float)best;
        }
    }
    const int wid = t >> 6, lane = t & 63;
    #pragma unroll 1
    for (int cc = 0; cc < 4; ++cc) {
        int v = pact ? pooled[cc] : 0;
        long long q = (long long)v * v;
        wred_i(v, q);
        if (lane == 0) { sWi[wid] = v; sWq[wid] = q; }
        __syncthreads();
        if (t == 0) {
            part[((size_t)(co0 + cc) * 64 + bg) * 2]     = (double)(sWi[0] + sWi[1] + sWi[2] + sWi[3] + sWi[4]);
            part[((size_t)(co0 + cc) * 64 + bg) * 2 + 1] = (double)(sWq[0] + sWq[1] + sWq[2] + sWq[3] + sWq[4]);
        }
        __syncthreads();
    }
}

// ---------------------------------------------------------------------------
__global__ void k_stats_final(const double* __restrict__ part, const float* __restrict__ g,
                              float* __restrict__ mean, float* __restrict__ inva,
                              int NB, long total) {
    __shared__ double sS[64], sQ[64];
    const int c = blockIdx.x, t = threadIdx.x;
    double s = 0.0, q = 0.0;
    for (int k = t; k < NB; k += 64) {
        s += part[((size_t)c * NB + k) * 2];
        q += part[((size_t)c * NB + k) * 2 + 1];
    }
    sS[t] = s; sQ[t] = q;
    __syncthreads();
    for (int o = 32; o > 0; o >>= 1) {
        if (t < o) { sS[t] += sS[t + o]; sQ[t] += sQ[t + o]; }
        __syncthreads();
    }
    if (t == 0) {
        double m = sS[0] / (double)total;
        double var = sQ[0] / (double)total - m * m;
        mean[c] = (float)m;
        inva[c] = g[c] * (float)(1.0 / sqrt(var + 1e-5));
    }
}

// ---- BN apply + sign + pack -> sign plane, za plane, per-batch zero flags ----
__global__ void k_bnpack2d(const float* __restrict__ x, const float* __restrict__ m,
                           const float* __restrict__ a, const float* __restrict__ bt,
                           u64* __restrict__ ps, u64* __restrict__ za,
                           int B, int C, int HW, int* __restrict__ bz) {
    int NW = C >> 6;
    int tot = B * HW * NW;
    int idx = blockIdx.x * blockDim.x + threadIdx.x;
    if (idx >= tot) return;
    int wd = idx % NW, t = idx / NW;
    int j = t % HW, b = t / HW;
    u64 s = 0, nz = 0;
    for (int c0 = 0; c0 < 64; ++c0) {
        int c = wd * 64 + c0;
        float v = (x[((size_t)b * C + c) * HW + j] - m[c]) * a[c] + bt[c];
        if (v > 0.0f) s |= (1ull << c0);
        if (v != 0.0f) nz |= (1ull << c0);
    }
    size_t o = ((size_t)b * HW + j) * NW + wd;
    ps[o] = s; za[o] = ~nz;
    if (nz != ~0ull) atomicOr(bz + b, 1);
}

__global__ void k_bnpack_flat(const float* __restrict__ x, const float* __restrict__ m,
                              const float* __restrict__ a, const float* __restrict__ bt,
                              u64* __restrict__ ps, u64* __restrict__ za,
                              int B, int* __restrict__ bz) {
    int idx = blockIdx.x * blockDim.x + threadIdx.x;
    if (idx >= B * 16) return;
    int wd = idx % 16, b = idx / 16;
    u64 s = 0, nz = 0;
    for (int k = 0; k < 64; ++k) {
        int f = wd * 64 + k;
        int c = f >> 2, j = f & 3;
        float v = (x[((size_t)b * 256 + c) * 4 + j] - m[c]) * a[c] + bt[c];
        if (v > 0.0f) s |= (1ull << k);
        if (v != 0.0f) nz |= (1ull << k);
    }
    ps[(size_t)b * 16 + wd] = s;
    za[(size_t)b * 16 + wd] = ~nz;
    if (nz != ~0ull) atomicOr(bz + b, 1);
}

__global__ void k_bnpack1d(const float* __restrict__ x, const float* __restrict__ m,
                           const float* __restrict__ a, const float* __restrict__ bt,
                           u64* __restrict__ ps, u64* __restrict__ za,
                           int B, int F, int* __restrict__ bz) {
    int NW = F >> 6;
    int idx = blockIdx.x * blockDim.x + threadIdx.x;
    if (idx >= B * NW) return;
    int wd = idx % NW, b = idx / NW;
    const float* row = x + (size_t)b * F + wd * 64;
    u64 s = 0, nz = 0;
    for (int c = 0; c < 64; ++c) {
        int f = wd * 64 + c;
        float v = (row[c] - m[f]) * a[f] + bt[f];
        if (v > 0.0f) s |= (1ull << c);
        if (v != 0.0f) nz |= (1ull << c);
    }
    ps[(size_t)b * NW + wd] = s;
    za[(size_t)b * NW + wd] = ~nz;
    if (nz != ~0ull) atomicOr(bz + b, 1);
}

// ---------------------------------------------------------------------------
// binary FC, 32x32 tile, 2x2 micro-tile, sign-only LDS, row zero-correction.
// ---------------------------------------------------------------------------
template<int NW>
__global__ __launch_bounds__(256)
void k_fcbin3(const u64* __restrict__ As_, const u64* __restrict__ zaA,
              const u64* __restrict__ Ws_, const u64* __restrict__ Wn_,
              const float* __restrict__ bias, float* __restrict__ C, int O,
              double* __restrict__ part, int nbc, const int* __restrict__ wflags,
              int slot, const int* __restrict__ rowz) {
    constexpr int ST = NW | 1;
    __shared__ u64 sA[32 * ST];
    __shared__ u64 sW[32 * ST];
    __shared__ int sacc[32][32];
    __shared__ int srz[32];
    const int t = threadIdx.x;
    const int wfl = wflags[slot];
    const int b0 = blockIdx.y * 32, o0 = blockIdx.x * 32;
    if (t < 32) srz[t] = rowz[b0 + t];
    for (int i = t; i < 32 * NW; i += 256) {
        int rr = i / NW, cc = i % NW;
        sA[rr * ST + cc] = As_[(size_t)(b0 + rr) * NW + cc];
        int o = o0 + rr;
        sW[rr * ST + cc] = (o < O) ? Ws_[(size_t)o * NW + cc] : 0ull;
    }
    __syncthreads();
    const int tx = t % 16, ty = t / 16;
    int acc[2][2];
    if (wfl == 0) {
        int S00 = 0, S01 = 0, S10 = 0, S11 = 0;
        #pragma unroll
        for (int wd = 0; wd < NW; ++wd) {
            u64 a0 = sA[ty * ST + wd], a1 = sA[(16 + ty) * ST + wd];
            u64 w0 = sW[tx * ST + wd], w1 = sW[(16 + tx) * ST + wd];
            S00 += (int)__popcll(a0 ^ w0); S01 += (int)__popcll(a0 ^ w1);
            S10 += (int)__popcll(a1 ^ w0); S11 += (int)__popcll(a1 ^ w1);
        }
        acc[0][0] = 64 * NW - 2 * S00; acc[0][1] = 64 * NW - 2 * S01;
        acc[1][0] = 64 * NW - 2 * S10; acc[1][1] = 64 * NW - 2 * S11;
        // rare zero-row correction
        #pragma unroll
        for (int i = 0; i < 2; ++i) {
            if (srz[ty + 16 * i]) {
                int b = b0 + ty + 16 * i;
                int c0_ = 0, c1_ = 0;
                #pragma unroll 1
                for (int wd = 0; wd < NW; ++wd) {
                    u64 za = zaA[(size_t)b * NW + wd];
                    if (za) {
                        int pz = (int)__popcll(za);
                        c0_ += 2 * (int)__popcll(sW[tx * ST + wd] & za) - pz;
                        c1_ += 2 * (int)__popcll(sW[(16 + tx) * ST + wd] & za) - pz;
                    }
                }
                acc[i][0] += c0_;
                acc[i][1] += c1_;
            }
        }
    } else {
        #pragma unroll 1
        for (int i = 0; i < 2; ++i)
            #pragma unroll 1
            for (int j = 0; j < 2; ++j) {
                int b = b0 + ty + 16 * i, o = o0 + tx + 16 * j;
                int aV = 0, aD = 0;
                if (o < O) {
                    for (int wd = 0; wd < NW; ++wd) {
                        u64 val = ~zaA[(size_t)b * NW + wd] & Wn_[(size_t)o * NW + wd];
                        u64 df  = (As_[(size_t)b * NW + wd] ^ Ws_[(size_t)o * NW + wd]) & val;
                        aV += (int)__popcll(val); aD += (int)__popcll(df);
                    }
                }
                acc[i][j] = aV - 2 * aD;
            }
    }
    #pragma unroll
    for (int i = 0; i < 2; ++i)
        #pragma unroll
        for (int j = 0; j < 2; ++j) {
            int o = o0 + tx + 16 * j;
            int v = (o < O) ? acc[i][j] : 0;
            if (o < O)
                C[(size_t)(b0 + ty + 16 * i) * O + o] = (float)v + (bias ? bias[o] : 0.0f);
            sacc[ty + 16 * i][tx + 16 * j] = v;
        }
    __syncthreads();
    if (part != nullptr && t < 32) {
        int s = 0; long long q = 0;
        #pragma unroll
        for (int b = 0; b < 32; ++b) {
            int v = sacc[b][t];
            s += v; q += (long long)v * v;
        }
        if (o0 + t < O) {
            part[((size_t)(o0 + t) * nbc + blockIdx.y) * 2]     = (double)s;
            part[((size_t)(o0 + t) * nbc + blockIdx.y) * 2 + 1] = (double)q;
        }
    }
}

// ---------------------------------------------------------------------------

static inline int cdiv(long a, int b) { return (int)((a + b - 1) / b); }

extern "C" void kernel_launch(void* const* d_in, const int* in_sizes, int n_in,
                              void* d_out, int out_size, void* d_ws, size_t ws_size,
                              hipStream_t stream) {
    const float* x   = (const float*)d_in[0];
    const float* w1  = (const float*)d_in[1];
    const float* g1  = (const float*)d_in[2];
    const float* b1  = (const float*)d_in[3];
    const float* w2  = (const float*)d_in[4];
    const float* g2  = (const float*)d_in[5];
    const float* b2  = (const float*)d_in[6];
    const float* w3  = (const float*)d_in[7];
    const float* g3  = (const float*)d_in[8];
    const float* b3  = (const float*)d_in[9];
    const float* w4  = (const float*)d_in[10];
    const float* g4  = (const float*)d_in[11];
    const float* b4  = (const float*)d_in[12];
    const float* w5  = (const float*)d_in[13];
    const float* g5  = (const float*)d_in[14];
    const float* b5  = (const float*)d_in[15];
    const float* wl1 = (const float*)d_in[16];
    const float* gl1 = (const float*)d_in[17];
    const float* bl1 = (const float*)d_in[18];
    const float* wl2 = (const float*)d_in[19];
    const float* gl2 = (const float*)d_in[20];
    const float* bl2 = (const float*)d_in[21];
    const float* wl3 = (const float*)d_in[22];
    const float* bl3 = (const float*)d_in[23];
    float* out = (float*)d_out;
    (void)in_sizes; (void)n_in; (void)out_size; (void)ws_size;

    char* base = (char*)d_ws;
    size_t off = 0;
    auto alloc = [&](size_t bytes) {
        char* p = base + off;
        off += (bytes + 15) & ~(size_t)15;
        return (void*)p;
    };
    float* R1   = (float*)alloc(7372800 * 4);
    float* R2   = (float*)alloc(4718592 * 4);
    float* R3   = (float*)alloc(524288 * 4);
    float* w1s  = (float*)alloc(4800 * 4);
    u64* p1s = (u64*)alloc(115200 * 8);   u64* p1z = (u64*)alloc(115200 * 8);
    u64* p2s = (u64*)alloc(55296 * 8);    u64* p2z = (u64*)alloc(55296 * 8);
    u64* p3s = (u64*)alloc(110592 * 8);   u64* p3z = (u64*)alloc(110592 * 8);
    u64* p4s = (u64*)alloc(73728 * 8);    u64* p4z = (u64*)alloc(73728 * 8);
    u64* p5s = (u64*)alloc(8192 * 8);     u64* p5z = (u64*)alloc(8192 * 8);
    u64* pf1s = (u64*)alloc(32768 * 8);   u64* pf1z = (u64*)alloc(32768 * 8);
    u64* pf2s = (u64*)alloc(16384 * 8);   u64* pf2z = (u64*)alloc(16384 * 8);
    u64* w2p  = (u64*)alloc(9600 * 8);
    u64* w3p  = (u64*)alloc(20736 * 8);
    u64* w4p  = (u64*)alloc(27648 * 8);
    u64* w5p  = (u64*)alloc(18432 * 8);
    u64* wl1s_ = (u64*)alloc(65536 * 8);  u64* wl1n_ = (u64*)alloc(65536 * 8);
    u64* wl2s_ = (u64*)alloc(131072 * 8); u64* wl2n_ = (u64*)alloc(131072 * 8);
    u64* wl3s_ = (u64*)alloc(320 * 8);    u64* wl3n_ = (u64*)alloc(320 * 8);
    double* part = (double*)alloc((size_t)4096 * 32 * 2 * 8);
    float* stats = (float*)alloc(7 * 2 * 4096 * 4);
    // zero-init region: 8 weight flags + 7 x 512 per-batch zero flags
    int* wflags = (int*)alloc((8 + 7 * 512) * 4);
    int* bzc2 = wflags + 8;
    int* bzc3 = bzc2 + 512;
    int* bzc4 = bzc3 + 512;
    int* bzc5 = bzc4 + 512;
    int* rz1  = bzc5 + 512;
    int* rz2  = rz1 + 512;
    int* rz3  = rz2 + 512;
    ushort* t2 = (ushort*)alloc(192 * 4 * 2);
    ushort* t3 = (ushort*)alloc(384 * 16 * 2);
    ushort* t4 = (ushort*)alloc(256 * 16 * 2);
    ushort* t5 = (ushort*)alloc(256 * 16 * 2);
    float* m_[7]; float* a_[7];
    for (int l = 0; l < 7; ++l) { m_[l] = stats + (size_t)l * 8192; a_[l] = m_[l] + 4096; }

    hipMemsetAsync(wflags, 0, (8 + 7 * 512) * 4, stream);

    // ---- weight prep ----
    k_prep<<<cdiv(PREP_TOTAL, 256), 256, 0, stream>>>(
        w1, w1s, w2, w2p, w3, w3p, w4, w4p, w5, w5p,
        wl1, wl1s_, wl1n_, wl2, wl2s_, wl2n_, wl3, wl3s_, wl3n_, wflags);
    k_prep2<<<cdiv(192 + 384 + 256 + 256, 256), 256, 0, stream>>>(
        w2p, w3p, w4p, w5p, t2, t3, t4, t5);

    // ---- conv1 + pool -> R1 (+stats); bn1; pack -> p1 ----
    k_conv1<<<dim3(8, 512), 256, 0, stream>>>(x, w1s, R1, part);
    k_stats_final<<<64, 64, 0, stream>>>(part, g1, m_[0], a_[0], 512, (long)512 * 225);
    k_bnpack2d<<<cdiv((long)512 * 225, 256), 256, 0, stream>>>(R1, m_[0], a_[0], b1, p1s, p1z, 512, 64, 225, bzc2);

    // ---- conv2 (CO=4) + pool -> R2 (+stats); bn2; pack -> p2 ----
    k_conv2<<<dim3(48, 64), 320, 0, stream>>>(p1s, p1z, w2p, R2, part, t2, wflags, bzc2);
    k_stats_final<<<192, 64, 0, stream>>>(part, g2, m_[1], a_[1], 64, (long)512 * 36);
    k_bnpack2d<<<cdiv((long)512 * 36 * 3, 256), 256, 0, stream>>>(R2, m_[1], a_[1], b2, p2s, p2z, 512, 192, 36, bzc3);

    // ---- conv3 (CO=4) -> R1 (+stats); bn3; pack -> p3 ----
    k_convbin3<3, 3><<<dim3(96, 64), 320, 0, stream>>>(p2s, p2z, w3p, R1, part, 384, t3, wflags, 1, bzc3);
    k_stats_final<<<384, 64, 0, stream>>>(part, g3, m_[2], a_[2], 64, (long)512 * 36);
    k_bnpack2d<<<cdiv((long)512 * 36 * 6, 256), 256, 0, stream>>>(R1, m_[2], a_[2], b3, p3s, p3z, 512, 384, 36, bzc4);

    // ---- conv4 (CO=4) -> R2 (+stats); bn4; pack -> p4 ----
    k_convbin3<6, 3><<<dim3(64, 64), 320, 0, stream>>>(p3s, p3z, w4p, R2, part, 256, t4, wflags, 2, bzc4);
    k_stats_final<<<256, 64, 0, stream>>>(part, g4, m_[3], a_[3], 64, (long)512 * 36);
    k_bnpack2d<<<cdiv((long)512 * 36 * 4, 256), 256, 0, stream>>>(R2, m_[3], a_[3], b4, p4s, p4z, 512, 256, 36, bzc5);

    // ---- conv5 (CO=4) + in-LDS pool -> R3 (+stats on pooled); bn5; pack -> p5 ----
    k_conv5<<<dim3(64, 64), 320, 0, stream>>>(p4s, p4z, w5p, R3, part, t5, wflags, bzc5);
    k_stats_final<<<256, 64, 0, stream>>>(part, g5, m_[4], a_[4], 64, (long)512 * 4);
    k_bnpack_flat<<<cdiv(512 * 16, 256), 256, 0, stream>>>(R3, m_[4], a_[4], b5, p5s, p5z, 512, rz1);

    // ---- fc1 -> R2 (+stats); bn; pack -> pf1 ----
    k_fcbin3<16><<<dim3(128, 16), 256, 0, stream>>>(p5s, p5z, wl1s_, wl1n_, nullptr, R2, 4096, part, 16, wflags, 4, rz1);
    k_stats_final<<<4096, 64, 0, stream>>>(part, gl1, m_[5], a_[5], 16, 512);
    k_bnpack1d<<<cdiv(512 * 64, 256), 256, 0, stream>>>(R2, m_[5], a_[5], bl1, pf1s, pf1z, 512, 4096, rz2);

    // ---- fc2 -> R1 (+stats); bn; pack -> pf2 ----
    k_fcbin3<64><<<dim3(64, 16), 256, 0, stream>>>(pf1s, pf1z, wl2s_, wl2n_, nullptr, R1, 2048, part, 16, wflags, 5, rz2);
    k_stats_final<<<2048, 64, 0, stream>>>(part, gl2, m_[6], a_[6], 16, 512);
    k_bnpack1d<<<cdiv(512 * 32, 256), 256, 0, stream>>>(R1, m_[6], a_[6], bl2, pf2s, pf2z, 512, 2048, rz3);

    // ---- fc3 + bias -> out [512,10] ----
    k_fcbin3<32><<<dim3(1, 16), 256, 0, stream>>>(pf2s, pf2z, wl3s_, wl3n_, bl3, out, 10, nullptr, 0, wflags, 6, rz3);
}